// Round 3
// baseline (4625.955 us; speedup 1.0000x reference)
//
#include <hip/hip_runtime.h>
#include <float.h>
#include <math.h>

// ---------------------------------------------------------------------------
// UltraMemLayerV1 — round 3: f32 selection path (flip-safe) + bf16 final GEMM.
//   k_prep32 : keys LN + knorm fold -> Bg (raw keysn, [c][hk][r][256]) and
//              Bct (u/v-combined, [c][hk][256])  — both k-contiguous f32
//   k_gemm32 : tuned f32 GEMM (128x128, BK=16, dbuf LDS, split-K option)
//       q    : hidden @ wq -> qpart[4]  (split-K=4)
//   k_ln_q   : sum qpart + LN -> q12n [side*4096+b][256]
//       score: q12n @ Bct^T -> s_r [8192][2048]   (sides fused in M)
//   k_topk1  : per (side,b,h) top-32 of 1024 -> i1/i2
//   k_gather : g1/g2 = q . keysn[selected]  (f32 dots, L2-resident Bg)
//   k_stage2 : 32x32 tucker bilinear, top-32, softmax, shuffle  (round-1)
//   k_agg    : weighted value gather -> aggb (bf16)
//   k_mfma   : aggb @ wvT -> out   (bf16 MFMA, error ~4e-5 « threshold)
// ---------------------------------------------------------------------------

typedef __attribute__((ext_vector_type(8))) __bf16 bf16x8;
typedef __attribute__((ext_vector_type(4))) float f32x4;

__device__ __forceinline__ unsigned short f2bf(float x) {
  unsigned int u = __float_as_uint(x);
  return (unsigned short)((u + 0x7FFFu + ((u >> 16) & 1u)) >> 16);
}

__device__ __forceinline__ float wave_sum(float x) {
#pragma unroll
  for (int o = 32; o; o >>= 1) x += __shfl_xor(x, o, 64);
  return x;
}

// ---------------- keys prep: LN over d, fold knorm + tucker u/v -------------
__global__ void k_prep32(const float* __restrict__ keys, const float* __restrict__ knw,
                         const float* __restrict__ tu, const float* __restrict__ tv,
                         float* __restrict__ Bct, float* __restrict__ Bg) {
  const int bid = blockIdx.x;  // 4096 = c*2048 + h*1024 + k
  const int lane = threadIdx.x;
  const int k = bid & 1023, h = (bid >> 10) & 1, c = bid >> 11;
  const float* base = keys + (size_t)((h * 2 + c) * 1024 + k) * 512;  // (h,c,k,d,r)
  float x0[4], x1[4];
  float s0 = 0.f, s1 = 0.f, sq0 = 0.f, sq1 = 0.f;
#pragma unroll
  for (int i = 0; i < 4; ++i) {
    const int d = lane + i * 64;
    const float2 p = *(const float2*)&base[d * 2];
    x0[i] = p.x; x1[i] = p.y;
    s0 += p.x; sq0 += p.x * p.x;
    s1 += p.y; sq1 += p.y * p.y;
  }
  s0 = wave_sum(s0); sq0 = wave_sum(sq0);
  s1 = wave_sum(s1); sq1 = wave_sum(sq1);
  const float m0 = s0 * (1.f / 256.f), m1 = s1 * (1.f / 256.f);
  const float rs0 = 1.f / sqrtf(sq0 * (1.f / 256.f) - m0 * m0 + 1e-5f);
  const float rs1 = 1.f / sqrtf(sq1 * (1.f / 256.f) - m1 * m1 + 1e-5f);
  const float* uv = c ? tv : tu;
  const float u0 = uv[h * 2 + 0], u1 = uv[h * 2 + 1];
  const int chk = c * 2048 + h * 1024 + k;
  float* bg = Bg + (size_t)chk * 512;
  float* bc = Bct + (size_t)chk * 256;
#pragma unroll
  for (int i = 0; i < 4; ++i) {
    const int d = lane + i * 64;
    const float w = knw[d];
    const float y0 = (x0[i] - m0) * rs0 * w;
    const float y1 = (x1[i] - m1) * rs1 * w;
    bg[d] = y0;
    bg[256 + d] = y1;
    bc[d] = y0 * u0 + y1 * u1;
  }
}

// ---------------- tuned f32 GEMM: C = A[M][K] @ B^T (or B[K][N]) ------------
// 128x128 tile, BK=16, 256 threads (TM=TN=8 split in column halves),
// double-buffered LDS, one barrier per K-tile. B1_ used for rows >= m_split.
template <bool BT, int SPLITK>
__global__ __launch_bounds__(256, 4) void k_gemm32(
    const float* __restrict__ A, const float* __restrict__ B0,
    const float* __restrict__ B1_, int m_split,
    float* __restrict__ C, int M, int N, int K) {
  constexpr int BK = 16;
  __shared__ float As[2][BK][132];
  __shared__ float Bs[2][BK][132];
  const int tid = threadIdx.x;
  const int tx = tid & 15, ty = tid >> 4;
  const int bm = blockIdx.x * 128, bn = blockIdx.y * 128;
  const float* Bp = (bm >= m_split) ? B1_ : B0;
  const int Ks = K / SPLITK;
  const int kbeg = blockIdx.z * Ks;
  float* Cp = C + (size_t)blockIdx.z * M * N;
  float acc[8][8] = {};
  float4 ar[2], br[2];

  auto load = [&](int t) {
    const int k0 = kbeg + t * BK;
#pragma unroll
    for (int u = 0; u < 2; ++u) {
      const int q = tid + u * 256;
      const int m = q >> 2, kc = q & 3;
      ar[u] = *(const float4*)&A[(size_t)(bm + m) * K + k0 + kc * 4];
      if (BT) {
        br[u] = *(const float4*)&Bp[(size_t)(bn + m) * K + k0 + kc * 4];
      } else {
        const int kk = q >> 5, nq = q & 31;
        br[u] = *(const float4*)&Bp[(size_t)(k0 + kk) * N + bn + nq * 4];
      }
    }
  };
  auto store = [&](int buf) {
#pragma unroll
    for (int u = 0; u < 2; ++u) {
      const int q = tid + u * 256;
      const int m = q >> 2, kc = q & 3;
      As[buf][kc * 4 + 0][m] = ar[u].x;
      As[buf][kc * 4 + 1][m] = ar[u].y;
      As[buf][kc * 4 + 2][m] = ar[u].z;
      As[buf][kc * 4 + 3][m] = ar[u].w;
      if (BT) {
        Bs[buf][kc * 4 + 0][m] = br[u].x;
        Bs[buf][kc * 4 + 1][m] = br[u].y;
        Bs[buf][kc * 4 + 2][m] = br[u].z;
        Bs[buf][kc * 4 + 3][m] = br[u].w;
      } else {
        const int kk = q >> 5, nq = q & 31;
        *(float4*)&Bs[buf][kk][nq * 4] = br[u];
      }
    }
  };
  auto compute = [&](int buf) {
#pragma unroll
    for (int kk = 0; kk < BK; ++kk) {
      float a[8], b[8];
      *(float4*)&a[0] = *(const float4*)&As[buf][kk][ty * 4];
      *(float4*)&a[4] = *(const float4*)&As[buf][kk][64 + ty * 4];
      *(float4*)&b[0] = *(const float4*)&Bs[buf][kk][tx * 4];
      *(float4*)&b[4] = *(const float4*)&Bs[buf][kk][64 + tx * 4];
#pragma unroll
      for (int i = 0; i < 8; ++i)
#pragma unroll
        for (int j = 0; j < 8; ++j) acc[i][j] += a[i] * b[j];
    }
  };

  const int T = Ks / BK;
  load(0);
  store(0);
  __syncthreads();
  int cur = 0;
  for (int t = 0; t < T; ++t) {
    if (t + 1 < T) load(t + 1);
    compute(cur);
    if (t + 1 < T) {
      store(cur ^ 1);
      __syncthreads();
      cur ^= 1;
    }
  }
#pragma unroll
  for (int ih = 0; ih < 2; ++ih)
#pragma unroll
    for (int i = 0; i < 4; ++i) {
      const size_t r = bm + ih * 64 + ty * 4 + i;
#pragma unroll
      for (int jh = 0; jh < 2; ++jh) {
        float4 v = {acc[ih * 4 + i][jh * 4 + 0], acc[ih * 4 + i][jh * 4 + 1],
                    acc[ih * 4 + i][jh * 4 + 2], acc[ih * 4 + i][jh * 4 + 3]};
        *(float4*)&Cp[r * N + bn + jh * 64 + tx * 4] = v;
      }
    }
}

// ---------------- q: sum split-K partials + LN -> q12n ----------------------
__global__ void k_ln_q(const float* __restrict__ qpart, const float* __restrict__ qnw,
                       float* __restrict__ q12n) {
  const int bid = blockIdx.x;  // b*2 + c
  const int lane = threadIdx.x;
  const int b = bid >> 1, c = bid & 1;
  float x[4] = {};
#pragma unroll
  for (int s = 0; s < 4; ++s) {
    const float4 p = *(const float4*)&qpart[(size_t)s * 4096 * 512 + (size_t)b * 512 + c * 256 + lane * 4];
    x[0] += p.x; x[1] += p.y; x[2] += p.z; x[3] += p.w;
  }
  float sm = x[0] + x[1] + x[2] + x[3];
  float sq = x[0] * x[0] + x[1] * x[1] + x[2] * x[2] + x[3] * x[3];
  sm = wave_sum(sm);
  sq = wave_sum(sq);
  const float mean = sm * (1.f / 256.f);
  const float rs = 1.f / sqrtf(sq * (1.f / 256.f) - mean * mean + 1e-5f);
  const float4 w4 = *(const float4*)&qnw[lane * 4];
  float4 o;
  o.x = (x[0] - mean) * rs * w4.x;
  o.y = (x[1] - mean) * rs * w4.y;
  o.z = (x[2] - mean) * rs * w4.z;
  o.w = (x[3] - mean) * rs * w4.w;
  *(float4*)&q12n[(size_t)(c * 4096 + b) * 256 + lane * 4] = o;
}

// ---------------- stage-1 top-32 over 1024 combined scores ------------------
__global__ void k_topk1(const float* __restrict__ s_r,
                        int* __restrict__ i1, int* __restrict__ i2) {
  const int bid = blockIdx.x;  // side*8192 + b*2 + h
  const int side = bid >> 13;
  const int bh = bid & 8191;
  const int b = bh >> 1, h = bh & 1;
  const int lane = threadIdx.x;
  const float* row = s_r + (size_t)(side * 4096 + b) * 2048 + h * 1024;
  float sv[16];
#pragma unroll
  for (int i = 0; i < 16; ++i) sv[i] = row[lane + (i << 6)];
  int* iout = side ? i2 : i1;
  int win_k = 0;
  for (int it = 0; it < 32; ++it) {
    float bv = -FLT_MAX;
    int bk = 0x7FFFFFFF;
#pragma unroll
    for (int i = 0; i < 16; ++i) {
      const int kk = lane + (i << 6);
      if (sv[i] > bv || (sv[i] == bv && kk < bk)) { bv = sv[i]; bk = kk; }
    }
#pragma unroll
    for (int o = 32; o; o >>= 1) {
      const float ov = __shfl_xor(bv, o, 64);
      const int ok = __shfl_xor(bk, o, 64);
      if (ov > bv || (ov == bv && ok < bk)) { bv = ov; bk = ok; }
    }
    if ((bk & 63) == lane) sv[bk >> 6] = -FLT_MAX;
    if (lane == it) win_k = bk;
  }
  if (lane < 32) iout[bh * 32 + lane] = win_k;
}

// ---------------- gather per-rank scores for selected keys ------------------
__global__ void k_gather(const float* __restrict__ q12n, const float* __restrict__ Bg,
                         const int* __restrict__ i1, const int* __restrict__ i2,
                         float* __restrict__ g1, float* __restrict__ g2) {
  __shared__ float qs[256];
  const int bid = blockIdx.x;  // side*8192 + b*2 + h
  const int side = bid >> 13;
  const int bh = bid & 8191;
  const int b = bh >> 1, h = bh & 1;
  const int lane = threadIdx.x;
  const float* q = q12n + (size_t)(side * 4096 + b) * 256;
  *(float4*)&qs[lane * 4] = *(const float4*)&q[lane * 4];
  __syncthreads();
  const int j = lane >> 1, r = lane & 1;
  const int sel = (side ? i2 : i1)[bh * 32 + j];
  const float* krow = Bg + ((size_t)(side * 2048 + h * 1024 + sel) * 2 + r) * 256;
  float acc = 0.f;
#pragma unroll
  for (int d = 0; d < 256; d += 4) {
    const float4 kv = *(const float4*)&krow[d];
    const float4 qv = *(const float4*)&qs[d];
    acc += kv.x * qv.x + kv.y * qv.y + kv.z * qv.z + kv.w * qv.w;
  }
  (side ? g2 : g1)[(bh * 32 + j) * 2 + r] = acc;
}

// ---------------- stage-2: 32x32 bilinear scores, top-32, softmax -----------
__global__ void k_stage2(const float* __restrict__ g1, const float* __restrict__ g2,
                         const int* __restrict__ i1, const int* __restrict__ i2,
                         const float* __restrict__ tucker_core,
                         const int* __restrict__ shuffle_index,
                         float* __restrict__ w_out, int* __restrict__ sh_out) {
  __shared__ float sg1x[32], sg1y[32], sg2x[32], sg2y[32];
  __shared__ int si1[32], si2[32];
  const int bh = blockIdx.x;
  const int h = bh & 1;
  const int lane = threadIdx.x;
  if (lane < 32) {
    const float2 p1 = *(const float2*)&g1[(bh * 32 + lane) * 2];
    const float2 p2 = *(const float2*)&g2[(bh * 32 + lane) * 2];
    sg1x[lane] = p1.x;
    sg1y[lane] = p1.y;
    sg2x[lane] = p2.x;
    sg2y[lane] = p2.y;
    si1[lane] = i1[bh * 32 + lane];
    si2[lane] = i2[bh * 32 + lane];
  }
  __syncthreads();
  const float c00 = tucker_core[h * 4 + 0] + tucker_core[8 + h * 4 + 0];
  const float c01 = tucker_core[h * 4 + 1] + tucker_core[8 + h * 4 + 1];
  const float c10 = tucker_core[h * 4 + 2] + tucker_core[8 + h * 4 + 2];
  const float c11 = tucker_core[h * 4 + 3] + tucker_core[8 + h * 4 + 3];
  float sv[16];
#pragma unroll
  for (int i = 0; i < 16; ++i) {
    const int p = lane + (i << 6);
    const int k = p >> 5, l = p & 31;
    const float a0 = sg1x[k] * c00 + sg1y[k] * c10;
    const float a1 = sg1x[k] * c01 + sg1y[k] * c11;
    sv[i] = a0 * sg2x[l] + a1 * sg2y[l];
  }
  float m0 = 0.f, Z = 0.f, win_e = 0.f;
  int win_p = 0;
  for (int it = 0; it < 32; ++it) {
    float bv = -FLT_MAX;
    int bp = 0x7FFFFFFF;
#pragma unroll
    for (int i = 0; i < 16; ++i) {
      const int p = lane + (i << 6);
      if (sv[i] > bv || (sv[i] == bv && p < bp)) { bv = sv[i]; bp = p; }
    }
#pragma unroll
    for (int o = 32; o; o >>= 1) {
      const float ov = __shfl_xor(bv, o, 64);
      const int op = __shfl_xor(bp, o, 64);
      if (ov > bv || (ov == bv && op < bp)) { bv = ov; bp = op; }
    }
    if (it == 0) m0 = bv;
    const float e = expf(bv - m0);
    Z += e;
    if ((bp & 63) == lane) sv[bp >> 6] = -FLT_MAX;
    if (lane == it) { win_e = e; win_p = bp; }
  }
  if (lane < 32) {
    const int k = win_p >> 5, l = win_p & 31;
    const int ai = si1[k] * 1024 + si2[l];
    const int sh = shuffle_index[ai];  // = (eidx<<18) | vidx
    w_out[bh * 32 + lane] = win_e / Z;
    sh_out[bh * 32 + lane] = sh;
  }
}

// ---------------- weighted value gather/aggregate -> bf16 agg ---------------
__global__ __launch_bounds__(256) void k_agg(const float* __restrict__ w_out,
                                             const int* __restrict__ sh_out,
                                             const float* __restrict__ values,
                                             unsigned short* __restrict__ aggb) {
  __shared__ float acc[4][1024];
  const int b = blockIdx.x;
  const int tid = threadIdx.x;
  const int wave = tid >> 6, lane = tid & 63;
  for (int i = tid; i < 4096; i += 256) ((float*)acc)[i] = 0.f;
  __syncthreads();
  for (int j = wave; j < 64; j += 4) {
    const float wgt = w_out[b * 64 + j];
    const int sh = sh_out[b * 64 + j];
    const int vidx = sh & 0x3FFFF;
    const int e = sh >> 18;
    const float4 v = *(const float4*)&values[(size_t)vidx * 256 + lane * 4];
    float* dst = &acc[wave][e * 256 + lane * 4];
    dst[0] += wgt * v.x;
    dst[1] += wgt * v.y;
    dst[2] += wgt * v.z;
    dst[3] += wgt * v.w;
  }
  __syncthreads();
  for (int i = tid; i < 1024; i += 256)
    aggb[(size_t)b * 1024 + i] = f2bf(acc[0][i] + acc[1][i] + acc[2][i] + acc[3][i]);
}

// ---------------- transpose + convert f32 -> bf16 (for wv) ------------------
__global__ __launch_bounds__(256) void k_tcvt(const float* __restrict__ src,
                                              unsigned short* __restrict__ dst,
                                              int R, int C) {
  __shared__ float tile[64][65];
  const int br = blockIdx.x * 64;
  const int bc = blockIdx.y * 64;
  const int tid = threadIdx.x;
  for (int idx = tid; idx < 4096; idx += 256) {
    const int r = idx >> 6, c = idx & 63;
    tile[r][c] = src[(size_t)(br + r) * C + bc + c];
  }
  __syncthreads();
  for (int idx = tid; idx < 4096; idx += 256) {
    const int cc = idx >> 6, rr = idx & 63;
    dst[(size_t)(bc + cc) * R + br + rr] = f2bf(tile[rr][cc]);
  }
}

// ---------------- bf16 MFMA GEMM (final projection) -------------------------
template <int BM, int BN>
__global__ __launch_bounds__(256) void k_mfma(const unsigned short* __restrict__ A,
                                              const unsigned short* __restrict__ Bt,
                                              float* __restrict__ C,
                                              int M, int N, int K) {
  constexpr int FM = BM / 32;
  constexpr int FN = BN / 32;
  __shared__ float4 As[BM * 4];
  __shared__ float4 Bs[BN * 4];
  const int tid = threadIdx.x;
  const int lane = tid & 63;
  const int w = tid >> 6;
  const int wr = w >> 1, wc = w & 1;
  const int bm = blockIdx.x * BM, bn = blockIdx.y * BN;
  f32x4 acc[FM][FN];
#pragma unroll
  for (int i = 0; i < FM; ++i)
#pragma unroll
    for (int j = 0; j < FN; ++j) acc[i][j] = 0.f;

  for (int k0 = 0; k0 < K; k0 += 32) {
#pragma unroll
    for (int u = 0; u < BM * 4 / 256; ++u) {
      const int q = tid + u * 256;
      const int m = q >> 2, c = q & 3;
      As[(m >> 4) * 64 + c * 16 + (m & 15)] =
          *(const float4*)&A[(size_t)(bm + m) * K + k0 + c * 8];
    }
#pragma unroll
    for (int u = 0; u < BN * 4 / 256; ++u) {
      const int q = tid + u * 256;
      const int n = q >> 2, c = q & 3;
      Bs[(n >> 4) * 64 + c * 16 + (n & 15)] =
          *(const float4*)&Bt[(size_t)(bn + n) * K + k0 + c * 8];
    }
    __syncthreads();
    bf16x8 af[FM], bfr[FN];
#pragma unroll
    for (int i = 0; i < FM; ++i) af[i] = *(const bf16x8*)&As[(wr * FM + i) * 64 + lane];
#pragma unroll
    for (int j = 0; j < FN; ++j) bfr[j] = *(const bf16x8*)&Bs[(wc * FN + j) * 64 + lane];
#pragma unroll
    for (int i = 0; i < FM; ++i)
#pragma unroll
      for (int j = 0; j < FN; ++j)
        acc[i][j] = __builtin_amdgcn_mfma_f32_16x16x32_bf16(af[i], bfr[j], acc[i][j], 0, 0, 0);
    __syncthreads();
  }
#pragma unroll
  for (int i = 0; i < FM; ++i) {
    const int r0 = bm + (wr * FM + i) * 16 + (lane >> 4) * 4;
#pragma unroll
    for (int j = 0; j < FN; ++j) {
      const int cc = bn + (wc * FN + j) * 16 + (lane & 15);
#pragma unroll
      for (int v = 0; v < 4; ++v) C[(size_t)(r0 + v) * N + cc] = acc[i][j][v];
    }
  }
}

// ---------------------------------------------------------------------------
extern "C" void kernel_launch(void* const* d_in, const int* in_sizes, int n_in,
                              void* d_out, int out_size, void* d_ws, size_t ws_size,
                              hipStream_t stream) {
  const float* hidden = (const float*)d_in[0];
  const float* wq     = (const float*)d_in[1];
  const float* qnw    = (const float*)d_in[2];
  const float* knw    = (const float*)d_in[3];
  const float* keys   = (const float*)d_in[4];
  const float* tcore  = (const float*)d_in[5];
  const float* tu     = (const float*)d_in[6];
  const float* tv     = (const float*)d_in[7];
  const float* values = (const float*)d_in[8];
  const float* wvm    = (const float*)d_in[9];
  const int*   shuf   = (const int*)d_in[10];
  float* out = (float*)d_out;

  char* ws = (char*)d_ws;
  size_t off = 0;
  auto alloc = [&](size_t bytes) -> void* {
    void* p = ws + off;
    off += (bytes + 255) & ~(size_t)255;
    return p;
  };
  float* Bct  = (float*)alloc((size_t)4096 * 256 * 4);       //  4 MB
  float* Bg   = (float*)alloc((size_t)4096 * 512 * 4);       //  8 MB
  float* q12n = (float*)alloc((size_t)8192 * 256 * 4);       //  8 MB
  unsigned short* wvT  = (unsigned short*)alloc((size_t)2048 * 1024 * 2);  // 4 MB
  unsigned short* aggb = (unsigned short*)alloc((size_t)4096 * 1024 * 2);  // 8 MB
  int*   i1  = (int*)  alloc((size_t)8192 * 32 * 4);
  int*   i2  = (int*)  alloc((size_t)8192 * 32 * 4);
  float* g1  = (float*)alloc((size_t)8192 * 64 * 4);
  float* g2  = (float*)alloc((size_t)8192 * 64 * 4);
  float* wgt = (float*)alloc((size_t)8192 * 32 * 4);
  int*   sho = (int*)  alloc((size_t)8192 * 32 * 4);
  float* big = (float*)alloc((size_t)8192 * 2048 * 4);  // 64 MB shared region
  float* qpart = big;   // 4 x 4096 x 512 (32 MB), dead after k_ln_q
  float* s_r   = big;   // 8192 x 2048 (64 MB), written after
  (void)ws_size; (void)in_sizes; (void)n_in; (void)out_size;

  // 1) keys -> Bg (raw keysn) + Bct (u/v-combined), f32, k-contiguous
  k_prep32<<<4096, 64, 0, stream>>>(keys, knw, tu, tv, Bct, Bg);
  // 2) wv -> bf16 transposed
  k_tcvt<<<dim3(16, 32), 256, 0, stream>>>(wvm, wvT, 1024, 2048);
  // 3) q projection, f32 split-K=4 (B in natural [K][N] layout)
  k_gemm32<false, 4><<<dim3(32, 4, 4), 256, 0, stream>>>(
      hidden, wq, wq, 1 << 30, qpart, 4096, 512, 2048);
  // 4) sum partials + LN -> q12n
  k_ln_q<<<8192, 64, 0, stream>>>(qpart, qnw, q12n);
  // 5) fused score GEMM, f32: rows [0,4096)=side1 vs Bct1, [4096,8192) vs Bct2
  k_gemm32<true, 1><<<dim3(64, 16, 1), 256, 0, stream>>>(
      q12n, Bct, Bct + (size_t)2048 * 256, 4096, s_r, 8192, 2048, 256);
  // 6) stage-1 top-32 (both sides)
  k_topk1<<<16384, 64, 0, stream>>>(s_r, i1, i2);
  // 7) gather per-rank scores for selected keys
  k_gather<<<16384, 64, 0, stream>>>(q12n, Bg, i1, i2, g1, g2);
  // 8) stage-2 bilinear scores, top-32, softmax, shuffle
  k_stage2<<<8192, 64, 0, stream>>>(g1, g2, i1, i2, tcore, shuf, wgt, sho);
  // 9) weighted value gather -> bf16 agg
  k_agg<<<4096, 256, 0, stream>>>(wgt, sho, values, aggb);
  // 10) output projection (bf16 MFMA)
  k_mfma<128, 128><<<dim3(32, 16), 256, 0, stream>>>(aggb, wvT, out, 4096, 2048, 1024);
}

// Round 4
// 1754.424 us; speedup vs baseline: 2.6367x; 2.6367x over previous
//
#include <hip/hip_runtime.h>
#include <float.h>
#include <math.h>

// ---------------------------------------------------------------------------
// UltraMemLayerV1 — round 4: round-3 pipeline, spill fixed.
// Round-3 bug: __launch_bounds__(256,4) capped VGPRs at 64 -> acc[8][8]
// spilled to scratch -> 8.7 GB HBM traffic/dispatch, VALUBusy 2.6%.
// Fix: __launch_bounds__(256,2) (cap 256 VGPR; kernel needs ~130).
// ---------------------------------------------------------------------------

typedef __attribute__((ext_vector_type(8))) __bf16 bf16x8;
typedef __attribute__((ext_vector_type(4))) float f32x4;

__device__ __forceinline__ unsigned short f2bf(float x) {
  unsigned int u = __float_as_uint(x);
  return (unsigned short)((u + 0x7FFFu + ((u >> 16) & 1u)) >> 16);
}

__device__ __forceinline__ float wave_sum(float x) {
#pragma unroll
  for (int o = 32; o; o >>= 1) x += __shfl_xor(x, o, 64);
  return x;
}

// ---------------- keys prep: LN over d, fold knorm + tucker u/v -------------
__global__ void k_prep32(const float* __restrict__ keys, const float* __restrict__ knw,
                         const float* __restrict__ tu, const float* __restrict__ tv,
                         float* __restrict__ Bct, float* __restrict__ Bg) {
  const int bid = blockIdx.x;  // 4096 = c*2048 + h*1024 + k
  const int lane = threadIdx.x;
  const int k = bid & 1023, h = (bid >> 10) & 1, c = bid >> 11;
  const float* base = keys + (size_t)((h * 2 + c) * 1024 + k) * 512;  // (h,c,k,d,r)
  float x0[4], x1[4];
  float s0 = 0.f, s1 = 0.f, sq0 = 0.f, sq1 = 0.f;
#pragma unroll
  for (int i = 0; i < 4; ++i) {
    const int d = lane + i * 64;
    const float2 p = *(const float2*)&base[d * 2];
    x0[i] = p.x; x1[i] = p.y;
    s0 += p.x; sq0 += p.x * p.x;
    s1 += p.y; sq1 += p.y * p.y;
  }
  s0 = wave_sum(s0); sq0 = wave_sum(sq0);
  s1 = wave_sum(s1); sq1 = wave_sum(sq1);
  const float m0 = s0 * (1.f / 256.f), m1 = s1 * (1.f / 256.f);
  const float rs0 = 1.f / sqrtf(sq0 * (1.f / 256.f) - m0 * m0 + 1e-5f);
  const float rs1 = 1.f / sqrtf(sq1 * (1.f / 256.f) - m1 * m1 + 1e-5f);
  const float* uv = c ? tv : tu;
  const float u0 = uv[h * 2 + 0], u1 = uv[h * 2 + 1];
  const int chk = c * 2048 + h * 1024 + k;
  float* bg = Bg + (size_t)chk * 512;
  float* bc = Bct + (size_t)chk * 256;
#pragma unroll
  for (int i = 0; i < 4; ++i) {
    const int d = lane + i * 64;
    const float w = knw[d];
    const float y0 = (x0[i] - m0) * rs0 * w;
    const float y1 = (x1[i] - m1) * rs1 * w;
    bg[d] = y0;
    bg[256 + d] = y1;
    bc[d] = y0 * u0 + y1 * u1;
  }
}

// ---------------- tuned f32 GEMM: C = A[M][K] @ B^T (or B[K][N]) ------------
// 128x128 tile, BK=16, 256 threads (TM=TN=8 split in column halves),
// double-buffered LDS, one barrier per K-tile. B1_ used for rows >= m_split.
template <bool BT, int SPLITK>
__global__ __launch_bounds__(256, 2) void k_gemm32(
    const float* __restrict__ A, const float* __restrict__ B0,
    const float* __restrict__ B1_, int m_split,
    float* __restrict__ C, int M, int N, int K) {
  constexpr int BK = 16;
  __shared__ float As[2][BK][132];
  __shared__ float Bs[2][BK][132];
  const int tid = threadIdx.x;
  const int tx = tid & 15, ty = tid >> 4;
  const int bm = blockIdx.x * 128, bn = blockIdx.y * 128;
  const float* Bp = (bm >= m_split) ? B1_ : B0;
  const int Ks = K / SPLITK;
  const int kbeg = blockIdx.z * Ks;
  float* Cp = C + (size_t)blockIdx.z * M * N;
  float acc[8][8] = {};
  float4 ar[2], br[2];

  auto load = [&](int t) {
    const int k0 = kbeg + t * BK;
#pragma unroll
    for (int u = 0; u < 2; ++u) {
      const int q = tid + u * 256;
      const int m = q >> 2, kc = q & 3;
      ar[u] = *(const float4*)&A[(size_t)(bm + m) * K + k0 + kc * 4];
      if (BT) {
        br[u] = *(const float4*)&Bp[(size_t)(bn + m) * K + k0 + kc * 4];
      } else {
        const int kk = q >> 5, nq = q & 31;
        br[u] = *(const float4*)&Bp[(size_t)(k0 + kk) * N + bn + nq * 4];
      }
    }
  };
  auto store = [&](int buf) {
#pragma unroll
    for (int u = 0; u < 2; ++u) {
      const int q = tid + u * 256;
      const int m = q >> 2, kc = q & 3;
      As[buf][kc * 4 + 0][m] = ar[u].x;
      As[buf][kc * 4 + 1][m] = ar[u].y;
      As[buf][kc * 4 + 2][m] = ar[u].z;
      As[buf][kc * 4 + 3][m] = ar[u].w;
      if (BT) {
        Bs[buf][kc * 4 + 0][m] = br[u].x;
        Bs[buf][kc * 4 + 1][m] = br[u].y;
        Bs[buf][kc * 4 + 2][m] = br[u].z;
        Bs[buf][kc * 4 + 3][m] = br[u].w;
      } else {
        const int kk = q >> 5, nq = q & 31;
        *(float4*)&Bs[buf][kk][nq * 4] = br[u];
      }
    }
  };
  auto compute = [&](int buf) {
#pragma unroll
    for (int kk = 0; kk < BK; ++kk) {
      float a[8], b[8];
      *(float4*)&a[0] = *(const float4*)&As[buf][kk][ty * 4];
      *(float4*)&a[4] = *(const float4*)&As[buf][kk][64 + ty * 4];
      *(float4*)&b[0] = *(const float4*)&Bs[buf][kk][tx * 4];
      *(float4*)&b[4] = *(const float4*)&Bs[buf][kk][64 + tx * 4];
#pragma unroll
      for (int i = 0; i < 8; ++i)
#pragma unroll
        for (int j = 0; j < 8; ++j) acc[i][j] += a[i] * b[j];
    }
  };

  const int T = Ks / BK;
  load(0);
  store(0);
  __syncthreads();
  int cur = 0;
  for (int t = 0; t < T; ++t) {
    if (t + 1 < T) load(t + 1);
    compute(cur);
    if (t + 1 < T) {
      store(cur ^ 1);
      __syncthreads();
      cur ^= 1;
    }
  }
#pragma unroll
  for (int ih = 0; ih < 2; ++ih)
#pragma unroll
    for (int i = 0; i < 4; ++i) {
      const size_t r = bm + ih * 64 + ty * 4 + i;
#pragma unroll
      for (int jh = 0; jh < 2; ++jh) {
        float4 v = {acc[ih * 4 + i][jh * 4 + 0], acc[ih * 4 + i][jh * 4 + 1],
                    acc[ih * 4 + i][jh * 4 + 2], acc[ih * 4 + i][jh * 4 + 3]};
        *(float4*)&Cp[r * N + bn + jh * 64 + tx * 4] = v;
      }
    }
}

// ---------------- q: sum split-K partials + LN -> q12n ----------------------
__global__ void k_ln_q(const float* __restrict__ qpart, const float* __restrict__ qnw,
                       float* __restrict__ q12n) {
  const int bid = blockIdx.x;  // b*2 + c
  const int lane = threadIdx.x;
  const int b = bid >> 1, c = bid & 1;
  float x[4] = {};
#pragma unroll
  for (int s = 0; s < 4; ++s) {
    const float4 p = *(const float4*)&qpart[(size_t)s * 4096 * 512 + (size_t)b * 512 + c * 256 + lane * 4];
    x[0] += p.x; x[1] += p.y; x[2] += p.z; x[3] += p.w;
  }
  float sm = x[0] + x[1] + x[2] + x[3];
  float sq = x[0] * x[0] + x[1] * x[1] + x[2] * x[2] + x[3] * x[3];
  sm = wave_sum(sm);
  sq = wave_sum(sq);
  const float mean = sm * (1.f / 256.f);
  const float rs = 1.f / sqrtf(sq * (1.f / 256.f) - mean * mean + 1e-5f);
  const float4 w4 = *(const float4*)&qnw[lane * 4];
  float4 o;
  o.x = (x[0] - mean) * rs * w4.x;
  o.y = (x[1] - mean) * rs * w4.y;
  o.z = (x[2] - mean) * rs * w4.z;
  o.w = (x[3] - mean) * rs * w4.w;
  *(float4*)&q12n[(size_t)(c * 4096 + b) * 256 + lane * 4] = o;
}

// ---------------- stage-1 top-32 over 1024 combined scores ------------------
__global__ void k_topk1(const float* __restrict__ s_r,
                        int* __restrict__ i1, int* __restrict__ i2) {
  const int bid = blockIdx.x;  // side*8192 + b*2 + h
  const int side = bid >> 13;
  const int bh = bid & 8191;
  const int b = bh >> 1, h = bh & 1;
  const int lane = threadIdx.x;
  const float* row = s_r + (size_t)(side * 4096 + b) * 2048 + h * 1024;
  float sv[16];
#pragma unroll
  for (int i = 0; i < 16; ++i) sv[i] = row[lane + (i << 6)];
  int* iout = side ? i2 : i1;
  int win_k = 0;
  for (int it = 0; it < 32; ++it) {
    float bv = -FLT_MAX;
    int bk = 0x7FFFFFFF;
#pragma unroll
    for (int i = 0; i < 16; ++i) {
      const int kk = lane + (i << 6);
      if (sv[i] > bv || (sv[i] == bv && kk < bk)) { bv = sv[i]; bk = kk; }
    }
#pragma unroll
    for (int o = 32; o; o >>= 1) {
      const float ov = __shfl_xor(bv, o, 64);
      const int ok = __shfl_xor(bk, o, 64);
      if (ov > bv || (ov == bv && ok < bk)) { bv = ov; bk = ok; }
    }
    if ((bk & 63) == lane) sv[bk >> 6] = -FLT_MAX;
    if (lane == it) win_k = bk;
  }
  if (lane < 32) iout[bh * 32 + lane] = win_k;
}

// ---------------- gather per-rank scores for selected keys ------------------
__global__ void k_gather(const float* __restrict__ q12n, const float* __restrict__ Bg,
                         const int* __restrict__ i1, const int* __restrict__ i2,
                         float* __restrict__ g1, float* __restrict__ g2) {
  __shared__ float qs[256];
  const int bid = blockIdx.x;  // side*8192 + b*2 + h
  const int side = bid >> 13;
  const int bh = bid & 8191;
  const int b = bh >> 1, h = bh & 1;
  const int lane = threadIdx.x;
  const float* q = q12n + (size_t)(side * 4096 + b) * 256;
  *(float4*)&qs[lane * 4] = *(const float4*)&q[lane * 4];
  __syncthreads();
  const int j = lane >> 1, r = lane & 1;
  const int sel = (side ? i2 : i1)[bh * 32 + j];
  const float* krow = Bg + ((size_t)(side * 2048 + h * 1024 + sel) * 2 + r) * 256;
  float acc = 0.f;
#pragma unroll
  for (int d = 0; d < 256; d += 4) {
    const float4 kv = *(const float4*)&krow[d];
    const float4 qv = *(const float4*)&qs[d];
    acc += kv.x * qv.x + kv.y * qv.y + kv.z * qv.z + kv.w * qv.w;
  }
  (side ? g2 : g1)[(bh * 32 + j) * 2 + r] = acc;
}

// ---------------- stage-2: 32x32 bilinear scores, top-32, softmax -----------
__global__ void k_stage2(const float* __restrict__ g1, const float* __restrict__ g2,
                         const int* __restrict__ i1, const int* __restrict__ i2,
                         const float* __restrict__ tucker_core,
                         const int* __restrict__ shuffle_index,
                         float* __restrict__ w_out, int* __restrict__ sh_out) {
  __shared__ float sg1x[32], sg1y[32], sg2x[32], sg2y[32];
  __shared__ int si1[32], si2[32];
  const int bh = blockIdx.x;
  const int h = bh & 1;
  const int lane = threadIdx.x;
  if (lane < 32) {
    const float2 p1 = *(const float2*)&g1[(bh * 32 + lane) * 2];
    const float2 p2 = *(const float2*)&g2[(bh * 32 + lane) * 2];
    sg1x[lane] = p1.x;
    sg1y[lane] = p1.y;
    sg2x[lane] = p2.x;
    sg2y[lane] = p2.y;
    si1[lane] = i1[bh * 32 + lane];
    si2[lane] = i2[bh * 32 + lane];
  }
  __syncthreads();
  const float c00 = tucker_core[h * 4 + 0] + tucker_core[8 + h * 4 + 0];
  const float c01 = tucker_core[h * 4 + 1] + tucker_core[8 + h * 4 + 1];
  const float c10 = tucker_core[h * 4 + 2] + tucker_core[8 + h * 4 + 2];
  const float c11 = tucker_core[h * 4 + 3] + tucker_core[8 + h * 4 + 3];
  float sv[16];
#pragma unroll
  for (int i = 0; i < 16; ++i) {
    const int p = lane + (i << 6);
    const int k = p >> 5, l = p & 31;
    const float a0 = sg1x[k] * c00 + sg1y[k] * c10;
    const float a1 = sg1x[k] * c01 + sg1y[k] * c11;
    sv[i] = a0 * sg2x[l] + a1 * sg2y[l];
  }
  float m0 = 0.f, Z = 0.f, win_e = 0.f;
  int win_p = 0;
  for (int it = 0; it < 32; ++it) {
    float bv = -FLT_MAX;
    int bp = 0x7FFFFFFF;
#pragma unroll
    for (int i = 0; i < 16; ++i) {
      const int p = lane + (i << 6);
      if (sv[i] > bv || (sv[i] == bv && p < bp)) { bv = sv[i]; bp = p; }
    }
#pragma unroll
    for (int o = 32; o; o >>= 1) {
      const float ov = __shfl_xor(bv, o, 64);
      const int op = __shfl_xor(bp, o, 64);
      if (ov > bv || (ov == bv && op < bp)) { bv = ov; bp = op; }
    }
    if (it == 0) m0 = bv;
    const float e = expf(bv - m0);
    Z += e;
    if ((bp & 63) == lane) sv[bp >> 6] = -FLT_MAX;
    if (lane == it) { win_e = e; win_p = bp; }
  }
  if (lane < 32) {
    const int k = win_p >> 5, l = win_p & 31;
    const int ai = si1[k] * 1024 + si2[l];
    const int sh = shuffle_index[ai];  // = (eidx<<18) | vidx
    w_out[bh * 32 + lane] = win_e / Z;
    sh_out[bh * 32 + lane] = sh;
  }
}

// ---------------- weighted value gather/aggregate -> bf16 agg ---------------
__global__ __launch_bounds__(256) void k_agg(const float* __restrict__ w_out,
                                             const int* __restrict__ sh_out,
                                             const float* __restrict__ values,
                                             unsigned short* __restrict__ aggb) {
  __shared__ float acc[4][1024];
  const int b = blockIdx.x;
  const int tid = threadIdx.x;
  const int wave = tid >> 6, lane = tid & 63;
  for (int i = tid; i < 4096; i += 256) ((float*)acc)[i] = 0.f;
  __syncthreads();
  for (int j = wave; j < 64; j += 4) {
    const float wgt = w_out[b * 64 + j];
    const int sh = sh_out[b * 64 + j];
    const int vidx = sh & 0x3FFFF;
    const int e = sh >> 18;
    const float4 v = *(const float4*)&values[(size_t)vidx * 256 + lane * 4];
    float* dst = &acc[wave][e * 256 + lane * 4];
    dst[0] += wgt * v.x;
    dst[1] += wgt * v.y;
    dst[2] += wgt * v.z;
    dst[3] += wgt * v.w;
  }
  __syncthreads();
  for (int i = tid; i < 1024; i += 256)
    aggb[(size_t)b * 1024 + i] = f2bf(acc[0][i] + acc[1][i] + acc[2][i] + acc[3][i]);
}

// ---------------- transpose + convert f32 -> bf16 (for wv) ------------------
__global__ __launch_bounds__(256) void k_tcvt(const float* __restrict__ src,
                                              unsigned short* __restrict__ dst,
                                              int R, int C) {
  __shared__ float tile[64][65];
  const int br = blockIdx.x * 64;
  const int bc = blockIdx.y * 64;
  const int tid = threadIdx.x;
  for (int idx = tid; idx < 4096; idx += 256) {
    const int r = idx >> 6, c = idx & 63;
    tile[r][c] = src[(size_t)(br + r) * C + bc + c];
  }
  __syncthreads();
  for (int idx = tid; idx < 4096; idx += 256) {
    const int cc = idx >> 6, rr = idx & 63;
    dst[(size_t)(bc + cc) * R + br + rr] = f2bf(tile[rr][cc]);
  }
}

// ---------------- bf16 MFMA GEMM (final projection) -------------------------
template <int BM, int BN>
__global__ __launch_bounds__(256) void k_mfma(const unsigned short* __restrict__ A,
                                              const unsigned short* __restrict__ Bt,
                                              float* __restrict__ C,
                                              int M, int N, int K) {
  constexpr int FM = BM / 32;
  constexpr int FN = BN / 32;
  __shared__ float4 As[BM * 4];
  __shared__ float4 Bs[BN * 4];
  const int tid = threadIdx.x;
  const int lane = tid & 63;
  const int w = tid >> 6;
  const int wr = w >> 1, wc = w & 1;
  const int bm = blockIdx.x * BM, bn = blockIdx.y * BN;
  f32x4 acc[FM][FN];
#pragma unroll
  for (int i = 0; i < FM; ++i)
#pragma unroll
    for (int j = 0; j < FN; ++j) acc[i][j] = 0.f;

  for (int k0 = 0; k0 < K; k0 += 32) {
#pragma unroll
    for (int u = 0; u < BM * 4 / 256; ++u) {
      const int q = tid + u * 256;
      const int m = q >> 2, c = q & 3;
      As[(m >> 4) * 64 + c * 16 + (m & 15)] =
          *(const float4*)&A[(size_t)(bm + m) * K + k0 + c * 8];
    }
#pragma unroll
    for (int u = 0; u < BN * 4 / 256; ++u) {
      const int q = tid + u * 256;
      const int n = q >> 2, c = q & 3;
      Bs[(n >> 4) * 64 + c * 16 + (n & 15)] =
          *(const float4*)&Bt[(size_t)(bn + n) * K + k0 + c * 8];
    }
    __syncthreads();
    bf16x8 af[FM], bfr[FN];
#pragma unroll
    for (int i = 0; i < FM; ++i) af[i] = *(const bf16x8*)&As[(wr * FM + i) * 64 + lane];
#pragma unroll
    for (int j = 0; j < FN; ++j) bfr[j] = *(const bf16x8*)&Bs[(wc * FN + j) * 64 + lane];
#pragma unroll
    for (int i = 0; i < FM; ++i)
#pragma unroll
      for (int j = 0; j < FN; ++j)
        acc[i][j] = __builtin_amdgcn_mfma_f32_16x16x32_bf16(af[i], bfr[j], acc[i][j], 0, 0, 0);
    __syncthreads();
  }
#pragma unroll
  for (int i = 0; i < FM; ++i) {
    const int r0 = bm + (wr * FM + i) * 16 + (lane >> 4) * 4;
#pragma unroll
    for (int j = 0; j < FN; ++j) {
      const int cc = bn + (wc * FN + j) * 16 + (lane & 15);
#pragma unroll
      for (int v = 0; v < 4; ++v) C[(size_t)(r0 + v) * N + cc] = acc[i][j][v];
    }
  }
}

// ---------------------------------------------------------------------------
extern "C" void kernel_launch(void* const* d_in, const int* in_sizes, int n_in,
                              void* d_out, int out_size, void* d_ws, size_t ws_size,
                              hipStream_t stream) {
  const float* hidden = (const float*)d_in[0];
  const float* wq     = (const float*)d_in[1];
  const float* qnw    = (const float*)d_in[2];
  const float* knw    = (const float*)d_in[3];
  const float* keys   = (const float*)d_in[4];
  const float* tcore  = (const float*)d_in[5];
  const float* tu     = (const float*)d_in[6];
  const float* tv     = (const float*)d_in[7];
  const float* values = (const float*)d_in[8];
  const float* wvm    = (const float*)d_in[9];
  const int*   shuf   = (const int*)d_in[10];
  float* out = (float*)d_out;

  char* ws = (char*)d_ws;
  size_t off = 0;
  auto alloc = [&](size_t bytes) -> void* {
    void* p = ws + off;
    off += (bytes + 255) & ~(size_t)255;
    return p;
  };
  float* Bct  = (float*)alloc((size_t)4096 * 256 * 4);       //  4 MB
  float* Bg   = (float*)alloc((size_t)4096 * 512 * 4);       //  8 MB
  float* q12n = (float*)alloc((size_t)8192 * 256 * 4);       //  8 MB
  unsigned short* wvT  = (unsigned short*)alloc((size_t)2048 * 1024 * 2);  // 4 MB
  unsigned short* aggb = (unsigned short*)alloc((size_t)4096 * 1024 * 2);  // 8 MB
  int*   i1  = (int*)  alloc((size_t)8192 * 32 * 4);
  int*   i2  = (int*)  alloc((size_t)8192 * 32 * 4);
  float* g1  = (float*)alloc((size_t)8192 * 64 * 4);
  float* g2  = (float*)alloc((size_t)8192 * 64 * 4);
  float* wgt = (float*)alloc((size_t)8192 * 32 * 4);
  int*   sho = (int*)  alloc((size_t)8192 * 32 * 4);
  float* big = (float*)alloc((size_t)8192 * 2048 * 4);  // 64 MB shared region
  float* qpart = big;   // 4 x 4096 x 512 (32 MB), dead after k_ln_q
  float* s_r   = big;   // 8192 x 2048 (64 MB), written after
  (void)ws_size; (void)in_sizes; (void)n_in; (void)out_size;

  // 1) keys -> Bg (raw keysn) + Bct (u/v-combined), f32, k-contiguous
  k_prep32<<<4096, 64, 0, stream>>>(keys, knw, tu, tv, Bct, Bg);
  // 2) wv -> bf16 transposed
  k_tcvt<<<dim3(16, 32), 256, 0, stream>>>(wvm, wvT, 1024, 2048);
  // 3) q projection, f32 split-K=4 (B in natural [K][N] layout)
  k_gemm32<false, 4><<<dim3(32, 4, 4), 256, 0, stream>>>(
      hidden, wq, wq, 1 << 30, qpart, 4096, 512, 2048);
  // 4) sum partials + LN -> q12n
  k_ln_q<<<8192, 64, 0, stream>>>(qpart, qnw, q12n);
  // 5) fused score GEMM, f32: rows [0,4096)=side1 vs Bct1, [4096,8192) vs Bct2
  k_gemm32<true, 1><<<dim3(64, 16, 1), 256, 0, stream>>>(
      q12n, Bct, Bct + (size_t)2048 * 256, 4096, s_r, 8192, 2048, 256);
  // 6) stage-1 top-32 (both sides)
  k_topk1<<<16384, 64, 0, stream>>>(s_r, i1, i2);
  // 7) gather per-rank scores for selected keys
  k_gather<<<16384, 64, 0, stream>>>(q12n, Bg, i1, i2, g1, g2);
  // 8) stage-2 bilinear scores, top-32, softmax, shuffle
  k_stage2<<<8192, 64, 0, stream>>>(g1, g2, i1, i2, tcore, shuf, wgt, sho);
  // 9) weighted value gather -> bf16 agg
  k_agg<<<4096, 256, 0, stream>>>(wgt, sho, values, aggb);
  // 10) output projection (bf16 MFMA)
  k_mfma<128, 128><<<dim3(32, 16), 256, 0, stream>>>(aggb, wvT, out, 4096, 2048, 1024);
}

// Round 5
// 774.407 us; speedup vs baseline: 5.9735x; 2.2655x over previous
//
#include <hip/hip_runtime.h>
#include <float.h>
#include <math.h>

// ---------------------------------------------------------------------------
// UltraMemLayerV1 — round 5: f32 GEMM via global_load_lds (no VGPR staging).
// Round-4 diagnosis: reg-staged double-buffer (ar/br, 32 VGPRs) spilled ->
// 2.9 GB scratch traffic/dispatch, VALUBusy 10%. Fix: operands pre-transposed
// to [K][*]; async global->LDS (width 16), single-buffer, acc-only registers.
// ---------------------------------------------------------------------------

typedef __attribute__((ext_vector_type(8))) __bf16 bf16x8;
typedef __attribute__((ext_vector_type(4))) float f32x4;

__device__ __forceinline__ unsigned short f2bf(float x) {
  unsigned int u = __float_as_uint(x);
  return (unsigned short)((u + 0x7FFFu + ((u >> 16) & 1u)) >> 16);
}

__device__ __forceinline__ float wave_sum(float x) {
#pragma unroll
  for (int o = 32; o; o >>= 1) x += __shfl_xor(x, o, 64);
  return x;
}

__device__ __forceinline__ void gll16(const float* g, float* l) {
  __builtin_amdgcn_global_load_lds(
      (const __attribute__((address_space(1))) void*)g,
      (__attribute__((address_space(3))) void*)l, 16, 0, 0);
}

// ---------------- keys prep: LN over d, fold knorm + tucker u/v -------------
__global__ void k_prep32(const float* __restrict__ keys, const float* __restrict__ knw,
                         const float* __restrict__ tu, const float* __restrict__ tv,
                         float* __restrict__ Bct, float* __restrict__ Bg) {
  const int bid = blockIdx.x;  // 4096 = c*2048 + h*1024 + k
  const int lane = threadIdx.x;
  const int k = bid & 1023, h = (bid >> 10) & 1, c = bid >> 11;
  const float* base = keys + (size_t)((h * 2 + c) * 1024 + k) * 512;  // (h,c,k,d,r)
  float x0[4], x1[4];
  float s0 = 0.f, s1 = 0.f, sq0 = 0.f, sq1 = 0.f;
#pragma unroll
  for (int i = 0; i < 4; ++i) {
    const int d = lane + i * 64;
    const float2 p = *(const float2*)&base[d * 2];
    x0[i] = p.x; x1[i] = p.y;
    s0 += p.x; sq0 += p.x * p.x;
    s1 += p.y; sq1 += p.y * p.y;
  }
  s0 = wave_sum(s0); sq0 = wave_sum(sq0);
  s1 = wave_sum(s1); sq1 = wave_sum(sq1);
  const float m0 = s0 * (1.f / 256.f), m1 = s1 * (1.f / 256.f);
  const float rs0 = 1.f / sqrtf(sq0 * (1.f / 256.f) - m0 * m0 + 1e-5f);
  const float rs1 = 1.f / sqrtf(sq1 * (1.f / 256.f) - m1 * m1 + 1e-5f);
  const float* uv = c ? tv : tu;
  const float u0 = uv[h * 2 + 0], u1 = uv[h * 2 + 1];
  const int chk = c * 2048 + h * 1024 + k;
  float* bg = Bg + (size_t)chk * 512;
  float* bc = Bct + (size_t)chk * 256;
#pragma unroll
  for (int i = 0; i < 4; ++i) {
    const int d = lane + i * 64;
    const float w = knw[d];
    const float y0 = (x0[i] - m0) * rs0 * w;
    const float y1 = (x1[i] - m1) * rs1 * w;
    bg[d] = y0;
    bg[256 + d] = y1;
    bc[d] = y0 * u0 + y1 * u1;
  }
}

// ---------------- f32 transpose: src[R][C] -> dst[C][R] ---------------------
__global__ __launch_bounds__(256) void k_tr32(const float* __restrict__ src,
                                              float* __restrict__ dst, int R, int C) {
  __shared__ float t[64][65];
  const int br = blockIdx.x * 64, bc = blockIdx.y * 64;
  const int tid = threadIdx.x;
  for (int idx = tid; idx < 4096; idx += 256) {
    const int r = idx >> 6, c = idx & 63;
    t[r][c] = src[(size_t)(br + r) * C + bc + c];
  }
  __syncthreads();
  for (int idx = tid; idx < 4096; idx += 256) {
    const int cc = idx >> 6, rr = idx & 63;
    dst[(size_t)(bc + cc) * R + br + rr] = t[rr][cc];
  }
}

// ---------------- f32 GEMM, operands in [K][*] layout, async staging --------
// C[M][N] = AT^T @ BT-slice.  AT:[K][lda] (cols = M rows), BT:[K][ldb]
// (cols bcol..bcol+127 used; bcol = bn + (bm>=m_split ? bsk : 0)).
// 256 thr, 128x128 tile, BK=32, single-buffer LDS via global_load_lds.
template <int SPLITK>
__global__ __launch_bounds__(256) void k_gemm32(
    const float* __restrict__ AT, int lda,
    const float* __restrict__ BT, int ldb, int bsk, int m_split,
    float* __restrict__ C, int M, int N, int K) {
  constexpr int BK = 32;
  __shared__ float As[BK][128];
  __shared__ float Bs[BK][128];
  const int tid = threadIdx.x;
  const int lane = tid & 63;
  const int w = tid >> 6;
  const int tx = tid & 15, ty = tid >> 4;
  const int bm = blockIdx.x * 128, bn = blockIdx.y * 128;
  const int bcol = bn + ((bm >= m_split) ? bsk : 0);
  const int Ks = K / SPLITK;
  const int kbeg = blockIdx.z * Ks;
  float* Cp = C + (size_t)blockIdx.z * M * N;
  const int l5 = lane >> 5, l31 = lane & 31;
  float acc[8][8] = {};

  for (int k0 = 0; k0 < Ks; k0 += BK) {
    // stage A,B tiles: each wave issues 4+4 async 1KB copies (2 rows each)
#pragma unroll
    for (int i = 0; i < 4; ++i) {
      const int rr = w * 8 + i * 2;
      const size_t krow = (size_t)(kbeg + k0 + rr + l5);
      gll16(&AT[krow * lda + bm + l31 * 4], &As[rr][0]);
      gll16(&BT[krow * ldb + bcol + l31 * 4], &Bs[rr][0]);
    }
    __syncthreads();
#pragma unroll
    for (int kk = 0; kk < BK; ++kk) {
      float a[8], b[8];
      *(float4*)&a[0] = *(const float4*)&As[kk][ty * 4];
      *(float4*)&a[4] = *(const float4*)&As[kk][64 + ty * 4];
      *(float4*)&b[0] = *(const float4*)&Bs[kk][tx * 4];
      *(float4*)&b[4] = *(const float4*)&Bs[kk][64 + tx * 4];
#pragma unroll
      for (int i = 0; i < 8; ++i)
#pragma unroll
        for (int j = 0; j < 8; ++j) acc[i][j] += a[i] * b[j];
    }
    __syncthreads();
  }
#pragma unroll
  for (int ih = 0; ih < 2; ++ih)
#pragma unroll
    for (int i = 0; i < 4; ++i) {
      const size_t r = bm + ih * 64 + ty * 4 + i;
#pragma unroll
      for (int jh = 0; jh < 2; ++jh) {
        float4 v = {acc[ih * 4 + i][jh * 4 + 0], acc[ih * 4 + i][jh * 4 + 1],
                    acc[ih * 4 + i][jh * 4 + 2], acc[ih * 4 + i][jh * 4 + 3]};
        *(float4*)&Cp[r * N + bn + jh * 64 + tx * 4] = v;
      }
    }
}

// ---------------- q: sum split-K partials + LN -> q12n ----------------------
__global__ void k_ln_q(const float* __restrict__ qpart, const float* __restrict__ qnw,
                       float* __restrict__ q12n) {
  const int bid = blockIdx.x;  // b*2 + c
  const int lane = threadIdx.x;
  const int b = bid >> 1, c = bid & 1;
  float x[4] = {};
#pragma unroll
  for (int s = 0; s < 4; ++s) {
    const float4 p = *(const float4*)&qpart[(size_t)s * 4096 * 512 + (size_t)b * 512 + c * 256 + lane * 4];
    x[0] += p.x; x[1] += p.y; x[2] += p.z; x[3] += p.w;
  }
  float sm = x[0] + x[1] + x[2] + x[3];
  float sq = x[0] * x[0] + x[1] * x[1] + x[2] * x[2] + x[3] * x[3];
  sm = wave_sum(sm);
  sq = wave_sum(sq);
  const float mean = sm * (1.f / 256.f);
  const float rs = 1.f / sqrtf(sq * (1.f / 256.f) - mean * mean + 1e-5f);
  const float4 w4 = *(const float4*)&qnw[lane * 4];
  float4 o;
  o.x = (x[0] - mean) * rs * w4.x;
  o.y = (x[1] - mean) * rs * w4.y;
  o.z = (x[2] - mean) * rs * w4.z;
  o.w = (x[3] - mean) * rs * w4.w;
  *(float4*)&q12n[(size_t)(c * 4096 + b) * 256 + lane * 4] = o;
}

// ---------------- stage-1 top-32 over 1024 combined scores ------------------
__global__ void k_topk1(const float* __restrict__ s_r,
                        int* __restrict__ i1, int* __restrict__ i2) {
  const int bid = blockIdx.x;  // side*8192 + b*2 + h
  const int side = bid >> 13;
  const int bh = bid & 8191;
  const int b = bh >> 1, h = bh & 1;
  const int lane = threadIdx.x;
  const float* row = s_r + (size_t)(side * 4096 + b) * 2048 + h * 1024;
  float sv[16];
#pragma unroll
  for (int i = 0; i < 16; ++i) sv[i] = row[lane + (i << 6)];
  int* iout = side ? i2 : i1;
  int win_k = 0;
  for (int it = 0; it < 32; ++it) {
    float bv = -FLT_MAX;
    int bk = 0x7FFFFFFF;
#pragma unroll
    for (int i = 0; i < 16; ++i) {
      const int kk = lane + (i << 6);
      if (sv[i] > bv || (sv[i] == bv && kk < bk)) { bv = sv[i]; bk = kk; }
    }
#pragma unroll
    for (int o = 32; o; o >>= 1) {
      const float ov = __shfl_xor(bv, o, 64);
      const int ok = __shfl_xor(bk, o, 64);
      if (ov > bv || (ov == bv && ok < bk)) { bv = ov; bk = ok; }
    }
    if ((bk & 63) == lane) sv[bk >> 6] = -FLT_MAX;
    if (lane == it) win_k = bk;
  }
  if (lane < 32) iout[bh * 32 + lane] = win_k;
}

// ---------------- gather per-rank scores for selected keys ------------------
__global__ void k_gather(const float* __restrict__ q12n, const float* __restrict__ Bg,
                         const int* __restrict__ i1, const int* __restrict__ i2,
                         float* __restrict__ g1, float* __restrict__ g2) {
  __shared__ float qs[256];
  const int bid = blockIdx.x;  // side*8192 + b*2 + h
  const int side = bid >> 13;
  const int bh = bid & 8191;
  const int b = bh >> 1, h = bh & 1;
  const int lane = threadIdx.x;
  const float* q = q12n + (size_t)(side * 4096 + b) * 256;
  *(float4*)&qs[lane * 4] = *(const float4*)&q[lane * 4];
  __syncthreads();
  const int j = lane >> 1, r = lane & 1;
  const int sel = (side ? i2 : i1)[bh * 32 + j];
  const float* krow = Bg + ((size_t)(side * 2048 + h * 1024 + sel) * 2 + r) * 256;
  float acc = 0.f;
#pragma unroll
  for (int d = 0; d < 256; d += 4) {
    const float4 kv = *(const float4*)&krow[d];
    const float4 qv = *(const float4*)&qs[d];
    acc += kv.x * qv.x + kv.y * qv.y + kv.z * qv.z + kv.w * qv.w;
  }
  (side ? g2 : g1)[(bh * 32 + j) * 2 + r] = acc;
}

// ---------------- stage-2: 32x32 bilinear scores, top-32, softmax -----------
__global__ void k_stage2(const float* __restrict__ g1, const float* __restrict__ g2,
                         const int* __restrict__ i1, const int* __restrict__ i2,
                         const float* __restrict__ tucker_core,
                         const int* __restrict__ shuffle_index,
                         float* __restrict__ w_out, int* __restrict__ sh_out) {
  __shared__ float sg1x[32], sg1y[32], sg2x[32], sg2y[32];
  __shared__ int si1[32], si2[32];
  const int bh = blockIdx.x;
  const int h = bh & 1;
  const int lane = threadIdx.x;
  if (lane < 32) {
    const float2 p1 = *(const float2*)&g1[(bh * 32 + lane) * 2];
    const float2 p2 = *(const float2*)&g2[(bh * 32 + lane) * 2];
    sg1x[lane] = p1.x;
    sg1y[lane] = p1.y;
    sg2x[lane] = p2.x;
    sg2y[lane] = p2.y;
    si1[lane] = i1[bh * 32 + lane];
    si2[lane] = i2[bh * 32 + lane];
  }
  __syncthreads();
  const float c00 = tucker_core[h * 4 + 0] + tucker_core[8 + h * 4 + 0];
  const float c01 = tucker_core[h * 4 + 1] + tucker_core[8 + h * 4 + 1];
  const float c10 = tucker_core[h * 4 + 2] + tucker_core[8 + h * 4 + 2];
  const float c11 = tucker_core[h * 4 + 3] + tucker_core[8 + h * 4 + 3];
  float sv[16];
#pragma unroll
  for (int i = 0; i < 16; ++i) {
    const int p = lane + (i << 6);
    const int k = p >> 5, l = p & 31;
    const float a0 = sg1x[k] * c00 + sg1y[k] * c10;
    const float a1 = sg1x[k] * c01 + sg1y[k] * c11;
    sv[i] = a0 * sg2x[l] + a1 * sg2y[l];
  }
  float m0 = 0.f, Z = 0.f, win_e = 0.f;
  int win_p = 0;
  for (int it = 0; it < 32; ++it) {
    float bv = -FLT_MAX;
    int bp = 0x7FFFFFFF;
#pragma unroll
    for (int i = 0; i < 16; ++i) {
      const int p = lane + (i << 6);
      if (sv[i] > bv || (sv[i] == bv && p < bp)) { bv = sv[i]; bp = p; }
    }
#pragma unroll
    for (int o = 32; o; o >>= 1) {
      const float ov = __shfl_xor(bv, o, 64);
      const int op = __shfl_xor(bp, o, 64);
      if (ov > bv || (ov == bv && op < bp)) { bv = ov; bp = op; }
    }
    if (it == 0) m0 = bv;
    const float e = expf(bv - m0);
    Z += e;
    if ((bp & 63) == lane) sv[bp >> 6] = -FLT_MAX;
    if (lane == it) { win_e = e; win_p = bp; }
  }
  if (lane < 32) {
    const int k = win_p >> 5, l = win_p & 31;
    const int ai = si1[k] * 1024 + si2[l];
    const int sh = shuffle_index[ai];  // = (eidx<<18) | vidx
    w_out[bh * 32 + lane] = win_e / Z;
    sh_out[bh * 32 + lane] = sh;
  }
}

// ---------------- weighted value gather/aggregate -> bf16 agg ---------------
__global__ __launch_bounds__(256) void k_agg(const float* __restrict__ w_out,
                                             const int* __restrict__ sh_out,
                                             const float* __restrict__ values,
                                             unsigned short* __restrict__ aggb) {
  __shared__ float acc[4][1024];
  const int b = blockIdx.x;
  const int tid = threadIdx.x;
  const int wave = tid >> 6, lane = tid & 63;
  for (int i = tid; i < 4096; i += 256) ((float*)acc)[i] = 0.f;
  __syncthreads();
  for (int j = wave; j < 64; j += 4) {
    const float wgt = w_out[b * 64 + j];
    const int sh = sh_out[b * 64 + j];
    const int vidx = sh & 0x3FFFF;
    const int e = sh >> 18;
    const float4 v = *(const float4*)&values[(size_t)vidx * 256 + lane * 4];
    float* dst = &acc[wave][e * 256 + lane * 4];
    dst[0] += wgt * v.x;
    dst[1] += wgt * v.y;
    dst[2] += wgt * v.z;
    dst[3] += wgt * v.w;
  }
  __syncthreads();
  for (int i = tid; i < 1024; i += 256)
    aggb[(size_t)b * 1024 + i] = f2bf(acc[0][i] + acc[1][i] + acc[2][i] + acc[3][i]);
}

// ---------------- transpose + convert f32 -> bf16 (for wv) ------------------
__global__ __launch_bounds__(256) void k_tcvt(const float* __restrict__ src,
                                              unsigned short* __restrict__ dst,
                                              int R, int C) {
  __shared__ float tile[64][65];
  const int br = blockIdx.x * 64;
  const int bc = blockIdx.y * 64;
  const int tid = threadIdx.x;
  for (int idx = tid; idx < 4096; idx += 256) {
    const int r = idx >> 6, c = idx & 63;
    tile[r][c] = src[(size_t)(br + r) * C + bc + c];
  }
  __syncthreads();
  for (int idx = tid; idx < 4096; idx += 256) {
    const int cc = idx >> 6, rr = idx & 63;
    dst[(size_t)(bc + cc) * R + br + rr] = f2bf(tile[rr][cc]);
  }
}

// ---------------- bf16 MFMA GEMM (final projection) -------------------------
template <int BM, int BN>
__global__ __launch_bounds__(256) void k_mfma(const unsigned short* __restrict__ A,
                                              const unsigned short* __restrict__ Bt,
                                              float* __restrict__ C,
                                              int M, int N, int K) {
  constexpr int FM = BM / 32;
  constexpr int FN = BN / 32;
  __shared__ float4 As[BM * 4];
  __shared__ float4 Bs[BN * 4];
  const int tid = threadIdx.x;
  const int lane = tid & 63;
  const int w = tid >> 6;
  const int wr = w >> 1, wc = w & 1;
  const int bm = blockIdx.x * BM, bn = blockIdx.y * BN;
  f32x4 acc[FM][FN];
#pragma unroll
  for (int i = 0; i < FM; ++i)
#pragma unroll
    for (int j = 0; j < FN; ++j) acc[i][j] = 0.f;

  for (int k0 = 0; k0 < K; k0 += 32) {
#pragma unroll
    for (int u = 0; u < BM * 4 / 256; ++u) {
      const int q = tid + u * 256;
      const int m = q >> 2, c = q & 3;
      As[(m >> 4) * 64 + c * 16 + (m & 15)] =
          *(const float4*)&A[(size_t)(bm + m) * K + k0 + c * 8];
    }
#pragma unroll
    for (int u = 0; u < BN * 4 / 256; ++u) {
      const int q = tid + u * 256;
      const int n = q >> 2, c = q & 3;
      Bs[(n >> 4) * 64 + c * 16 + (n & 15)] =
          *(const float4*)&Bt[(size_t)(bn + n) * K + k0 + c * 8];
    }
    __syncthreads();
    bf16x8 af[FM], bfr[FN];
#pragma unroll
    for (int i = 0; i < FM; ++i) af[i] = *(const bf16x8*)&As[(wr * FM + i) * 64 + lane];
#pragma unroll
    for (int j = 0; j < FN; ++j) bfr[j] = *(const bf16x8*)&Bs[(wc * FN + j) * 64 + lane];
#pragma unroll
    for (int i = 0; i < FM; ++i)
#pragma unroll
      for (int j = 0; j < FN; ++j)
        acc[i][j] = __builtin_amdgcn_mfma_f32_16x16x32_bf16(af[i], bfr[j], acc[i][j], 0, 0, 0);
    __syncthreads();
  }
#pragma unroll
  for (int i = 0; i < FM; ++i) {
    const int r0 = bm + (wr * FM + i) * 16 + (lane >> 4) * 4;
#pragma unroll
    for (int j = 0; j < FN; ++j) {
      const int cc = bn + (wc * FN + j) * 16 + (lane & 15);
#pragma unroll
      for (int v = 0; v < 4; ++v) C[(size_t)(r0 + v) * N + cc] = acc[i][j][v];
    }
  }
}

// ---------------------------------------------------------------------------
extern "C" void kernel_launch(void* const* d_in, const int* in_sizes, int n_in,
                              void* d_out, int out_size, void* d_ws, size_t ws_size,
                              hipStream_t stream) {
  const float* hidden = (const float*)d_in[0];
  const float* wq     = (const float*)d_in[1];
  const float* qnw    = (const float*)d_in[2];
  const float* knw    = (const float*)d_in[3];
  const float* keys   = (const float*)d_in[4];
  const float* tcore  = (const float*)d_in[5];
  const float* tu     = (const float*)d_in[6];
  const float* tv     = (const float*)d_in[7];
  const float* values = (const float*)d_in[8];
  const float* wvm    = (const float*)d_in[9];
  const int*   shuf   = (const int*)d_in[10];
  float* out = (float*)d_out;

  char* ws = (char*)d_ws;
  size_t off = 0;
  auto alloc = [&](size_t bytes) -> void* {
    void* p = ws + off;
    off += (bytes + 255) & ~(size_t)255;
    return p;
  };
  float* Bct   = (float*)alloc((size_t)4096 * 256 * 4);      //  4 MB
  float* BctT  = (float*)alloc((size_t)256 * 4096 * 4);      //  4 MB
  float* Bg    = (float*)alloc((size_t)4096 * 512 * 4);      //  8 MB
  float* q12n  = (float*)alloc((size_t)8192 * 256 * 4);      //  8 MB
  float* q12nT = (float*)alloc((size_t)256 * 8192 * 4);      //  8 MB
  unsigned short* wvT  = (unsigned short*)alloc((size_t)2048 * 1024 * 2);  // 4 MB
  unsigned short* aggb = (unsigned short*)alloc((size_t)4096 * 1024 * 2);  // 8 MB
  int*   i1  = (int*)  alloc((size_t)8192 * 32 * 4);
  int*   i2  = (int*)  alloc((size_t)8192 * 32 * 4);
  float* g1  = (float*)alloc((size_t)8192 * 64 * 4);
  float* g2  = (float*)alloc((size_t)8192 * 64 * 4);
  float* wgt = (float*)alloc((size_t)8192 * 32 * 4);
  int*   sho = (int*)  alloc((size_t)8192 * 32 * 4);
  float* big = (float*)alloc((size_t)8192 * 2048 * 4);  // 64 MB shared region
  float* qpart   = big;                          // 4 x 4096 x 512 (32 MB)
  float* hiddenT = big + (size_t)8 * 1024 * 1024;  // 2048 x 4096 (32 MB)
  float* s_r     = big;                          // 8192 x 2048 (64 MB), later
  (void)ws_size; (void)in_sizes; (void)n_in; (void)out_size;

  // 1) keys -> Bg (raw keysn) + Bct (u/v-combined)
  k_prep32<<<4096, 64, 0, stream>>>(keys, knw, tu, tv, Bct, Bg);
  // 2) wv -> bf16 transposed; Bct -> BctT; hidden -> hiddenT
  k_tcvt<<<dim3(16, 32), 256, 0, stream>>>(wvm, wvT, 1024, 2048);
  k_tr32<<<dim3(64, 4), 256, 0, stream>>>(Bct, BctT, 4096, 256);
  k_tr32<<<dim3(64, 32), 256, 0, stream>>>(hidden, hiddenT, 4096, 2048);
  // 3) q projection, f32 split-K=4: qpart[z] = hiddenT^T @ wq (K-slice z)
  k_gemm32<4><<<dim3(32, 4, 4), 256, 0, stream>>>(
      hiddenT, 4096, wq, 512, 0, 1 << 30, qpart, 4096, 512, 2048);
  // 4) sum partials + LN -> q12n; transpose
  k_ln_q<<<8192, 64, 0, stream>>>(qpart, qnw, q12n);
  k_tr32<<<dim3(128, 4), 256, 0, stream>>>(q12n, q12nT, 8192, 256);
  // 5) fused score GEMM: rows [0,4096)=side1 (B cols 0..2047),
  //    rows [4096,8192)=side2 (B cols 2048..4095)
  k_gemm32<1><<<dim3(64, 16, 1), 256, 0, stream>>>(
      q12nT, 8192, BctT, 4096, 2048, 4096, s_r, 8192, 2048, 256);
  // 6) stage-1 top-32 (both sides)
  k_topk1<<<16384, 64, 0, stream>>>(s_r, i1, i2);
  // 7) gather per-rank scores for selected keys
  k_gather<<<16384, 64, 0, stream>>>(q12n, Bg, i1, i2, g1, g2);
  // 8) stage-2 bilinear scores, top-32, softmax, shuffle
  k_stage2<<<8192, 64, 0, stream>>>(g1, g2, i1, i2, tcore, shuf, wgt, sho);
  // 9) weighted value gather -> bf16 agg
  k_agg<<<4096, 256, 0, stream>>>(wgt, sho, values, aggb);
  // 10) output projection (bf16 MFMA)
  k_mfma<128, 128><<<dim3(32, 16), 256, 0, stream>>>(aggb, wvT, out, 4096, 2048, 1024);
}

// Round 6
// 638.862 us; speedup vs baseline: 7.2409x; 1.2122x over previous
//
#include <hip/hip_runtime.h>
#include <float.h>
#include <math.h>

// ---------------------------------------------------------------------------
// UltraMemLayerV1 — round 6: bisection top-k (stage 1).
// Round-5 profile: k_topk1 = 205 us, VALU-issue-bound (iterative 32-round
// extraction ~6000 insts/wave). Downstream needs only the top-32 SET, so:
// exact 32-step radix bisection for the 32nd-largest monotone-u32 key +
// deterministic prefix-compaction emission (~1700 insts/wave).
// All other kernels identical to the passing round 5.
// ---------------------------------------------------------------------------

typedef __attribute__((ext_vector_type(8))) __bf16 bf16x8;
typedef __attribute__((ext_vector_type(4))) float f32x4;

__device__ __forceinline__ unsigned short f2bf(float x) {
  unsigned int u = __float_as_uint(x);
  return (unsigned short)((u + 0x7FFFu + ((u >> 16) & 1u)) >> 16);
}

__device__ __forceinline__ float wave_sum(float x) {
#pragma unroll
  for (int o = 32; o; o >>= 1) x += __shfl_xor(x, o, 64);
  return x;
}

__device__ __forceinline__ void gll16(const float* g, float* l) {
  __builtin_amdgcn_global_load_lds(
      (const __attribute__((address_space(1))) void*)g,
      (__attribute__((address_space(3))) void*)l, 16, 0, 0);
}

// ---------------- keys prep: LN over d, fold knorm + tucker u/v -------------
__global__ void k_prep32(const float* __restrict__ keys, const float* __restrict__ knw,
                         const float* __restrict__ tu, const float* __restrict__ tv,
                         float* __restrict__ Bct, float* __restrict__ Bg) {
  const int bid = blockIdx.x;  // 4096 = c*2048 + h*1024 + k
  const int lane = threadIdx.x;
  const int k = bid & 1023, h = (bid >> 10) & 1, c = bid >> 11;
  const float* base = keys + (size_t)((h * 2 + c) * 1024 + k) * 512;  // (h,c,k,d,r)
  float x0[4], x1[4];
  float s0 = 0.f, s1 = 0.f, sq0 = 0.f, sq1 = 0.f;
#pragma unroll
  for (int i = 0; i < 4; ++i) {
    const int d = lane + i * 64;
    const float2 p = *(const float2*)&base[d * 2];
    x0[i] = p.x; x1[i] = p.y;
    s0 += p.x; sq0 += p.x * p.x;
    s1 += p.y; sq1 += p.y * p.y;
  }
  s0 = wave_sum(s0); sq0 = wave_sum(sq0);
  s1 = wave_sum(s1); sq1 = wave_sum(sq1);
  const float m0 = s0 * (1.f / 256.f), m1 = s1 * (1.f / 256.f);
  const float rs0 = 1.f / sqrtf(sq0 * (1.f / 256.f) - m0 * m0 + 1e-5f);
  const float rs1 = 1.f / sqrtf(sq1 * (1.f / 256.f) - m1 * m1 + 1e-5f);
  const float* uv = c ? tv : tu;
  const float u0 = uv[h * 2 + 0], u1 = uv[h * 2 + 1];
  const int chk = c * 2048 + h * 1024 + k;
  float* bg = Bg + (size_t)chk * 512;
  float* bc = Bct + (size_t)chk * 256;
#pragma unroll
  for (int i = 0; i < 4; ++i) {
    const int d = lane + i * 64;
    const float w = knw[d];
    const float y0 = (x0[i] - m0) * rs0 * w;
    const float y1 = (x1[i] - m1) * rs1 * w;
    bg[d] = y0;
    bg[256 + d] = y1;
    bc[d] = y0 * u0 + y1 * u1;
  }
}

// ---------------- f32 transpose: src[R][C] -> dst[C][R] ---------------------
__global__ __launch_bounds__(256) void k_tr32(const float* __restrict__ src,
                                              float* __restrict__ dst, int R, int C) {
  __shared__ float t[64][65];
  const int br = blockIdx.x * 64, bc = blockIdx.y * 64;
  const int tid = threadIdx.x;
  for (int idx = tid; idx < 4096; idx += 256) {
    const int r = idx >> 6, c = idx & 63;
    t[r][c] = src[(size_t)(br + r) * C + bc + c];
  }
  __syncthreads();
  for (int idx = tid; idx < 4096; idx += 256) {
    const int cc = idx >> 6, rr = idx & 63;
    dst[(size_t)(bc + cc) * R + br + rr] = t[rr][cc];
  }
}

// ---------------- f32 GEMM, operands in [K][*] layout, async staging --------
template <int SPLITK>
__global__ __launch_bounds__(256) void k_gemm32(
    const float* __restrict__ AT, int lda,
    const float* __restrict__ BT, int ldb, int bsk, int m_split,
    float* __restrict__ C, int M, int N, int K) {
  constexpr int BK = 32;
  __shared__ float As[BK][128];
  __shared__ float Bs[BK][128];
  const int tid = threadIdx.x;
  const int lane = tid & 63;
  const int w = tid >> 6;
  const int tx = tid & 15, ty = tid >> 4;
  const int bm = blockIdx.x * 128, bn = blockIdx.y * 128;
  const int bcol = bn + ((bm >= m_split) ? bsk : 0);
  const int Ks = K / SPLITK;
  const int kbeg = blockIdx.z * Ks;
  float* Cp = C + (size_t)blockIdx.z * M * N;
  const int l5 = lane >> 5, l31 = lane & 31;
  float acc[8][8] = {};

  for (int k0 = 0; k0 < Ks; k0 += BK) {
#pragma unroll
    for (int i = 0; i < 4; ++i) {
      const int rr = w * 8 + i * 2;
      const size_t krow = (size_t)(kbeg + k0 + rr + l5);
      gll16(&AT[krow * lda + bm + l31 * 4], &As[rr][0]);
      gll16(&BT[krow * ldb + bcol + l31 * 4], &Bs[rr][0]);
    }
    __syncthreads();
#pragma unroll
    for (int kk = 0; kk < BK; ++kk) {
      float a[8], b[8];
      *(float4*)&a[0] = *(const float4*)&As[kk][ty * 4];
      *(float4*)&a[4] = *(const float4*)&As[kk][64 + ty * 4];
      *(float4*)&b[0] = *(const float4*)&Bs[kk][tx * 4];
      *(float4*)&b[4] = *(const float4*)&Bs[kk][64 + tx * 4];
#pragma unroll
      for (int i = 0; i < 8; ++i)
#pragma unroll
        for (int j = 0; j < 8; ++j) acc[i][j] += a[i] * b[j];
    }
    __syncthreads();
  }
#pragma unroll
  for (int ih = 0; ih < 2; ++ih)
#pragma unroll
    for (int i = 0; i < 4; ++i) {
      const size_t r = bm + ih * 64 + ty * 4 + i;
#pragma unroll
      for (int jh = 0; jh < 2; ++jh) {
        float4 v = {acc[ih * 4 + i][jh * 4 + 0], acc[ih * 4 + i][jh * 4 + 1],
                    acc[ih * 4 + i][jh * 4 + 2], acc[ih * 4 + i][jh * 4 + 3]};
        *(float4*)&Cp[r * N + bn + jh * 64 + tx * 4] = v;
      }
    }
}

// ---------------- q: sum split-K partials + LN -> q12n ----------------------
__global__ void k_ln_q(const float* __restrict__ qpart, const float* __restrict__ qnw,
                       float* __restrict__ q12n) {
  const int bid = blockIdx.x;  // b*2 + c
  const int lane = threadIdx.x;
  const int b = bid >> 1, c = bid & 1;
  float x[4] = {};
#pragma unroll
  for (int s = 0; s < 4; ++s) {
    const float4 p = *(const float4*)&qpart[(size_t)s * 4096 * 512 + (size_t)b * 512 + c * 256 + lane * 4];
    x[0] += p.x; x[1] += p.y; x[2] += p.z; x[3] += p.w;
  }
  float sm = x[0] + x[1] + x[2] + x[3];
  float sq = x[0] * x[0] + x[1] * x[1] + x[2] * x[2] + x[3] * x[3];
  sm = wave_sum(sm);
  sq = wave_sum(sq);
  const float mean = sm * (1.f / 256.f);
  const float rs = 1.f / sqrtf(sq * (1.f / 256.f) - mean * mean + 1e-5f);
  const float4 w4 = *(const float4*)&qnw[lane * 4];
  float4 o;
  o.x = (x[0] - mean) * rs * w4.x;
  o.y = (x[1] - mean) * rs * w4.y;
  o.z = (x[2] - mean) * rs * w4.z;
  o.w = (x[3] - mean) * rs * w4.w;
  *(float4*)&q12n[(size_t)(c * 4096 + b) * 256 + lane * 4] = o;
}

// ---------------- stage-1 top-32 via exact radix bisection ------------------
// Downstream consumes i1/i2 as SETS (stage-2 re-scores the 32x32 grid), so
// ordered extraction is unnecessary. Find T = 32nd-largest monotone-u32 key
// exactly (32 bisection steps, wave-uniform), then emit {key>T} plus the
// first (32 - cnt_gt) of {key==T} in fixed (slot,lane) order. Deterministic.
__global__ void k_topk1(const float* __restrict__ s_r,
                        int* __restrict__ i1, int* __restrict__ i2) {
  const int bid = blockIdx.x;  // side*8192 + b*2 + h
  const int side = bid >> 13;
  const int bh = bid & 8191;
  const int b = bh >> 1, h = bh & 1;
  const int lane = threadIdx.x;
  const float* row = s_r + (size_t)(side * 4096 + b) * 2048 + h * 1024;
  // monotone key: neg -> ~bits, pos -> bits|0x80000000 (order-preserving)
  unsigned int ku[16];
#pragma unroll
  for (int i = 0; i < 16; ++i) {
    const unsigned int u = __float_as_uint(row[lane + (i << 6)]);
    ku[i] = u ^ (((unsigned int)((int)u >> 31)) | 0x80000000u);
  }
  // bisection for T = 32nd largest key (largest t with count(>=t) >= 32)
  unsigned int T = 0u;
  for (int bpos = 31; bpos >= 0; --bpos) {
    const unsigned int cand = T | (1u << bpos);
    int c = 0;
#pragma unroll
    for (int i = 0; i < 16; ++i) c += (ku[i] >= cand) ? 1 : 0;
#pragma unroll
    for (int o = 32; o; o >>= 1) c += __shfl_xor(c, o, 64);
    if (c >= 32) T = cand;  // c is wave-uniform -> no divergence
  }
  // counts and wave-wide exclusive prefixes (deterministic compaction)
  int cgt = 0, ceq = 0;
#pragma unroll
  for (int i = 0; i < 16; ++i) {
    cgt += (ku[i] > T) ? 1 : 0;
    ceq += (ku[i] == T) ? 1 : 0;
  }
  int pgt = cgt, peq = ceq;
#pragma unroll
  for (int o = 1; o < 64; o <<= 1) {
    const int t1 = __shfl_up(pgt, o, 64);
    const int t2 = __shfl_up(peq, o, 64);
    if (lane >= o) { pgt += t1; peq += t2; }
  }
  const int total_gt = __shfl(pgt, 63, 64);  // < 32
  const int need_eq = 32 - total_gt;         // >= 1
  int sgt = pgt - cgt;       // my exclusive prefix among >T
  int seq = peq - ceq;       // my exclusive prefix among ==T
  int* iout = (side ? i2 : i1) + bh * 32;
#pragma unroll
  for (int i = 0; i < 16; ++i) {
    const int idx = (i << 6) + lane;
    if (ku[i] > T) {
      iout[sgt++] = idx;
    } else if (ku[i] == T) {
      if (seq < need_eq) iout[total_gt + seq] = idx;
      ++seq;
    }
  }
}

// ---------------- gather per-rank scores for selected keys ------------------
__global__ void k_gather(const float* __restrict__ q12n, const float* __restrict__ Bg,
                         const int* __restrict__ i1, const int* __restrict__ i2,
                         float* __restrict__ g1, float* __restrict__ g2) {
  __shared__ float qs[256];
  const int bid = blockIdx.x;  // side*8192 + b*2 + h
  const int side = bid >> 13;
  const int bh = bid & 8191;
  const int b = bh >> 1, h = bh & 1;
  const int lane = threadIdx.x;
  const float* q = q12n + (size_t)(side * 4096 + b) * 256;
  *(float4*)&qs[lane * 4] = *(const float4*)&q[lane * 4];
  __syncthreads();
  const int j = lane >> 1, r = lane & 1;
  const int sel = (side ? i2 : i1)[bh * 32 + j];
  const float* krow = Bg + ((size_t)(side * 2048 + h * 1024 + sel) * 2 + r) * 256;
  float acc = 0.f;
#pragma unroll
  for (int d = 0; d < 256; d += 4) {
    const float4 kv = *(const float4*)&krow[d];
    const float4 qv = *(const float4*)&qs[d];
    acc += kv.x * qv.x + kv.y * qv.y + kv.z * qv.z + kv.w * qv.w;
  }
  (side ? g2 : g1)[(bh * 32 + j) * 2 + r] = acc;
}

// ---------------- stage-2: 32x32 bilinear scores, top-32, softmax -----------
__global__ void k_stage2(const float* __restrict__ g1, const float* __restrict__ g2,
                         const int* __restrict__ i1, const int* __restrict__ i2,
                         const float* __restrict__ tucker_core,
                         const int* __restrict__ shuffle_index,
                         float* __restrict__ w_out, int* __restrict__ sh_out) {
  __shared__ float sg1x[32], sg1y[32], sg2x[32], sg2y[32];
  __shared__ int si1[32], si2[32];
  const int bh = blockIdx.x;
  const int h = bh & 1;
  const int lane = threadIdx.x;
  if (lane < 32) {
    const float2 p1 = *(const float2*)&g1[(bh * 32 + lane) * 2];
    const float2 p2 = *(const float2*)&g2[(bh * 32 + lane) * 2];
    sg1x[lane] = p1.x;
    sg1y[lane] = p1.y;
    sg2x[lane] = p2.x;
    sg2y[lane] = p2.y;
    si1[lane] = i1[bh * 32 + lane];
    si2[lane] = i2[bh * 32 + lane];
  }
  __syncthreads();
  const float c00 = tucker_core[h * 4 + 0] + tucker_core[8 + h * 4 + 0];
  const float c01 = tucker_core[h * 4 + 1] + tucker_core[8 + h * 4 + 1];
  const float c10 = tucker_core[h * 4 + 2] + tucker_core[8 + h * 4 + 2];
  const float c11 = tucker_core[h * 4 + 3] + tucker_core[8 + h * 4 + 3];
  float sv[16];
#pragma unroll
  for (int i = 0; i < 16; ++i) {
    const int p = lane + (i << 6);
    const int k = p >> 5, l = p & 31;
    const float a0 = sg1x[k] * c00 + sg1y[k] * c10;
    const float a1 = sg1x[k] * c01 + sg1y[k] * c11;
    sv[i] = a0 * sg2x[l] + a1 * sg2y[l];
  }
  float m0 = 0.f, Z = 0.f, win_e = 0.f;
  int win_p = 0;
  for (int it = 0; it < 32; ++it) {
    float bv = -FLT_MAX;
    int bp = 0x7FFFFFFF;
#pragma unroll
    for (int i = 0; i < 16; ++i) {
      const int p = lane + (i << 6);
      if (sv[i] > bv || (sv[i] == bv && p < bp)) { bv = sv[i]; bp = p; }
    }
#pragma unroll
    for (int o = 32; o; o >>= 1) {
      const float ov = __shfl_xor(bv, o, 64);
      const int op = __shfl_xor(bp, o, 64);
      if (ov > bv || (ov == bv && op < bp)) { bv = ov; bp = op; }
    }
    if (it == 0) m0 = bv;
    const float e = expf(bv - m0);
    Z += e;
    if ((bp & 63) == lane) sv[bp >> 6] = -FLT_MAX;
    if (lane == it) { win_e = e; win_p = bp; }
  }
  if (lane < 32) {
    const int k = win_p >> 5, l = win_p & 31;
    const int ai = si1[k] * 1024 + si2[l];
    const int sh = shuffle_index[ai];  // = (eidx<<18) | vidx
    w_out[bh * 32 + lane] = win_e / Z;
    sh_out[bh * 32 + lane] = sh;
  }
}

// ---------------- weighted value gather/aggregate -> bf16 agg ---------------
__global__ __launch_bounds__(256) void k_agg(const float* __restrict__ w_out,
                                             const int* __restrict__ sh_out,
                                             const float* __restrict__ values,
                                             unsigned short* __restrict__ aggb) {
  __shared__ float acc[4][1024];
  const int b = blockIdx.x;
  const int tid = threadIdx.x;
  const int wave = tid >> 6, lane = tid & 63;
  for (int i = tid; i < 4096; i += 256) ((float*)acc)[i] = 0.f;
  __syncthreads();
  for (int j = wave; j < 64; j += 4) {
    const float wgt = w_out[b * 64 + j];
    const int sh = sh_out[b * 64 + j];
    const int vidx = sh & 0x3FFFF;
    const int e = sh >> 18;
    const float4 v = *(const float4*)&values[(size_t)vidx * 256 + lane * 4];
    float* dst = &acc[wave][e * 256 + lane * 4];
    dst[0] += wgt * v.x;
    dst[1] += wgt * v.y;
    dst[2] += wgt * v.z;
    dst[3] += wgt * v.w;
  }
  __syncthreads();
  for (int i = tid; i < 1024; i += 256)
    aggb[(size_t)b * 1024 + i] = f2bf(acc[0][i] + acc[1][i] + acc[2][i] + acc[3][i]);
}

// ---------------- transpose + convert f32 -> bf16 (for wv) ------------------
__global__ __launch_bounds__(256) void k_tcvt(const float* __restrict__ src,
                                              unsigned short* __restrict__ dst,
                                              int R, int C) {
  __shared__ float tile[64][65];
  const int br = blockIdx.x * 64;
  const int bc = blockIdx.y * 64;
  const int tid = threadIdx.x;
  for (int idx = tid; idx < 4096; idx += 256) {
    const int r = idx >> 6, c = idx & 63;
    tile[r][c] = src[(size_t)(br + r) * C + bc + c];
  }
  __syncthreads();
  for (int idx = tid; idx < 4096; idx += 256) {
    const int cc = idx >> 6, rr = idx & 63;
    dst[(size_t)(bc + cc) * R + br + rr] = f2bf(tile[rr][cc]);
  }
}

// ---------------- bf16 MFMA GEMM (final projection) -------------------------
template <int BM, int BN>
__global__ __launch_bounds__(256) void k_mfma(const unsigned short* __restrict__ A,
                                              const unsigned short* __restrict__ Bt,
                                              float* __restrict__ C,
                                              int M, int N, int K) {
  constexpr int FM = BM / 32;
  constexpr int FN = BN / 32;
  __shared__ float4 As[BM * 4];
  __shared__ float4 Bs[BN * 4];
  const int tid = threadIdx.x;
  const int lane = tid & 63;
  const int w = tid >> 6;
  const int wr = w >> 1, wc = w & 1;
  const int bm = blockIdx.x * BM, bn = blockIdx.y * BN;
  f32x4 acc[FM][FN];
#pragma unroll
  for (int i = 0; i < FM; ++i)
#pragma unroll
    for (int j = 0; j < FN; ++j) acc[i][j] = 0.f;

  for (int k0 = 0; k0 < K; k0 += 32) {
#pragma unroll
    for (int u = 0; u < BM * 4 / 256; ++u) {
      const int q = tid + u * 256;
      const int m = q >> 2, c = q & 3;
      As[(m >> 4) * 64 + c * 16 + (m & 15)] =
          *(const float4*)&A[(size_t)(bm + m) * K + k0 + c * 8];
    }
#pragma unroll
    for (int u = 0; u < BN * 4 / 256; ++u) {
      const int q = tid + u * 256;
      const int n = q >> 2, c = q & 3;
      Bs[(n >> 4) * 64 + c * 16 + (n & 15)] =
          *(const float4*)&Bt[(size_t)(bn + n) * K + k0 + c * 8];
    }
    __syncthreads();
    bf16x8 af[FM], bfr[FN];
#pragma unroll
    for (int i = 0; i < FM; ++i) af[i] = *(const bf16x8*)&As[(wr * FM + i) * 64 + lane];
#pragma unroll
    for (int j = 0; j < FN; ++j) bfr[j] = *(const bf16x8*)&Bs[(wc * FN + j) * 64 + lane];
#pragma unroll
    for (int i = 0; i < FM; ++i)
#pragma unroll
      for (int j = 0; j < FN; ++j)
        acc[i][j] = __builtin_amdgcn_mfma_f32_16x16x32_bf16(af[i], bfr[j], acc[i][j], 0, 0, 0);
    __syncthreads();
  }
#pragma unroll
  for (int i = 0; i < FM; ++i) {
    const int r0 = bm + (wr * FM + i) * 16 + (lane >> 4) * 4;
#pragma unroll
    for (int j = 0; j < FN; ++j) {
      const int cc = bn + (wc * FN + j) * 16 + (lane & 15);
#pragma unroll
      for (int v = 0; v < 4; ++v) C[(size_t)(r0 + v) * N + cc] = acc[i][j][v];
    }
  }
}

// ---------------------------------------------------------------------------
extern "C" void kernel_launch(void* const* d_in, const int* in_sizes, int n_in,
                              void* d_out, int out_size, void* d_ws, size_t ws_size,
                              hipStream_t stream) {
  const float* hidden = (const float*)d_in[0];
  const float* wq     = (const float*)d_in[1];
  const float* qnw    = (const float*)d_in[2];
  const float* knw    = (const float*)d_in[3];
  const float* keys   = (const float*)d_in[4];
  const float* tcore  = (const float*)d_in[5];
  const float* tu     = (const float*)d_in[6];
  const float* tv     = (const float*)d_in[7];
  const float* values = (const float*)d_in[8];
  const float* wvm    = (const float*)d_in[9];
  const int*   shuf   = (const int*)d_in[10];
  float* out = (float*)d_out;

  char* ws = (char*)d_ws;
  size_t off = 0;
  auto alloc = [&](size_t bytes) -> void* {
    void* p = ws + off;
    off += (bytes + 255) & ~(size_t)255;
    return p;
  };
  float* Bct   = (float*)alloc((size_t)4096 * 256 * 4);      //  4 MB
  float* BctT  = (float*)alloc((size_t)256 * 4096 * 4);      //  4 MB
  float* Bg    = (float*)alloc((size_t)4096 * 512 * 4);      //  8 MB
  float* q12n  = (float*)alloc((size_t)8192 * 256 * 4);      //  8 MB
  float* q12nT = (float*)alloc((size_t)256 * 8192 * 4);      //  8 MB
  unsigned short* wvT  = (unsigned short*)alloc((size_t)2048 * 1024 * 2);  // 4 MB
  unsigned short* aggb = (unsigned short*)alloc((size_t)4096 * 1024 * 2);  // 8 MB
  int*   i1  = (int*)  alloc((size_t)8192 * 32 * 4);
  int*   i2  = (int*)  alloc((size_t)8192 * 32 * 4);
  float* g1  = (float*)alloc((size_t)8192 * 64 * 4);
  float* g2  = (float*)alloc((size_t)8192 * 64 * 4);
  float* wgt = (float*)alloc((size_t)8192 * 32 * 4);
  int*   sho = (int*)  alloc((size_t)8192 * 32 * 4);
  float* big = (float*)alloc((size_t)8192 * 2048 * 4);  // 64 MB shared region
  float* qpart   = big;                            // 4 x 4096 x 512 (32 MB)
  float* hiddenT = big + (size_t)8 * 1024 * 1024;  // 2048 x 4096 (32 MB)
  float* s_r     = big;                            // 8192 x 2048 (64 MB), later
  (void)ws_size; (void)in_sizes; (void)n_in; (void)out_size;

  // 1) keys -> Bg (raw keysn) + Bct (u/v-combined)
  k_prep32<<<4096, 64, 0, stream>>>(keys, knw, tu, tv, Bct, Bg);
  // 2) wv -> bf16 transposed; Bct -> BctT; hidden -> hiddenT
  k_tcvt<<<dim3(16, 32), 256, 0, stream>>>(wvm, wvT, 1024, 2048);
  k_tr32<<<dim3(64, 4), 256, 0, stream>>>(Bct, BctT, 4096, 256);
  k_tr32<<<dim3(64, 32), 256, 0, stream>>>(hidden, hiddenT, 4096, 2048);
  // 3) q projection, f32 split-K=4: qpart[z] = hiddenT^T @ wq (K-slice z)
  k_gemm32<4><<<dim3(32, 4, 4), 256, 0, stream>>>(
      hiddenT, 4096, wq, 512, 0, 1 << 30, qpart, 4096, 512, 2048);
  // 4) sum partials + LN -> q12n; transpose
  k_ln_q<<<8192, 64, 0, stream>>>(qpart, qnw, q12n);
  k_tr32<<<dim3(128, 4), 256, 0, stream>>>(q12n, q12nT, 8192, 256);
  // 5) fused score GEMM: rows [0,4096)=side1 (B cols 0..2047),
  //    rows [4096,8192)=side2 (B cols 2048..4095)
  k_gemm32<1><<<dim3(64, 16, 1), 256, 0, stream>>>(
      q12nT, 8192, BctT, 4096, 2048, 4096, s_r, 8192, 2048, 256);
  // 6) stage-1 top-32 (both sides, bisection)
  k_topk1<<<16384, 64, 0, stream>>>(s_r, i1, i2);
  // 7) gather per-rank scores for selected keys
  k_gather<<<16384, 64, 0, stream>>>(q12n, Bg, i1, i2, g1, g2);
  // 8) stage-2 bilinear scores, top-32, softmax, shuffle
  k_stage2<<<8192, 64, 0, stream>>>(g1, g2, i1, i2, tcore, shuf, wgt, sho);
  // 9) weighted value gather -> bf16 agg
  k_agg<<<4096, 256, 0, stream>>>(wgt, sho, values, aggb);
  // 10) output projection (bf16 MFMA)
  k_mfma<128, 128><<<dim3(32, 16), 256, 0, stream>>>(aggb, wvT, out, 4096, 2048, 1024);
}

// Round 7
// 608.973 us; speedup vs baseline: 7.5963x; 1.0491x over previous
//
#include <hip/hip_runtime.h>
#include <float.h>
#include <math.h>

// ---------------------------------------------------------------------------
// UltraMemLayerV1 — round 7: coalesced gather.
// Round-6 profile: k_gather = 160 us, VALUBusy 6%, HBM 2% -> TA-bound
// (64 distinct cache lines per load instruction: lane-per-row layout).
// Fix: 4 lanes per selected row, each reading a contiguous 64B quarter
// -> 16 lines/instruction (data floor). q row + sel indices staged in LDS,
// shfl_xor(1,2) group reduction. All other kernels = passing round 6.
// ---------------------------------------------------------------------------

typedef __attribute__((ext_vector_type(8))) __bf16 bf16x8;
typedef __attribute__((ext_vector_type(4))) float f32x4;

__device__ __forceinline__ unsigned short f2bf(float x) {
  unsigned int u = __float_as_uint(x);
  return (unsigned short)((u + 0x7FFFu + ((u >> 16) & 1u)) >> 16);
}

__device__ __forceinline__ float wave_sum(float x) {
#pragma unroll
  for (int o = 32; o; o >>= 1) x += __shfl_xor(x, o, 64);
  return x;
}

__device__ __forceinline__ void gll16(const float* g, float* l) {
  __builtin_amdgcn_global_load_lds(
      (const __attribute__((address_space(1))) void*)g,
      (__attribute__((address_space(3))) void*)l, 16, 0, 0);
}

// ---------------- keys prep: LN over d, fold knorm + tucker u/v -------------
__global__ void k_prep32(const float* __restrict__ keys, const float* __restrict__ knw,
                         const float* __restrict__ tu, const float* __restrict__ tv,
                         float* __restrict__ Bct, float* __restrict__ Bg) {
  const int bid = blockIdx.x;  // 4096 = c*2048 + h*1024 + k
  const int lane = threadIdx.x;
  const int k = bid & 1023, h = (bid >> 10) & 1, c = bid >> 11;
  const float* base = keys + (size_t)((h * 2 + c) * 1024 + k) * 512;  // (h,c,k,d,r)
  float x0[4], x1[4];
  float s0 = 0.f, s1 = 0.f, sq0 = 0.f, sq1 = 0.f;
#pragma unroll
  for (int i = 0; i < 4; ++i) {
    const int d = lane + i * 64;
    const float2 p = *(const float2*)&base[d * 2];
    x0[i] = p.x; x1[i] = p.y;
    s0 += p.x; sq0 += p.x * p.x;
    s1 += p.y; sq1 += p.y * p.y;
  }
  s0 = wave_sum(s0); sq0 = wave_sum(sq0);
  s1 = wave_sum(s1); sq1 = wave_sum(sq1);
  const float m0 = s0 * (1.f / 256.f), m1 = s1 * (1.f / 256.f);
  const float rs0 = 1.f / sqrtf(sq0 * (1.f / 256.f) - m0 * m0 + 1e-5f);
  const float rs1 = 1.f / sqrtf(sq1 * (1.f / 256.f) - m1 * m1 + 1e-5f);
  const float* uv = c ? tv : tu;
  const float u0 = uv[h * 2 + 0], u1 = uv[h * 2 + 1];
  const int chk = c * 2048 + h * 1024 + k;
  float* bg = Bg + (size_t)chk * 512;
  float* bc = Bct + (size_t)chk * 256;
#pragma unroll
  for (int i = 0; i < 4; ++i) {
    const int d = lane + i * 64;
    const float w = knw[d];
    const float y0 = (x0[i] - m0) * rs0 * w;
    const float y1 = (x1[i] - m1) * rs1 * w;
    bg[d] = y0;
    bg[256 + d] = y1;
    bc[d] = y0 * u0 + y1 * u1;
  }
}

// ---------------- f32 transpose: src[R][C] -> dst[C][R] ---------------------
__global__ __launch_bounds__(256) void k_tr32(const float* __restrict__ src,
                                              float* __restrict__ dst, int R, int C) {
  __shared__ float t[64][65];
  const int br = blockIdx.x * 64, bc = blockIdx.y * 64;
  const int tid = threadIdx.x;
  for (int idx = tid; idx < 4096; idx += 256) {
    const int r = idx >> 6, c = idx & 63;
    t[r][c] = src[(size_t)(br + r) * C + bc + c];
  }
  __syncthreads();
  for (int idx = tid; idx < 4096; idx += 256) {
    const int cc = idx >> 6, rr = idx & 63;
    dst[(size_t)(bc + cc) * R + br + rr] = t[rr][cc];
  }
}

// ---------------- f32 GEMM, operands in [K][*] layout, async staging --------
template <int SPLITK>
__global__ __launch_bounds__(256) void k_gemm32(
    const float* __restrict__ AT, int lda,
    const float* __restrict__ BT, int ldb, int bsk, int m_split,
    float* __restrict__ C, int M, int N, int K) {
  constexpr int BK = 32;
  __shared__ float As[BK][128];
  __shared__ float Bs[BK][128];
  const int tid = threadIdx.x;
  const int lane = tid & 63;
  const int w = tid >> 6;
  const int tx = tid & 15, ty = tid >> 4;
  const int bm = blockIdx.x * 128, bn = blockIdx.y * 128;
  const int bcol = bn + ((bm >= m_split) ? bsk : 0);
  const int Ks = K / SPLITK;
  const int kbeg = blockIdx.z * Ks;
  float* Cp = C + (size_t)blockIdx.z * M * N;
  const int l5 = lane >> 5, l31 = lane & 31;
  float acc[8][8] = {};

  for (int k0 = 0; k0 < Ks; k0 += BK) {
#pragma unroll
    for (int i = 0; i < 4; ++i) {
      const int rr = w * 8 + i * 2;
      const size_t krow = (size_t)(kbeg + k0 + rr + l5);
      gll16(&AT[krow * lda + bm + l31 * 4], &As[rr][0]);
      gll16(&BT[krow * ldb + bcol + l31 * 4], &Bs[rr][0]);
    }
    __syncthreads();
#pragma unroll
    for (int kk = 0; kk < BK; ++kk) {
      float a[8], b[8];
      *(float4*)&a[0] = *(const float4*)&As[kk][ty * 4];
      *(float4*)&a[4] = *(const float4*)&As[kk][64 + ty * 4];
      *(float4*)&b[0] = *(const float4*)&Bs[kk][tx * 4];
      *(float4*)&b[4] = *(const float4*)&Bs[kk][64 + tx * 4];
#pragma unroll
      for (int i = 0; i < 8; ++i)
#pragma unroll
        for (int j = 0; j < 8; ++j) acc[i][j] += a[i] * b[j];
    }
    __syncthreads();
  }
#pragma unroll
  for (int ih = 0; ih < 2; ++ih)
#pragma unroll
    for (int i = 0; i < 4; ++i) {
      const size_t r = bm + ih * 64 + ty * 4 + i;
#pragma unroll
      for (int jh = 0; jh < 2; ++jh) {
        float4 v = {acc[ih * 4 + i][jh * 4 + 0], acc[ih * 4 + i][jh * 4 + 1],
                    acc[ih * 4 + i][jh * 4 + 2], acc[ih * 4 + i][jh * 4 + 3]};
        *(float4*)&Cp[r * N + bn + jh * 64 + tx * 4] = v;
      }
    }
}

// ---------------- q: sum split-K partials + LN -> q12n ----------------------
__global__ void k_ln_q(const float* __restrict__ qpart, const float* __restrict__ qnw,
                       float* __restrict__ q12n) {
  const int bid = blockIdx.x;  // b*2 + c
  const int lane = threadIdx.x;
  const int b = bid >> 1, c = bid & 1;
  float x[4] = {};
#pragma unroll
  for (int s = 0; s < 4; ++s) {
    const float4 p = *(const float4*)&qpart[(size_t)s * 4096 * 512 + (size_t)b * 512 + c * 256 + lane * 4];
    x[0] += p.x; x[1] += p.y; x[2] += p.z; x[3] += p.w;
  }
  float sm = x[0] + x[1] + x[2] + x[3];
  float sq = x[0] * x[0] + x[1] * x[1] + x[2] * x[2] + x[3] * x[3];
  sm = wave_sum(sm);
  sq = wave_sum(sq);
  const float mean = sm * (1.f / 256.f);
  const float rs = 1.f / sqrtf(sq * (1.f / 256.f) - mean * mean + 1e-5f);
  const float4 w4 = *(const float4*)&qnw[lane * 4];
  float4 o;
  o.x = (x[0] - mean) * rs * w4.x;
  o.y = (x[1] - mean) * rs * w4.y;
  o.z = (x[2] - mean) * rs * w4.z;
  o.w = (x[3] - mean) * rs * w4.w;
  *(float4*)&q12n[(size_t)(c * 4096 + b) * 256 + lane * 4] = o;
}

// ---------------- stage-1 top-32 via exact radix bisection ------------------
__global__ void k_topk1(const float* __restrict__ s_r,
                        int* __restrict__ i1, int* __restrict__ i2) {
  const int bid = blockIdx.x;  // side*8192 + b*2 + h
  const int side = bid >> 13;
  const int bh = bid & 8191;
  const int b = bh >> 1, h = bh & 1;
  const int lane = threadIdx.x;
  const float* row = s_r + (size_t)(side * 4096 + b) * 2048 + h * 1024;
  unsigned int ku[16];
#pragma unroll
  for (int i = 0; i < 16; ++i) {
    const unsigned int u = __float_as_uint(row[lane + (i << 6)]);
    ku[i] = u ^ (((unsigned int)((int)u >> 31)) | 0x80000000u);
  }
  unsigned int T = 0u;
  for (int bpos = 31; bpos >= 0; --bpos) {
    const unsigned int cand = T | (1u << bpos);
    int c = 0;
#pragma unroll
    for (int i = 0; i < 16; ++i) c += (ku[i] >= cand) ? 1 : 0;
#pragma unroll
    for (int o = 32; o; o >>= 1) c += __shfl_xor(c, o, 64);
    if (c >= 32) T = cand;
  }
  int cgt = 0, ceq = 0;
#pragma unroll
  for (int i = 0; i < 16; ++i) {
    cgt += (ku[i] > T) ? 1 : 0;
    ceq += (ku[i] == T) ? 1 : 0;
  }
  int pgt = cgt, peq = ceq;
#pragma unroll
  for (int o = 1; o < 64; o <<= 1) {
    const int t1 = __shfl_up(pgt, o, 64);
    const int t2 = __shfl_up(peq, o, 64);
    if (lane >= o) { pgt += t1; peq += t2; }
  }
  const int total_gt = __shfl(pgt, 63, 64);
  const int need_eq = 32 - total_gt;
  int sgt = pgt - cgt;
  int seq = peq - ceq;
  int* iout = (side ? i2 : i1) + bh * 32;
#pragma unroll
  for (int i = 0; i < 16; ++i) {
    const int idx = (i << 6) + lane;
    if (ku[i] > T) {
      iout[sgt++] = idx;
    } else if (ku[i] == T) {
      if (seq < need_eq) iout[total_gt + seq] = idx;
      ++seq;
    }
  }
}

// ---------------- gather per-rank scores for selected keys (coalesced) ------
// 256 threads per (side,b,h). 4 lanes per selected (row = slot*2 + r), each
// reading a contiguous 64-float quarter -> one 64B line per 4-lane group.
__global__ __launch_bounds__(256) void k_gather(
    const float* __restrict__ q12n, const float* __restrict__ Bg,
    const int* __restrict__ i1, const int* __restrict__ i2,
    float* __restrict__ g1, float* __restrict__ g2) {
  __shared__ float qs[256];
  __shared__ int ssel[32];
  const int bid = blockIdx.x;  // side*8192 + b*2 + h
  const int side = bid >> 13;
  const int bh = bid & 8191;
  const int b = bh >> 1, h = bh & 1;
  const int tid = threadIdx.x;
  if (tid < 64) {
    *(float4*)&qs[tid * 4] =
        *(const float4*)&q12n[(size_t)(side * 4096 + b) * 256 + tid * 4];
  } else if (tid < 96) {
    ssel[tid - 64] = (side ? i2 : i1)[bh * 32 + (tid - 64)];
  }
  __syncthreads();
  const int j = tid >> 2;    // 0..63 = slot*2 + r
  const int c4 = tid & 3;    // quarter of the 256-dot
  const int slot = j >> 1, r = j & 1;
  const int sel = ssel[slot];
  const float* krow =
      Bg + ((size_t)(side * 2048 + h * 1024 + sel) * 2 + r) * 256 + c4 * 64;
  const float* qp = qs + c4 * 64;
  float px = 0.f, py = 0.f, pz = 0.f, pw = 0.f;
#pragma unroll
  for (int i = 0; i < 16; ++i) {
    const float4 kv = *(const float4*)&krow[i * 4];
    const float4 qv = *(const float4*)&qp[i * 4];
    px += kv.x * qv.x;
    py += kv.y * qv.y;
    pz += kv.z * qv.z;
    pw += kv.w * qv.w;
  }
  float acc = (px + py) + (pz + pw);
  acc += __shfl_xor(acc, 1, 64);
  acc += __shfl_xor(acc, 2, 64);
  if (c4 == 0) (side ? g2 : g1)[(bh * 32 + slot) * 2 + r] = acc;
}

// ---------------- stage-2: 32x32 bilinear scores, top-32, softmax -----------
__global__ void k_stage2(const float* __restrict__ g1, const float* __restrict__ g2,
                         const int* __restrict__ i1, const int* __restrict__ i2,
                         const float* __restrict__ tucker_core,
                         const int* __restrict__ shuffle_index,
                         float* __restrict__ w_out, int* __restrict__ sh_out) {
  __shared__ float sg1x[32], sg1y[32], sg2x[32], sg2y[32];
  __shared__ int si1[32], si2[32];
  const int bh = blockIdx.x;
  const int h = bh & 1;
  const int lane = threadIdx.x;
  if (lane < 32) {
    const float2 p1 = *(const float2*)&g1[(bh * 32 + lane) * 2];
    const float2 p2 = *(const float2*)&g2[(bh * 32 + lane) * 2];
    sg1x[lane] = p1.x;
    sg1y[lane] = p1.y;
    sg2x[lane] = p2.x;
    sg2y[lane] = p2.y;
    si1[lane] = i1[bh * 32 + lane];
    si2[lane] = i2[bh * 32 + lane];
  }
  __syncthreads();
  const float c00 = tucker_core[h * 4 + 0] + tucker_core[8 + h * 4 + 0];
  const float c01 = tucker_core[h * 4 + 1] + tucker_core[8 + h * 4 + 1];
  const float c10 = tucker_core[h * 4 + 2] + tucker_core[8 + h * 4 + 2];
  const float c11 = tucker_core[h * 4 + 3] + tucker_core[8 + h * 4 + 3];
  float sv[16];
#pragma unroll
  for (int i = 0; i < 16; ++i) {
    const int p = lane + (i << 6);
    const int k = p >> 5, l = p & 31;
    const float a0 = sg1x[k] * c00 + sg1y[k] * c10;
    const float a1 = sg1x[k] * c01 + sg1y[k] * c11;
    sv[i] = a0 * sg2x[l] + a1 * sg2y[l];
  }
  float m0 = 0.f, Z = 0.f, win_e = 0.f;
  int win_p = 0;
  for (int it = 0; it < 32; ++it) {
    float bv = -FLT_MAX;
    int bp = 0x7FFFFFFF;
#pragma unroll
    for (int i = 0; i < 16; ++i) {
      const int p = lane + (i << 6);
      if (sv[i] > bv || (sv[i] == bv && p < bp)) { bv = sv[i]; bp = p; }
    }
#pragma unroll
    for (int o = 32; o; o >>= 1) {
      const float ov = __shfl_xor(bv, o, 64);
      const int op = __shfl_xor(bp, o, 64);
      if (ov > bv || (ov == bv && op < bp)) { bv = ov; bp = op; }
    }
    if (it == 0) m0 = bv;
    const float e = expf(bv - m0);
    Z += e;
    if ((bp & 63) == lane) sv[bp >> 6] = -FLT_MAX;
    if (lane == it) { win_e = e; win_p = bp; }
  }
  if (lane < 32) {
    const int k = win_p >> 5, l = win_p & 31;
    const int ai = si1[k] * 1024 + si2[l];
    const int sh = shuffle_index[ai];  // = (eidx<<18) | vidx
    w_out[bh * 32 + lane] = win_e / Z;
    sh_out[bh * 32 + lane] = sh;
  }
}

// ---------------- weighted value gather/aggregate -> bf16 agg ---------------
__global__ __launch_bounds__(256) void k_agg(const float* __restrict__ w_out,
                                             const int* __restrict__ sh_out,
                                             const float* __restrict__ values,
                                             unsigned short* __restrict__ aggb) {
  __shared__ float acc[4][1024];
  const int b = blockIdx.x;
  const int tid = threadIdx.x;
  const int wave = tid >> 6, lane = tid & 63;
  for (int i = tid; i < 4096; i += 256) ((float*)acc)[i] = 0.f;
  __syncthreads();
  for (int j = wave; j < 64; j += 4) {
    const float wgt = w_out[b * 64 + j];
    const int sh = sh_out[b * 64 + j];
    const int vidx = sh & 0x3FFFF;
    const int e = sh >> 18;
    const float4 v = *(const float4*)&values[(size_t)vidx * 256 + lane * 4];
    float* dst = &acc[wave][e * 256 + lane * 4];
    dst[0] += wgt * v.x;
    dst[1] += wgt * v.y;
    dst[2] += wgt * v.z;
    dst[3] += wgt * v.w;
  }
  __syncthreads();
  for (int i = tid; i < 1024; i += 256)
    aggb[(size_t)b * 1024 + i] = f2bf(acc[0][i] + acc[1][i] + acc[2][i] + acc[3][i]);
}

// ---------------- transpose + convert f32 -> bf16 (for wv) ------------------
__global__ __launch_bounds__(256) void k_tcvt(const float* __restrict__ src,
                                              unsigned short* __restrict__ dst,
                                              int R, int C) {
  __shared__ float tile[64][65];
  const int br = blockIdx.x * 64;
  const int bc = blockIdx.y * 64;
  const int tid = threadIdx.x;
  for (int idx = tid; idx < 4096; idx += 256) {
    const int r = idx >> 6, c = idx & 63;
    tile[r][c] = src[(size_t)(br + r) * C + bc + c];
  }
  __syncthreads();
  for (int idx = tid; idx < 4096; idx += 256) {
    const int cc = idx >> 6, rr = idx & 63;
    dst[(size_t)(bc + cc) * R + br + rr] = f2bf(tile[rr][cc]);
  }
}

// ---------------- bf16 MFMA GEMM (final projection) -------------------------
template <int BM, int BN>
__global__ __launch_bounds__(256) void k_mfma(const unsigned short* __restrict__ A,
                                              const unsigned short* __restrict__ Bt,
                                              float* __restrict__ C,
                                              int M, int N, int K) {
  constexpr int FM = BM / 32;
  constexpr int FN = BN / 32;
  __shared__ float4 As[BM * 4];
  __shared__ float4 Bs[BN * 4];
  const int tid = threadIdx.x;
  const int lane = tid & 63;
  const int w = tid >> 6;
  const int wr = w >> 1, wc = w & 1;
  const int bm = blockIdx.x * BM, bn = blockIdx.y * BN;
  f32x4 acc[FM][FN];
#pragma unroll
  for (int i = 0; i < FM; ++i)
#pragma unroll
    for (int j = 0; j < FN; ++j) acc[i][j] = 0.f;

  for (int k0 = 0; k0 < K; k0 += 32) {
#pragma unroll
    for (int u = 0; u < BM * 4 / 256; ++u) {
      const int q = tid + u * 256;
      const int m = q >> 2, c = q & 3;
      As[(m >> 4) * 64 + c * 16 + (m & 15)] =
          *(const float4*)&A[(size_t)(bm + m) * K + k0 + c * 8];
    }
#pragma unroll
    for (int u = 0; u < BN * 4 / 256; ++u) {
      const int q = tid + u * 256;
      const int n = q >> 2, c = q & 3;
      Bs[(n >> 4) * 64 + c * 16 + (n & 15)] =
          *(const float4*)&Bt[(size_t)(bn + n) * K + k0 + c * 8];
    }
    __syncthreads();
    bf16x8 af[FM], bfr[FN];
#pragma unroll
    for (int i = 0; i < FM; ++i) af[i] = *(const bf16x8*)&As[(wr * FM + i) * 64 + lane];
#pragma unroll
    for (int j = 0; j < FN; ++j) bfr[j] = *(const bf16x8*)&Bs[(wc * FN + j) * 64 + lane];
#pragma unroll
    for (int i = 0; i < FM; ++i)
#pragma unroll
      for (int j = 0; j < FN; ++j)
        acc[i][j] = __builtin_amdgcn_mfma_f32_16x16x32_bf16(af[i], bfr[j], acc[i][j], 0, 0, 0);
    __syncthreads();
  }
#pragma unroll
  for (int i = 0; i < FM; ++i) {
    const int r0 = bm + (wr * FM + i) * 16 + (lane >> 4) * 4;
#pragma unroll
    for (int j = 0; j < FN; ++j) {
      const int cc = bn + (wc * FN + j) * 16 + (lane & 15);
#pragma unroll
      for (int v = 0; v < 4; ++v) C[(size_t)(r0 + v) * N + cc] = acc[i][j][v];
    }
  }
}

// ---------------------------------------------------------------------------
extern "C" void kernel_launch(void* const* d_in, const int* in_sizes, int n_in,
                              void* d_out, int out_size, void* d_ws, size_t ws_size,
                              hipStream_t stream) {
  const float* hidden = (const float*)d_in[0];
  const float* wq     = (const float*)d_in[1];
  const float* qnw    = (const float*)d_in[2];
  const float* knw    = (const float*)d_in[3];
  const float* keys   = (const float*)d_in[4];
  const float* tcore  = (const float*)d_in[5];
  const float* tu     = (const float*)d_in[6];
  const float* tv     = (const float*)d_in[7];
  const float* values = (const float*)d_in[8];
  const float* wvm    = (const float*)d_in[9];
  const int*   shuf   = (const int*)d_in[10];
  float* out = (float*)d_out;

  char* ws = (char*)d_ws;
  size_t off = 0;
  auto alloc = [&](size_t bytes) -> void* {
    void* p = ws + off;
    off += (bytes + 255) & ~(size_t)255;
    return p;
  };
  float* Bct   = (float*)alloc((size_t)4096 * 256 * 4);      //  4 MB
  float* BctT  = (float*)alloc((size_t)256 * 4096 * 4);      //  4 MB
  float* Bg    = (float*)alloc((size_t)4096 * 512 * 4);      //  8 MB
  float* q12n  = (float*)alloc((size_t)8192 * 256 * 4);      //  8 MB
  float* q12nT = (float*)alloc((size_t)256 * 8192 * 4);      //  8 MB
  unsigned short* wvT  = (unsigned short*)alloc((size_t)2048 * 1024 * 2);  // 4 MB
  unsigned short* aggb = (unsigned short*)alloc((size_t)4096 * 1024 * 2);  // 8 MB
  int*   i1  = (int*)  alloc((size_t)8192 * 32 * 4);
  int*   i2  = (int*)  alloc((size_t)8192 * 32 * 4);
  float* g1  = (float*)alloc((size_t)8192 * 64 * 4);
  float* g2  = (float*)alloc((size_t)8192 * 64 * 4);
  float* wgt = (float*)alloc((size_t)8192 * 32 * 4);
  int*   sho = (int*)  alloc((size_t)8192 * 32 * 4);
  float* big = (float*)alloc((size_t)8192 * 2048 * 4);  // 64 MB shared region
  float* qpart   = big;                            // 4 x 4096 x 512 (32 MB)
  float* hiddenT = big + (size_t)8 * 1024 * 1024;  // 2048 x 4096 (32 MB)
  float* s_r     = big;                            // 8192 x 2048 (64 MB), later
  (void)ws_size; (void)in_sizes; (void)n_in; (void)out_size;

  // 1) keys -> Bg (raw keysn) + Bct (u/v-combined)
  k_prep32<<<4096, 64, 0, stream>>>(keys, knw, tu, tv, Bct, Bg);
  // 2) wv -> bf16 transposed; Bct -> BctT; hidden -> hiddenT
  k_tcvt<<<dim3(16, 32), 256, 0, stream>>>(wvm, wvT, 1024, 2048);
  k_tr32<<<dim3(64, 4), 256, 0, stream>>>(Bct, BctT, 4096, 256);
  k_tr32<<<dim3(64, 32), 256, 0, stream>>>(hidden, hiddenT, 4096, 2048);
  // 3) q projection, f32 split-K=4: qpart[z] = hiddenT^T @ wq (K-slice z)
  k_gemm32<4><<<dim3(32, 4, 4), 256, 0, stream>>>(
      hiddenT, 4096, wq, 512, 0, 1 << 30, qpart, 4096, 512, 2048);
  // 4) sum partials + LN -> q12n; transpose
  k_ln_q<<<8192, 64, 0, stream>>>(qpart, qnw, q12n);
  k_tr32<<<dim3(128, 4), 256, 0, stream>>>(q12n, q12nT, 8192, 256);
  // 5) fused score GEMM: rows [0,4096)=side1 (B cols 0..2047),
  //    rows [4096,8192)=side2 (B cols 2048..4095)
  k_gemm32<1><<<dim3(64, 16, 1), 256, 0, stream>>>(
      q12nT, 8192, BctT, 4096, 2048, 4096, s_r, 8192, 2048, 256);
  // 6) stage-1 top-32 (both sides, bisection)
  k_topk1<<<16384, 64, 0, stream>>>(s_r, i1, i2);
  // 7) gather per-rank scores for selected keys (coalesced)
  k_gather<<<16384, 256, 0, stream>>>(q12n, Bg, i1, i2, g1, g2);
  // 8) stage-2 bilinear scores, top-32, softmax, shuffle
  k_stage2<<<8192, 64, 0, stream>>>(g1, g2, i1, i2, tcore, shuf, wgt, sho);
  // 9) weighted value gather -> bf16 agg
  k_agg<<<4096, 256, 0, stream>>>(wgt, sho, values, aggb);
  // 10) output projection (bf16 MFMA)
  k_mfma<128, 128><<<dim3(32, 16), 256, 0, stream>>>(aggb, wvT, out, 4096, 2048, 1024);
}

// Round 8
// 547.288 us; speedup vs baseline: 8.4525x; 1.1127x over previous
//
#include <hip/hip_runtime.h>
#include <float.h>
#include <math.h>

// ---------------------------------------------------------------------------
// UltraMemLayerV1 — round 8:
//  (a) k_stage2 -> exact bisection top-32 + set-softmax (order-invariant
//      downstream), ~6000 -> ~1300 insts/wave.
//  (b) k_gemm32 -> 2-phase prefetch: double-buffered LDS (BK=16, same 32KB),
//      global_load_lds for tile t+1 issued BEFORE compute of tile t, one
//      barrier per tile. q GEMM split-K 4->8 (1024 blocks = 4/CU).
// All other kernels identical to the passing round 7.
// ---------------------------------------------------------------------------

typedef __attribute__((ext_vector_type(8))) __bf16 bf16x8;
typedef __attribute__((ext_vector_type(4))) float f32x4;

__device__ __forceinline__ unsigned short f2bf(float x) {
  unsigned int u = __float_as_uint(x);
  return (unsigned short)((u + 0x7FFFu + ((u >> 16) & 1u)) >> 16);
}

__device__ __forceinline__ float wave_sum(float x) {
#pragma unroll
  for (int o = 32; o; o >>= 1) x += __shfl_xor(x, o, 64);
  return x;
}

__device__ __forceinline__ void gll16(const float* g, float* l) {
  __builtin_amdgcn_global_load_lds(
      (const __attribute__((address_space(1))) void*)g,
      (__attribute__((address_space(3))) void*)l, 16, 0, 0);
}

// monotone f32 -> u32 key (order-preserving) and inverse
__device__ __forceinline__ unsigned int f2key(float f) {
  const unsigned int u = __float_as_uint(f);
  return u ^ (((unsigned int)((int)u >> 31)) | 0x80000000u);
}
__device__ __forceinline__ float key2f(unsigned int k) {
  return __uint_as_float((k & 0x80000000u) ? (k ^ 0x80000000u) : ~k);
}

// ---------------- keys prep: LN over d, fold knorm + tucker u/v -------------
__global__ void k_prep32(const float* __restrict__ keys, const float* __restrict__ knw,
                         const float* __restrict__ tu, const float* __restrict__ tv,
                         float* __restrict__ Bct, float* __restrict__ Bg) {
  const int bid = blockIdx.x;  // 4096 = c*2048 + h*1024 + k
  const int lane = threadIdx.x;
  const int k = bid & 1023, h = (bid >> 10) & 1, c = bid >> 11;
  const float* base = keys + (size_t)((h * 2 + c) * 1024 + k) * 512;  // (h,c,k,d,r)
  float x0[4], x1[4];
  float s0 = 0.f, s1 = 0.f, sq0 = 0.f, sq1 = 0.f;
#pragma unroll
  for (int i = 0; i < 4; ++i) {
    const int d = lane + i * 64;
    const float2 p = *(const float2*)&base[d * 2];
    x0[i] = p.x; x1[i] = p.y;
    s0 += p.x; sq0 += p.x * p.x;
    s1 += p.y; sq1 += p.y * p.y;
  }
  s0 = wave_sum(s0); sq0 = wave_sum(sq0);
  s1 = wave_sum(s1); sq1 = wave_sum(sq1);
  const float m0 = s0 * (1.f / 256.f), m1 = s1 * (1.f / 256.f);
  const float rs0 = 1.f / sqrtf(sq0 * (1.f / 256.f) - m0 * m0 + 1e-5f);
  const float rs1 = 1.f / sqrtf(sq1 * (1.f / 256.f) - m1 * m1 + 1e-5f);
  const float* uv = c ? tv : tu;
  const float u0 = uv[h * 2 + 0], u1 = uv[h * 2 + 1];
  const int chk = c * 2048 + h * 1024 + k;
  float* bg = Bg + (size_t)chk * 512;
  float* bc = Bct + (size_t)chk * 256;
#pragma unroll
  for (int i = 0; i < 4; ++i) {
    const int d = lane + i * 64;
    const float w = knw[d];
    const float y0 = (x0[i] - m0) * rs0 * w;
    const float y1 = (x1[i] - m1) * rs1 * w;
    bg[d] = y0;
    bg[256 + d] = y1;
    bc[d] = y0 * u0 + y1 * u1;
  }
}

// ---------------- f32 transpose: src[R][C] -> dst[C][R] ---------------------
__global__ __launch_bounds__(256) void k_tr32(const float* __restrict__ src,
                                              float* __restrict__ dst, int R, int C) {
  __shared__ float t[64][65];
  const int br = blockIdx.x * 64, bc = blockIdx.y * 64;
  const int tid = threadIdx.x;
  for (int idx = tid; idx < 4096; idx += 256) {
    const int r = idx >> 6, c = idx & 63;
    t[r][c] = src[(size_t)(br + r) * C + bc + c];
  }
  __syncthreads();
  for (int idx = tid; idx < 4096; idx += 256) {
    const int cc = idx >> 6, rr = idx & 63;
    dst[(size_t)(bc + cc) * R + br + rr] = t[rr][cc];
  }
}

// ---------------- f32 GEMM, [K][*] operands, 2-phase prefetch dbuf ----------
// C[M][N] = AT^T @ BT-slice. BK=16, double-buffered LDS (32KB total),
// global_load_lds for tile t+1 issued before compute of tile t; one barrier
// per tile (its implicit vmcnt(0) drains loads that ran under the compute).
template <int SPLITK>
__global__ __launch_bounds__(256) void k_gemm32(
    const float* __restrict__ AT, int lda,
    const float* __restrict__ BT, int ldb, int bsk, int m_split,
    float* __restrict__ C, int M, int N, int K) {
  constexpr int BK = 16;
  __shared__ float As[2][BK][128];
  __shared__ float Bs[2][BK][128];
  const int tid = threadIdx.x;
  const int lane = tid & 63;
  const int w = tid >> 6;
  const int tx = tid & 15, ty = tid >> 4;
  const int bm = blockIdx.x * 128, bn = blockIdx.y * 128;
  const int bcol = bn + ((bm >= m_split) ? bsk : 0);
  const int Ks = K / SPLITK;
  const int kbeg = blockIdx.z * Ks;
  float* Cp = C + (size_t)blockIdx.z * M * N;
  const int l5 = lane >> 5, l31 = lane & 31;
  float acc[8][8] = {};

  auto stage = [&](int buf, int t) {
    const int k0 = t * BK;
#pragma unroll
    for (int i = 0; i < 2; ++i) {
      const int rr = w * 4 + i * 2;  // wave covers 4 rows via 2x 1KB copies
      const size_t krow = (size_t)(kbeg + k0 + rr + l5);
      gll16(&AT[krow * lda + bm + l31 * 4], &As[buf][rr][0]);
      gll16(&BT[krow * ldb + bcol + l31 * 4], &Bs[buf][rr][0]);
    }
  };

  const int T = Ks / BK;
  stage(0, 0);
  __syncthreads();
  int cur = 0;
  for (int t = 0; t < T; ++t) {
    if (t + 1 < T) stage(cur ^ 1, t + 1);  // prefetch under compute
#pragma unroll
    for (int kk = 0; kk < BK; ++kk) {
      float a[8], b[8];
      *(float4*)&a[0] = *(const float4*)&As[cur][kk][ty * 4];
      *(float4*)&a[4] = *(const float4*)&As[cur][kk][64 + ty * 4];
      *(float4*)&b[0] = *(const float4*)&Bs[cur][kk][tx * 4];
      *(float4*)&b[4] = *(const float4*)&Bs[cur][kk][64 + tx * 4];
#pragma unroll
      for (int i = 0; i < 8; ++i)
#pragma unroll
        for (int j = 0; j < 8; ++j) acc[i][j] += a[i] * b[j];
    }
    __syncthreads();  // drains prefetch vmcnt + guards buffer reuse
    cur ^= 1;
  }
#pragma unroll
  for (int ih = 0; ih < 2; ++ih)
#pragma unroll
    for (int i = 0; i < 4; ++i) {
      const size_t r = bm + ih * 64 + ty * 4 + i;
#pragma unroll
      for (int jh = 0; jh < 2; ++jh) {
        float4 v = {acc[ih * 4 + i][jh * 4 + 0], acc[ih * 4 + i][jh * 4 + 1],
                    acc[ih * 4 + i][jh * 4 + 2], acc[ih * 4 + i][jh * 4 + 3]};
        *(float4*)&Cp[r * N + bn + jh * 64 + tx * 4] = v;
      }
    }
}

// ---------------- q: sum split-K partials (8) + LN -> q12n ------------------
__global__ void k_ln_q(const float* __restrict__ qpart, const float* __restrict__ qnw,
                       float* __restrict__ q12n) {
  const int bid = blockIdx.x;  // b*2 + c
  const int lane = threadIdx.x;
  const int b = bid >> 1, c = bid & 1;
  float x[4] = {};
#pragma unroll
  for (int s = 0; s < 8; ++s) {
    const float4 p = *(const float4*)&qpart[(size_t)s * 4096 * 512 + (size_t)b * 512 + c * 256 + lane * 4];
    x[0] += p.x; x[1] += p.y; x[2] += p.z; x[3] += p.w;
  }
  float sm = x[0] + x[1] + x[2] + x[3];
  float sq = x[0] * x[0] + x[1] * x[1] + x[2] * x[2] + x[3] * x[3];
  sm = wave_sum(sm);
  sq = wave_sum(sq);
  const float mean = sm * (1.f / 256.f);
  const float rs = 1.f / sqrtf(sq * (1.f / 256.f) - mean * mean + 1e-5f);
  const float4 w4 = *(const float4*)&qnw[lane * 4];
  float4 o;
  o.x = (x[0] - mean) * rs * w4.x;
  o.y = (x[1] - mean) * rs * w4.y;
  o.z = (x[2] - mean) * rs * w4.z;
  o.w = (x[3] - mean) * rs * w4.w;
  *(float4*)&q12n[(size_t)(c * 4096 + b) * 256 + lane * 4] = o;
}

// ---------------- stage-1 top-32 via exact radix bisection ------------------
__global__ void k_topk1(const float* __restrict__ s_r,
                        int* __restrict__ i1, int* __restrict__ i2) {
  const int bid = blockIdx.x;  // side*8192 + b*2 + h
  const int side = bid >> 13;
  const int bh = bid & 8191;
  const int b = bh >> 1, h = bh & 1;
  const int lane = threadIdx.x;
  const float* row = s_r + (size_t)(side * 4096 + b) * 2048 + h * 1024;
  unsigned int ku[16];
#pragma unroll
  for (int i = 0; i < 16; ++i) ku[i] = f2key(row[lane + (i << 6)]);
  unsigned int T = 0u;
  for (int bpos = 31; bpos >= 0; --bpos) {
    const unsigned int cand = T | (1u << bpos);
    int c = 0;
#pragma unroll
    for (int i = 0; i < 16; ++i) c += (ku[i] >= cand) ? 1 : 0;
#pragma unroll
    for (int o = 32; o; o >>= 1) c += __shfl_xor(c, o, 64);
    if (c >= 32) T = cand;
  }
  int cgt = 0, ceq = 0;
#pragma unroll
  for (int i = 0; i < 16; ++i) {
    cgt += (ku[i] > T) ? 1 : 0;
    ceq += (ku[i] == T) ? 1 : 0;
  }
  int pgt = cgt, peq = ceq;
#pragma unroll
  for (int o = 1; o < 64; o <<= 1) {
    const int t1 = __shfl_up(pgt, o, 64);
    const int t2 = __shfl_up(peq, o, 64);
    if (lane >= o) { pgt += t1; peq += t2; }
  }
  const int total_gt = __shfl(pgt, 63, 64);
  const int need_eq = 32 - total_gt;
  int sgt = pgt - cgt;
  int seq = peq - ceq;
  int* iout = (side ? i2 : i1) + bh * 32;
#pragma unroll
  for (int i = 0; i < 16; ++i) {
    const int idx = (i << 6) + lane;
    if (ku[i] > T) {
      iout[sgt++] = idx;
    } else if (ku[i] == T) {
      if (seq < need_eq) iout[total_gt + seq] = idx;
      ++seq;
    }
  }
}

// ---------------- gather per-rank scores for selected keys (coalesced) ------
__global__ __launch_bounds__(256) void k_gather(
    const float* __restrict__ q12n, const float* __restrict__ Bg,
    const int* __restrict__ i1, const int* __restrict__ i2,
    float* __restrict__ g1, float* __restrict__ g2) {
  __shared__ float qs[256];
  __shared__ int ssel[32];
  const int bid = blockIdx.x;  // side*8192 + b*2 + h
  const int side = bid >> 13;
  const int bh = bid & 8191;
  const int b = bh >> 1, h = bh & 1;
  const int tid = threadIdx.x;
  if (tid < 64) {
    *(float4*)&qs[tid * 4] =
        *(const float4*)&q12n[(size_t)(side * 4096 + b) * 256 + tid * 4];
  } else if (tid < 96) {
    ssel[tid - 64] = (side ? i2 : i1)[bh * 32 + (tid - 64)];
  }
  __syncthreads();
  const int j = tid >> 2;
  const int c4 = tid & 3;
  const int slot = j >> 1, r = j & 1;
  const int sel = ssel[slot];
  const float* krow =
      Bg + ((size_t)(side * 2048 + h * 1024 + sel) * 2 + r) * 256 + c4 * 64;
  const float* qp = qs + c4 * 64;
  float px = 0.f, py = 0.f, pz = 0.f, pw = 0.f;
#pragma unroll
  for (int i = 0; i < 16; ++i) {
    const float4 kv = *(const float4*)&krow[i * 4];
    const float4 qv = *(const float4*)&qp[i * 4];
    px += kv.x * qv.x;
    py += kv.y * qv.y;
    pz += kv.z * qv.z;
    pw += kv.w * qv.w;
  }
  float acc = (px + py) + (pz + pw);
  acc += __shfl_xor(acc, 1, 64);
  acc += __shfl_xor(acc, 2, 64);
  if (c4 == 0) (side ? g2 : g1)[(bh * 32 + slot) * 2 + r] = acc;
}

// ---------------- stage-2: bilinear scores, bisection top-32, set-softmax ---
__global__ void k_stage2(const float* __restrict__ g1, const float* __restrict__ g2,
                         const int* __restrict__ i1, const int* __restrict__ i2,
                         const float* __restrict__ tucker_core,
                         const int* __restrict__ shuffle_index,
                         float* __restrict__ w_out, int* __restrict__ sh_out) {
  __shared__ float sg1x[32], sg1y[32], sg2x[32], sg2y[32];
  __shared__ int si1[32], si2[32];
  const int bh = blockIdx.x;
  const int h = bh & 1;
  const int lane = threadIdx.x;
  if (lane < 32) {
    const float2 p1 = *(const float2*)&g1[(bh * 32 + lane) * 2];
    const float2 p2 = *(const float2*)&g2[(bh * 32 + lane) * 2];
    sg1x[lane] = p1.x;
    sg1y[lane] = p1.y;
    sg2x[lane] = p2.x;
    sg2y[lane] = p2.y;
    si1[lane] = i1[bh * 32 + lane];
    si2[lane] = i2[bh * 32 + lane];
  }
  __syncthreads();
  const float c00 = tucker_core[h * 4 + 0] + tucker_core[8 + h * 4 + 0];
  const float c01 = tucker_core[h * 4 + 1] + tucker_core[8 + h * 4 + 1];
  const float c10 = tucker_core[h * 4 + 2] + tucker_core[8 + h * 4 + 2];
  const float c11 = tucker_core[h * 4 + 3] + tucker_core[8 + h * 4 + 3];
  float sv[16];
  unsigned int ku[16];
  float m = -FLT_MAX;
#pragma unroll
  for (int i = 0; i < 16; ++i) {
    const int p = lane + (i << 6);
    const int k = p >> 5, l = p & 31;
    const float a0 = sg1x[k] * c00 + sg1y[k] * c10;
    const float a1 = sg1x[k] * c01 + sg1y[k] * c11;
    sv[i] = a0 * sg2x[l] + a1 * sg2y[l];
    ku[i] = f2key(sv[i]);
    m = fmaxf(m, sv[i]);
  }
#pragma unroll
  for (int o = 32; o; o >>= 1) m = fmaxf(m, __shfl_xor(m, o, 64));
  // bisection for T = 32nd-largest key
  unsigned int T = 0u;
  for (int bpos = 31; bpos >= 0; --bpos) {
    const unsigned int cand = T | (1u << bpos);
    int c = 0;
#pragma unroll
    for (int i = 0; i < 16; ++i) c += (ku[i] >= cand) ? 1 : 0;
#pragma unroll
    for (int o = 32; o; o >>= 1) c += __shfl_xor(c, o, 64);
    if (c >= 32) T = cand;
  }
  int cgt = 0, ceq = 0;
  float zp = 0.f;
#pragma unroll
  for (int i = 0; i < 16; ++i) {
    if (ku[i] > T) { ++cgt; zp += expf(sv[i] - m); }
    ceq += (ku[i] == T) ? 1 : 0;
  }
  int pgt = cgt, peq = ceq;
#pragma unroll
  for (int o = 1; o < 64; o <<= 1) {
    const int t1 = __shfl_up(pgt, o, 64);
    const int t2 = __shfl_up(peq, o, 64);
    if (lane >= o) { pgt += t1; peq += t2; }
  }
  const int total_gt = __shfl(pgt, 63, 64);
  const int need_eq = 32 - total_gt;
  const float eT = expf(key2f(T) - m);
  const float Z = wave_sum(zp) + (float)need_eq * eT;
  const float rZ = 1.f / Z;
  int sgt = pgt - cgt;
  int seq = peq - ceq;
  float* wp = w_out + bh * 32;
  int* shp = sh_out + bh * 32;
#pragma unroll
  for (int i = 0; i < 16; ++i) {
    int slot = -1;
    if (ku[i] > T) {
      slot = sgt++;
    } else if (ku[i] == T) {
      if (seq < need_eq) slot = total_gt + seq;
      ++seq;
    }
    if (slot >= 0) {
      const int p = lane + (i << 6);
      const int k = p >> 5, l = p & 31;
      const int ai = si1[k] * 1024 + si2[l];
      wp[slot] = expf(sv[i] - m) * rZ;
      shp[slot] = shuffle_index[ai];  // = (eidx<<18) | vidx
    }
  }
}

// ---------------- weighted value gather/aggregate -> bf16 agg ---------------
__global__ __launch_bounds__(256) void k_agg(const float* __restrict__ w_out,
                                             const int* __restrict__ sh_out,
                                             const float* __restrict__ values,
                                             unsigned short* __restrict__ aggb) {
  __shared__ float acc[4][1024];
  const int b = blockIdx.x;
  const int tid = threadIdx.x;
  const int wave = tid >> 6, lane = tid & 63;
  for (int i = tid; i < 4096; i += 256) ((float*)acc)[i] = 0.f;
  __syncthreads();
  for (int j = wave; j < 64; j += 4) {
    const float wgt = w_out[b * 64 + j];
    const int sh = sh_out[b * 64 + j];
    const int vidx = sh & 0x3FFFF;
    const int e = sh >> 18;
    const float4 v = *(const float4*)&values[(size_t)vidx * 256 + lane * 4];
    float* dst = &acc[wave][e * 256 + lane * 4];
    dst[0] += wgt * v.x;
    dst[1] += wgt * v.y;
    dst[2] += wgt * v.z;
    dst[3] += wgt * v.w;
  }
  __syncthreads();
  for (int i = tid; i < 1024; i += 256)
    aggb[(size_t)b * 1024 + i] = f2bf(acc[0][i] + acc[1][i] + acc[2][i] + acc[3][i]);
}

// ---------------- transpose + convert f32 -> bf16 (for wv) ------------------
__global__ __launch_bounds__(256) void k_tcvt(const float* __restrict__ src,
                                              unsigned short* __restrict__ dst,
                                              int R, int C) {
  __shared__ float tile[64][65];
  const int br = blockIdx.x * 64;
  const int bc = blockIdx.y * 64;
  const int tid = threadIdx.x;
  for (int idx = tid; idx < 4096; idx += 256) {
    const int r = idx >> 6, c = idx & 63;
    tile[r][c] = src[(size_t)(br + r) * C + bc + c];
  }
  __syncthreads();
  for (int idx = tid; idx < 4096; idx += 256) {
    const int cc = idx >> 6, rr = idx & 63;
    dst[(size_t)(bc + cc) * R + br + rr] = f2bf(tile[rr][cc]);
  }
}

// ---------------- bf16 MFMA GEMM (final projection) -------------------------
template <int BM, int BN>
__global__ __launch_bounds__(256) void k_mfma(const unsigned short* __restrict__ A,
                                              const unsigned short* __restrict__ Bt,
                                              float* __restrict__ C,
                                              int M, int N, int K) {
  constexpr int FM = BM / 32;
  constexpr int FN = BN / 32;
  __shared__ float4 As[BM * 4];
  __shared__ float4 Bs[BN * 4];
  const int tid = threadIdx.x;
  const int lane = tid & 63;
  const int w = tid >> 6;
  const int wr = w >> 1, wc = w & 1;
  const int bm = blockIdx.x * BM, bn = blockIdx.y * BN;
  f32x4 acc[FM][FN];
#pragma unroll
  for (int i = 0; i < FM; ++i)
#pragma unroll
    for (int j = 0; j < FN; ++j) acc[i][j] = 0.f;

  for (int k0 = 0; k0 < K; k0 += 32) {
#pragma unroll
    for (int u = 0; u < BM * 4 / 256; ++u) {
      const int q = tid + u * 256;
      const int m = q >> 2, c = q & 3;
      As[(m >> 4) * 64 + c * 16 + (m & 15)] =
          *(const float4*)&A[(size_t)(bm + m) * K + k0 + c * 8];
    }
#pragma unroll
    for (int u = 0; u < BN * 4 / 256; ++u) {
      const int q = tid + u * 256;
      const int n = q >> 2, c = q & 3;
      Bs[(n >> 4) * 64 + c * 16 + (n & 15)] =
          *(const float4*)&Bt[(size_t)(bn + n) * K + k0 + c * 8];
    }
    __syncthreads();
    bf16x8 af[FM], bfr[FN];
#pragma unroll
    for (int i = 0; i < FM; ++i) af[i] = *(const bf16x8*)&As[(wr * FM + i) * 64 + lane];
#pragma unroll
    for (int j = 0; j < FN; ++j) bfr[j] = *(const bf16x8*)&Bs[(wc * FN + j) * 64 + lane];
#pragma unroll
    for (int i = 0; i < FM; ++i)
#pragma unroll
      for (int j = 0; j < FN; ++j)
        acc[i][j] = __builtin_amdgcn_mfma_f32_16x16x32_bf16(af[i], bfr[j], acc[i][j], 0, 0, 0);
    __syncthreads();
  }
#pragma unroll
  for (int i = 0; i < FM; ++i) {
    const int r0 = bm + (wr * FM + i) * 16 + (lane >> 4) * 4;
#pragma unroll
    for (int j = 0; j < FN; ++j) {
      const int cc = bn + (wc * FN + j) * 16 + (lane & 15);
#pragma unroll
      for (int v = 0; v < 4; ++v) C[(size_t)(r0 + v) * N + cc] = acc[i][j][v];
    }
  }
}

// ---------------------------------------------------------------------------
extern "C" void kernel_launch(void* const* d_in, const int* in_sizes, int n_in,
                              void* d_out, int out_size, void* d_ws, size_t ws_size,
                              hipStream_t stream) {
  const float* hidden = (const float*)d_in[0];
  const float* wq     = (const float*)d_in[1];
  const float* qnw    = (const float*)d_in[2];
  const float* knw    = (const float*)d_in[3];
  const float* keys   = (const float*)d_in[4];
  const float* tcore  = (const float*)d_in[5];
  const float* tu     = (const float*)d_in[6];
  const float* tv     = (const float*)d_in[7];
  const float* values = (const float*)d_in[8];
  const float* wvm    = (const float*)d_in[9];
  const int*   shuf   = (const int*)d_in[10];
  float* out = (float*)d_out;

  char* ws = (char*)d_ws;
  size_t off = 0;
  auto alloc = [&](size_t bytes) -> void* {
    void* p = ws + off;
    off += (bytes + 255) & ~(size_t)255;
    return p;
  };
  float* Bct   = (float*)alloc((size_t)4096 * 256 * 4);      //  4 MB
  float* BctT  = (float*)alloc((size_t)256 * 4096 * 4);      //  4 MB
  float* Bg    = (float*)alloc((size_t)4096 * 512 * 4);      //  8 MB
  float* q12n  = (float*)alloc((size_t)8192 * 256 * 4);      //  8 MB
  float* q12nT = (float*)alloc((size_t)256 * 8192 * 4);      //  8 MB
  unsigned short* wvT  = (unsigned short*)alloc((size_t)2048 * 1024 * 2);  // 4 MB
  unsigned short* aggb = (unsigned short*)alloc((size_t)4096 * 1024 * 2);  // 8 MB
  int*   i1  = (int*)  alloc((size_t)8192 * 32 * 4);
  int*   i2  = (int*)  alloc((size_t)8192 * 32 * 4);
  float* g1  = (float*)alloc((size_t)8192 * 64 * 4);
  float* g2  = (float*)alloc((size_t)8192 * 64 * 4);
  float* wgt = (float*)alloc((size_t)8192 * 32 * 4);
  int*   sho = (int*)  alloc((size_t)8192 * 32 * 4);
  float* hiddenT = (float*)alloc((size_t)2048 * 4096 * 4);  // 32 MB
  float* big = (float*)alloc((size_t)8192 * 2048 * 4);      // 64 MB shared
  float* qpart = big;  // 8 x 4096 x 512 (64 MB), dead after k_ln_q
  float* s_r   = big;  // 8192 x 2048 (64 MB), written after
  (void)ws_size; (void)in_sizes; (void)n_in; (void)out_size;

  // 1) keys -> Bg (raw keysn) + Bct (u/v-combined)
  k_prep32<<<4096, 64, 0, stream>>>(keys, knw, tu, tv, Bct, Bg);
  // 2) wv -> bf16 transposed; Bct -> BctT; hidden -> hiddenT
  k_tcvt<<<dim3(16, 32), 256, 0, stream>>>(wvm, wvT, 1024, 2048);
  k_tr32<<<dim3(64, 4), 256, 0, stream>>>(Bct, BctT, 4096, 256);
  k_tr32<<<dim3(64, 32), 256, 0, stream>>>(hidden, hiddenT, 4096, 2048);
  // 3) q projection, f32 split-K=8: qpart[z] = hiddenT^T @ wq (K-slice z)
  k_gemm32<8><<<dim3(32, 4, 8), 256, 0, stream>>>(
      hiddenT, 4096, wq, 512, 0, 1 << 30, qpart, 4096, 512, 2048);
  // 4) sum partials + LN -> q12n; transpose
  k_ln_q<<<8192, 64, 0, stream>>>(qpart, qnw, q12n);
  k_tr32<<<dim3(128, 4), 256, 0, stream>>>(q12n, q12nT, 8192, 256);
  // 5) fused score GEMM: rows [0,4096)=side1 (B cols 0..2047),
  //    rows [4096,8192)=side2 (B cols 2048..4095)
  k_gemm32<1><<<dim3(64, 16, 1), 256, 0, stream>>>(
      q12nT, 8192, BctT, 4096, 2048, 4096, s_r, 8192, 2048, 256);
  // 6) stage-1 top-32 (both sides, bisection)
  k_topk1<<<16384, 64, 0, stream>>>(s_r, i1, i2);
  // 7) gather per-rank scores for selected keys (coalesced)
  k_gather<<<16384, 256, 0, stream>>>(q12n, Bg, i1, i2, g1, g2);
  // 8) stage-2 bisection top-32 + set-softmax + shuffle
  k_stage2<<<8192, 64, 0, stream>>>(g1, g2, i1, i2, tcore, shuf, wgt, sho);
  // 9) weighted value gather -> bf16 agg
  k_agg<<<4096, 256, 0, stream>>>(wgt, sho, values, aggb);
  // 10) output projection (bf16 MFMA)
  k_mfma<128, 128><<<dim3(32, 16), 256, 0, stream>>>(aggb, wvT, out, 4096, 2048, 1024);
}

// Round 9
// 465.608 us; speedup vs baseline: 9.9353x; 1.1754x over previous
//
#include <hip/hip_runtime.h>
#include <float.h>
#include <math.h>

// ---------------------------------------------------------------------------
// UltraMemLayerV1 — round 9:
//  (a) k_gather: TRUE line-dense mapping. Round-7 version had c4 stride 256B
//      so each instruction still touched 64 distinct lines; now the 4 lanes
//      of a group read consecutive 16B chunks (1 line/group/instruction).
//  (b) q GEMM split-K back to 4 (drop 64MB of qpart traffic), keep 2-phase.
// All other kernels identical to the passing round 8.
// ---------------------------------------------------------------------------

typedef __attribute__((ext_vector_type(8))) __bf16 bf16x8;
typedef __attribute__((ext_vector_type(4))) float f32x4;

__device__ __forceinline__ unsigned short f2bf(float x) {
  unsigned int u = __float_as_uint(x);
  return (unsigned short)((u + 0x7FFFu + ((u >> 16) & 1u)) >> 16);
}

__device__ __forceinline__ float wave_sum(float x) {
#pragma unroll
  for (int o = 32; o; o >>= 1) x += __shfl_xor(x, o, 64);
  return x;
}

__device__ __forceinline__ void gll16(const float* g, float* l) {
  __builtin_amdgcn_global_load_lds(
      (const __attribute__((address_space(1))) void*)g,
      (__attribute__((address_space(3))) void*)l, 16, 0, 0);
}

// monotone f32 -> u32 key (order-preserving) and inverse
__device__ __forceinline__ unsigned int f2key(float f) {
  const unsigned int u = __float_as_uint(f);
  return u ^ (((unsigned int)((int)u >> 31)) | 0x80000000u);
}
__device__ __forceinline__ float key2f(unsigned int k) {
  return __uint_as_float((k & 0x80000000u) ? (k ^ 0x80000000u) : ~k);
}

// ---------------- keys prep: LN over d, fold knorm + tucker u/v -------------
__global__ void k_prep32(const float* __restrict__ keys, const float* __restrict__ knw,
                         const float* __restrict__ tu, const float* __restrict__ tv,
                         float* __restrict__ Bct, float* __restrict__ Bg) {
  const int bid = blockIdx.x;  // 4096 = c*2048 + h*1024 + k
  const int lane = threadIdx.x;
  const int k = bid & 1023, h = (bid >> 10) & 1, c = bid >> 11;
  const float* base = keys + (size_t)((h * 2 + c) * 1024 + k) * 512;  // (h,c,k,d,r)
  float x0[4], x1[4];
  float s0 = 0.f, s1 = 0.f, sq0 = 0.f, sq1 = 0.f;
#pragma unroll
  for (int i = 0; i < 4; ++i) {
    const int d = lane + i * 64;
    const float2 p = *(const float2*)&base[d * 2];
    x0[i] = p.x; x1[i] = p.y;
    s0 += p.x; sq0 += p.x * p.x;
    s1 += p.y; sq1 += p.y * p.y;
  }
  s0 = wave_sum(s0); sq0 = wave_sum(sq0);
  s1 = wave_sum(s1); sq1 = wave_sum(sq1);
  const float m0 = s0 * (1.f / 256.f), m1 = s1 * (1.f / 256.f);
  const float rs0 = 1.f / sqrtf(sq0 * (1.f / 256.f) - m0 * m0 + 1e-5f);
  const float rs1 = 1.f / sqrtf(sq1 * (1.f / 256.f) - m1 * m1 + 1e-5f);
  const float* uv = c ? tv : tu;
  const float u0 = uv[h * 2 + 0], u1 = uv[h * 2 + 1];
  const int chk = c * 2048 + h * 1024 + k;
  float* bg = Bg + (size_t)chk * 512;
  float* bc = Bct + (size_t)chk * 256;
#pragma unroll
  for (int i = 0; i < 4; ++i) {
    const int d = lane + i * 64;
    const float w = knw[d];
    const float y0 = (x0[i] - m0) * rs0 * w;
    const float y1 = (x1[i] - m1) * rs1 * w;
    bg[d] = y0;
    bg[256 + d] = y1;
    bc[d] = y0 * u0 + y1 * u1;
  }
}

// ---------------- f32 transpose: src[R][C] -> dst[C][R] ---------------------
__global__ __launch_bounds__(256) void k_tr32(const float* __restrict__ src,
                                              float* __restrict__ dst, int R, int C) {
  __shared__ float t[64][65];
  const int br = blockIdx.x * 64, bc = blockIdx.y * 64;
  const int tid = threadIdx.x;
  for (int idx = tid; idx < 4096; idx += 256) {
    const int r = idx >> 6, c = idx & 63;
    t[r][c] = src[(size_t)(br + r) * C + bc + c];
  }
  __syncthreads();
  for (int idx = tid; idx < 4096; idx += 256) {
    const int cc = idx >> 6, rr = idx & 63;
    dst[(size_t)(bc + cc) * R + br + rr] = t[rr][cc];
  }
}

// ---------------- f32 GEMM, [K][*] operands, 2-phase prefetch dbuf ----------
template <int SPLITK>
__global__ __launch_bounds__(256) void k_gemm32(
    const float* __restrict__ AT, int lda,
    const float* __restrict__ BT, int ldb, int bsk, int m_split,
    float* __restrict__ C, int M, int N, int K) {
  constexpr int BK = 16;
  __shared__ float As[2][BK][128];
  __shared__ float Bs[2][BK][128];
  const int tid = threadIdx.x;
  const int lane = tid & 63;
  const int w = tid >> 6;
  const int tx = tid & 15, ty = tid >> 4;
  const int bm = blockIdx.x * 128, bn = blockIdx.y * 128;
  const int bcol = bn + ((bm >= m_split) ? bsk : 0);
  const int Ks = K / SPLITK;
  const int kbeg = blockIdx.z * Ks;
  float* Cp = C + (size_t)blockIdx.z * M * N;
  const int l5 = lane >> 5, l31 = lane & 31;
  float acc[8][8] = {};

  auto stage = [&](int buf, int t) {
    const int k0 = t * BK;
#pragma unroll
    for (int i = 0; i < 2; ++i) {
      const int rr = w * 4 + i * 2;
      const size_t krow = (size_t)(kbeg + k0 + rr + l5);
      gll16(&AT[krow * lda + bm + l31 * 4], &As[buf][rr][0]);
      gll16(&BT[krow * ldb + bcol + l31 * 4], &Bs[buf][rr][0]);
    }
  };

  const int T = Ks / BK;
  stage(0, 0);
  __syncthreads();
  int cur = 0;
  for (int t = 0; t < T; ++t) {
    if (t + 1 < T) stage(cur ^ 1, t + 1);  // prefetch under compute
#pragma unroll
    for (int kk = 0; kk < BK; ++kk) {
      float a[8], b[8];
      *(float4*)&a[0] = *(const float4*)&As[cur][kk][ty * 4];
      *(float4*)&a[4] = *(const float4*)&As[cur][kk][64 + ty * 4];
      *(float4*)&b[0] = *(const float4*)&Bs[cur][kk][tx * 4];
      *(float4*)&b[4] = *(const float4*)&Bs[cur][kk][64 + tx * 4];
#pragma unroll
      for (int i = 0; i < 8; ++i)
#pragma unroll
        for (int j = 0; j < 8; ++j) acc[i][j] += a[i] * b[j];
    }
    __syncthreads();
    cur ^= 1;
  }
#pragma unroll
  for (int ih = 0; ih < 2; ++ih)
#pragma unroll
    for (int i = 0; i < 4; ++i) {
      const size_t r = bm + ih * 64 + ty * 4 + i;
#pragma unroll
      for (int jh = 0; jh < 2; ++jh) {
        float4 v = {acc[ih * 4 + i][jh * 4 + 0], acc[ih * 4 + i][jh * 4 + 1],
                    acc[ih * 4 + i][jh * 4 + 2], acc[ih * 4 + i][jh * 4 + 3]};
        *(float4*)&Cp[r * N + bn + jh * 64 + tx * 4] = v;
      }
    }
}

// ---------------- q: sum split-K partials (4) + LN -> q12n ------------------
__global__ void k_ln_q(const float* __restrict__ qpart, const float* __restrict__ qnw,
                       float* __restrict__ q12n) {
  const int bid = blockIdx.x;  // b*2 + c
  const int lane = threadIdx.x;
  const int b = bid >> 1, c = bid & 1;
  float x[4] = {};
#pragma unroll
  for (int s = 0; s < 4; ++s) {
    const float4 p = *(const float4*)&qpart[(size_t)s * 4096 * 512 + (size_t)b * 512 + c * 256 + lane * 4];
    x[0] += p.x; x[1] += p.y; x[2] += p.z; x[3] += p.w;
  }
  float sm = x[0] + x[1] + x[2] + x[3];
  float sq = x[0] * x[0] + x[1] * x[1] + x[2] * x[2] + x[3] * x[3];
  sm = wave_sum(sm);
  sq = wave_sum(sq);
  const float mean = sm * (1.f / 256.f);
  const float rs = 1.f / sqrtf(sq * (1.f / 256.f) - mean * mean + 1e-5f);
  const float4 w4 = *(const float4*)&qnw[lane * 4];
  float4 o;
  o.x = (x[0] - mean) * rs * w4.x;
  o.y = (x[1] - mean) * rs * w4.y;
  o.z = (x[2] - mean) * rs * w4.z;
  o.w = (x[3] - mean) * rs * w4.w;
  *(float4*)&q12n[(size_t)(c * 4096 + b) * 256 + lane * 4] = o;
}

// ---------------- stage-1 top-32 via exact radix bisection ------------------
__global__ void k_topk1(const float* __restrict__ s_r,
                        int* __restrict__ i1, int* __restrict__ i2) {
  const int bid = blockIdx.x;  // side*8192 + b*2 + h
  const int side = bid >> 13;
  const int bh = bid & 8191;
  const int b = bh >> 1, h = bh & 1;
  const int lane = threadIdx.x;
  const float* row = s_r + (size_t)(side * 4096 + b) * 2048 + h * 1024;
  unsigned int ku[16];
#pragma unroll
  for (int i = 0; i < 16; ++i) ku[i] = f2key(row[lane + (i << 6)]);
  unsigned int T = 0u;
  for (int bpos = 31; bpos >= 0; --bpos) {
    const unsigned int cand = T | (1u << bpos);
    int c = 0;
#pragma unroll
    for (int i = 0; i < 16; ++i) c += (ku[i] >= cand) ? 1 : 0;
#pragma unroll
    for (int o = 32; o; o >>= 1) c += __shfl_xor(c, o, 64);
    if (c >= 32) T = cand;
  }
  int cgt = 0, ceq = 0;
#pragma unroll
  for (int i = 0; i < 16; ++i) {
    cgt += (ku[i] > T) ? 1 : 0;
    ceq += (ku[i] == T) ? 1 : 0;
  }
  int pgt = cgt, peq = ceq;
#pragma unroll
  for (int o = 1; o < 64; o <<= 1) {
    const int t1 = __shfl_up(pgt, o, 64);
    const int t2 = __shfl_up(peq, o, 64);
    if (lane >= o) { pgt += t1; peq += t2; }
  }
  const int total_gt = __shfl(pgt, 63, 64);
  const int need_eq = 32 - total_gt;
  int sgt = pgt - cgt;
  int seq = peq - ceq;
  int* iout = (side ? i2 : i1) + bh * 32;
#pragma unroll
  for (int i = 0; i < 16; ++i) {
    const int idx = (i << 6) + lane;
    if (ku[i] > T) {
      iout[sgt++] = idx;
    } else if (ku[i] == T) {
      if (seq < need_eq) iout[total_gt + seq] = idx;
      ++seq;
    }
  }
}

// ---------------- gather per-rank scores for selected keys (line-dense) -----
// 256 threads per (side,b,h). 4 lanes (c4) per selected (row = slot*2 + r);
// at each unrolled step the 4 lanes read CONSECUTIVE float4 chunks ->
// exactly one 64B line per group per instruction (16 lines/wave-instr).
__global__ __launch_bounds__(256) void k_gather(
    const float* __restrict__ q12n, const float* __restrict__ Bg,
    const int* __restrict__ i1, const int* __restrict__ i2,
    float* __restrict__ g1, float* __restrict__ g2) {
  __shared__ float qs[256];
  __shared__ int ssel[32];
  const int bid = blockIdx.x;  // side*8192 + b*2 + h
  const int side = bid >> 13;
  const int bh = bid & 8191;
  const int b = bh >> 1, h = bh & 1;
  const int tid = threadIdx.x;
  if (tid < 64) {
    *(float4*)&qs[tid * 4] =
        *(const float4*)&q12n[(size_t)(side * 4096 + b) * 256 + tid * 4];
  } else if (tid < 96) {
    ssel[tid - 64] = (side ? i2 : i1)[bh * 32 + (tid - 64)];
  }
  __syncthreads();
  const int j = tid >> 2;    // 0..63 = slot*2 + r
  const int c4 = tid & 3;    // 16B sub-chunk within each 64B line
  const int slot = j >> 1, r = j & 1;
  const int sel = ssel[slot];
  const float* krow =
      Bg + ((size_t)(side * 2048 + h * 1024 + sel) * 2 + r) * 256;
  float px = 0.f, py = 0.f, pz = 0.f, pw = 0.f;
#pragma unroll
  for (int i = 0; i < 16; ++i) {
    const int e = (i * 4 + c4) * 4;  // group of 4 lanes covers one 64B line
    const float4 kv = *(const float4*)&krow[e];
    const float4 qv = *(const float4*)&qs[e];  // same addr per group: broadcast
    px += kv.x * qv.x;
    py += kv.y * qv.y;
    pz += kv.z * qv.z;
    pw += kv.w * qv.w;
  }
  float acc = (px + py) + (pz + pw);
  acc += __shfl_xor(acc, 1, 64);
  acc += __shfl_xor(acc, 2, 64);
  if (c4 == 0) (side ? g2 : g1)[(bh * 32 + slot) * 2 + r] = acc;
}

// ---------------- stage-2: bilinear scores, bisection top-32, set-softmax ---
__global__ void k_stage2(const float* __restrict__ g1, const float* __restrict__ g2,
                         const int* __restrict__ i1, const int* __restrict__ i2,
                         const float* __restrict__ tucker_core,
                         const int* __restrict__ shuffle_index,
                         float* __restrict__ w_out, int* __restrict__ sh_out) {
  __shared__ float sg1x[32], sg1y[32], sg2x[32], sg2y[32];
  __shared__ int si1[32], si2[32];
  const int bh = blockIdx.x;
  const int h = bh & 1;
  const int lane = threadIdx.x;
  if (lane < 32) {
    const float2 p1 = *(const float2*)&g1[(bh * 32 + lane) * 2];
    const float2 p2 = *(const float2*)&g2[(bh * 32 + lane) * 2];
    sg1x[lane] = p1.x;
    sg1y[lane] = p1.y;
    sg2x[lane] = p2.x;
    sg2y[lane] = p2.y;
    si1[lane] = i1[bh * 32 + lane];
    si2[lane] = i2[bh * 32 + lane];
  }
  __syncthreads();
  const float c00 = tucker_core[h * 4 + 0] + tucker_core[8 + h * 4 + 0];
  const float c01 = tucker_core[h * 4 + 1] + tucker_core[8 + h * 4 + 1];
  const float c10 = tucker_core[h * 4 + 2] + tucker_core[8 + h * 4 + 2];
  const float c11 = tucker_core[h * 4 + 3] + tucker_core[8 + h * 4 + 3];
  float sv[16];
  unsigned int ku[16];
  float m = -FLT_MAX;
#pragma unroll
  for (int i = 0; i < 16; ++i) {
    const int p = lane + (i << 6);
    const int k = p >> 5, l = p & 31;
    const float a0 = sg1x[k] * c00 + sg1y[k] * c10;
    const float a1 = sg1x[k] * c01 + sg1y[k] * c11;
    sv[i] = a0 * sg2x[l] + a1 * sg2y[l];
    ku[i] = f2key(sv[i]);
    m = fmaxf(m, sv[i]);
  }
#pragma unroll
  for (int o = 32; o; o >>= 1) m = fmaxf(m, __shfl_xor(m, o, 64));
  unsigned int T = 0u;
  for (int bpos = 31; bpos >= 0; --bpos) {
    const unsigned int cand = T | (1u << bpos);
    int c = 0;
#pragma unroll
    for (int i = 0; i < 16; ++i) c += (ku[i] >= cand) ? 1 : 0;
#pragma unroll
    for (int o = 32; o; o >>= 1) c += __shfl_xor(c, o, 64);
    if (c >= 32) T = cand;
  }
  int cgt = 0, ceq = 0;
  float zp = 0.f;
#pragma unroll
  for (int i = 0; i < 16; ++i) {
    if (ku[i] > T) { ++cgt; zp += expf(sv[i] - m); }
    ceq += (ku[i] == T) ? 1 : 0;
  }
  int pgt = cgt, peq = ceq;
#pragma unroll
  for (int o = 1; o < 64; o <<= 1) {
    const int t1 = __shfl_up(pgt, o, 64);
    const int t2 = __shfl_up(peq, o, 64);
    if (lane >= o) { pgt += t1; peq += t2; }
  }
  const int total_gt = __shfl(pgt, 63, 64);
  const int need_eq = 32 - total_gt;
  const float eT = expf(key2f(T) - m);
  const float Z = wave_sum(zp) + (float)need_eq * eT;
  const float rZ = 1.f / Z;
  int sgt = pgt - cgt;
  int seq = peq - ceq;
  float* wp = w_out + bh * 32;
  int* shp = sh_out + bh * 32;
#pragma unroll
  for (int i = 0; i < 16; ++i) {
    int slot = -1;
    if (ku[i] > T) {
      slot = sgt++;
    } else if (ku[i] == T) {
      if (seq < need_eq) slot = total_gt + seq;
      ++seq;
    }
    if (slot >= 0) {
      const int p = lane + (i << 6);
      const int k = p >> 5, l = p & 31;
      const int ai = si1[k] * 1024 + si2[l];
      wp[slot] = expf(sv[i] - m) * rZ;
      shp[slot] = shuffle_index[ai];  // = (eidx<<18) | vidx
    }
  }
}

// ---------------- weighted value gather/aggregate -> bf16 agg ---------------
__global__ __launch_bounds__(256) void k_agg(const float* __restrict__ w_out,
                                             const int* __restrict__ sh_out,
                                             const float* __restrict__ values,
                                             unsigned short* __restrict__ aggb) {
  __shared__ float acc[4][1024];
  const int b = blockIdx.x;
  const int tid = threadIdx.x;
  const int wave = tid >> 6, lane = tid & 63;
  for (int i = tid; i < 4096; i += 256) ((float*)acc)[i] = 0.f;
  __syncthreads();
  for (int j = wave; j < 64; j += 4) {
    const float wgt = w_out[b * 64 + j];
    const int sh = sh_out[b * 64 + j];
    const int vidx = sh & 0x3FFFF;
    const int e = sh >> 18;
    const float4 v = *(const float4*)&values[(size_t)vidx * 256 + lane * 4];
    float* dst = &acc[wave][e * 256 + lane * 4];
    dst[0] += wgt * v.x;
    dst[1] += wgt * v.y;
    dst[2] += wgt * v.z;
    dst[3] += wgt * v.w;
  }
  __syncthreads();
  for (int i = tid; i < 1024; i += 256)
    aggb[(size_t)b * 1024 + i] = f2bf(acc[0][i] + acc[1][i] + acc[2][i] + acc[3][i]);
}

// ---------------- transpose + convert f32 -> bf16 (for wv) ------------------
__global__ __launch_bounds__(256) void k_tcvt(const float* __restrict__ src,
                                              unsigned short* __restrict__ dst,
                                              int R, int C) {
  __shared__ float tile[64][65];
  const int br = blockIdx.x * 64;
  const int bc = blockIdx.y * 64;
  const int tid = threadIdx.x;
  for (int idx = tid; idx < 4096; idx += 256) {
    const int r = idx >> 6, c = idx & 63;
    tile[r][c] = src[(size_t)(br + r) * C + bc + c];
  }
  __syncthreads();
  for (int idx = tid; idx < 4096; idx += 256) {
    const int cc = idx >> 6, rr = idx & 63;
    dst[(size_t)(bc + cc) * R + br + rr] = f2bf(tile[rr][cc]);
  }
}

// ---------------- bf16 MFMA GEMM (final projection) -------------------------
template <int BM, int BN>
__global__ __launch_bounds__(256) void k_mfma(const unsigned short* __restrict__ A,
                                              const unsigned short* __restrict__ Bt,
                                              float* __restrict__ C,
                                              int M, int N, int K) {
  constexpr int FM = BM / 32;
  constexpr int FN = BN / 32;
  __shared__ float4 As[BM * 4];
  __shared__ float4 Bs[BN * 4];
  const int tid = threadIdx.x;
  const int lane = tid & 63;
  const int w = tid >> 6;
  const int wr = w >> 1, wc = w & 1;
  const int bm = blockIdx.x * BM, bn = blockIdx.y * BN;
  f32x4 acc[FM][FN];
#pragma unroll
  for (int i = 0; i < FM; ++i)
#pragma unroll
    for (int j = 0; j < FN; ++j) acc[i][j] = 0.f;

  for (int k0 = 0; k0 < K; k0 += 32) {
#pragma unroll
    for (int u = 0; u < BM * 4 / 256; ++u) {
      const int q = tid + u * 256;
      const int m = q >> 2, c = q & 3;
      As[(m >> 4) * 64 + c * 16 + (m & 15)] =
          *(const float4*)&A[(size_t)(bm + m) * K + k0 + c * 8];
    }
#pragma unroll
    for (int u = 0; u < BN * 4 / 256; ++u) {
      const int q = tid + u * 256;
      const int n = q >> 2, c = q & 3;
      Bs[(n >> 4) * 64 + c * 16 + (n & 15)] =
          *(const float4*)&Bt[(size_t)(bn + n) * K + k0 + c * 8];
    }
    __syncthreads();
    bf16x8 af[FM], bfr[FN];
#pragma unroll
    for (int i = 0; i < FM; ++i) af[i] = *(const bf16x8*)&As[(wr * FM + i) * 64 + lane];
#pragma unroll
    for (int j = 0; j < FN; ++j) bfr[j] = *(const bf16x8*)&Bs[(wc * FN + j) * 64 + lane];
#pragma unroll
    for (int i = 0; i < FM; ++i)
#pragma unroll
      for (int j = 0; j < FN; ++j)
        acc[i][j] = __builtin_amdgcn_mfma_f32_16x16x32_bf16(af[i], bfr[j], acc[i][j], 0, 0, 0);
    __syncthreads();
  }
#pragma unroll
  for (int i = 0; i < FM; ++i) {
    const int r0 = bm + (wr * FM + i) * 16 + (lane >> 4) * 4;
#pragma unroll
    for (int j = 0; j < FN; ++j) {
      const int cc = bn + (wc * FN + j) * 16 + (lane & 15);
#pragma unroll
      for (int v = 0; v < 4; ++v) C[(size_t)(r0 + v) * N + cc] = acc[i][j][v];
    }
  }
}

// ---------------------------------------------------------------------------
extern "C" void kernel_launch(void* const* d_in, const int* in_sizes, int n_in,
                              void* d_out, int out_size, void* d_ws, size_t ws_size,
                              hipStream_t stream) {
  const float* hidden = (const float*)d_in[0];
  const float* wq     = (const float*)d_in[1];
  const float* qnw    = (const float*)d_in[2];
  const float* knw    = (const float*)d_in[3];
  const float* keys   = (const float*)d_in[4];
  const float* tcore  = (const float*)d_in[5];
  const float* tu     = (const float*)d_in[6];
  const float* tv     = (const float*)d_in[7];
  const float* values = (const float*)d_in[8];
  const float* wvm    = (const float*)d_in[9];
  const int*   shuf   = (const int*)d_in[10];
  float* out = (float*)d_out;

  char* ws = (char*)d_ws;
  size_t off = 0;
  auto alloc = [&](size_t bytes) -> void* {
    void* p = ws + off;
    off += (bytes + 255) & ~(size_t)255;
    return p;
  };
  float* Bct   = (float*)alloc((size_t)4096 * 256 * 4);      //  4 MB
  float* BctT  = (float*)alloc((size_t)256 * 4096 * 4);      //  4 MB
  float* Bg    = (float*)alloc((size_t)4096 * 512 * 4);      //  8 MB
  float* q12n  = (float*)alloc((size_t)8192 * 256 * 4);      //  8 MB
  float* q12nT = (float*)alloc((size_t)256 * 8192 * 4);      //  8 MB
  unsigned short* wvT  = (unsigned short*)alloc((size_t)2048 * 1024 * 2);  // 4 MB
  unsigned short* aggb = (unsigned short*)alloc((size_t)4096 * 1024 * 2);  // 8 MB
  int*   i1  = (int*)  alloc((size_t)8192 * 32 * 4);
  int*   i2  = (int*)  alloc((size_t)8192 * 32 * 4);
  float* g1  = (float*)alloc((size_t)8192 * 64 * 4);
  float* g2  = (float*)alloc((size_t)8192 * 64 * 4);
  float* wgt = (float*)alloc((size_t)8192 * 32 * 4);
  int*   sho = (int*)  alloc((size_t)8192 * 32 * 4);
  float* hiddenT = (float*)alloc((size_t)2048 * 4096 * 4);  // 32 MB
  float* big = (float*)alloc((size_t)8192 * 2048 * 4);      // 64 MB shared
  float* qpart = big;  // 4 x 4096 x 512 (32 MB), dead after k_ln_q
  float* s_r   = big;  // 8192 x 2048 (64 MB), written after
  (void)ws_size; (void)in_sizes; (void)n_in; (void)out_size;

  // 1) keys -> Bg (raw keysn) + Bct (u/v-combined)
  k_prep32<<<4096, 64, 0, stream>>>(keys, knw, tu, tv, Bct, Bg);
  // 2) wv -> bf16 transposed; Bct -> BctT; hidden -> hiddenT
  k_tcvt<<<dim3(16, 32), 256, 0, stream>>>(wvm, wvT, 1024, 2048);
  k_tr32<<<dim3(64, 4), 256, 0, stream>>>(Bct, BctT, 4096, 256);
  k_tr32<<<dim3(64, 32), 256, 0, stream>>>(hidden, hiddenT, 4096, 2048);
  // 3) q projection, f32 split-K=4: qpart[z] = hiddenT^T @ wq (K-slice z)
  k_gemm32<4><<<dim3(32, 4, 4), 256, 0, stream>>>(
      hiddenT, 4096, wq, 512, 0, 1 << 30, qpart, 4096, 512, 2048);
  // 4) sum partials + LN -> q12n; transpose
  k_ln_q<<<8192, 64, 0, stream>>>(qpart, qnw, q12n);
  k_tr32<<<dim3(128, 4), 256, 0, stream>>>(q12n, q12nT, 8192, 256);
  // 5) fused score GEMM: rows [0,4096)=side1 (B cols 0..2047),
  //    rows [4096,8192)=side2 (B cols 2048..4095)
  k_gemm32<1><<<dim3(64, 16, 1), 256, 0, stream>>>(
      q12nT, 8192, BctT, 4096, 2048, 4096, s_r, 8192, 2048, 256);
  // 6) stage-1 top-32 (both sides, bisection)
  k_topk1<<<16384, 64, 0, stream>>>(s_r, i1, i2);
  // 7) gather per-rank scores for selected keys (line-dense)
  k_gather<<<16384, 256, 0, stream>>>(q12n, Bg, i1, i2, g1, g2);
  // 8) stage-2 bisection top-32 + set-softmax + shuffle
  k_stage2<<<8192, 64, 0, stream>>>(g1, g2, i1, i2, tcore, shuf, wgt, sho);
  // 9) weighted value gather -> bf16 agg
  k_agg<<<4096, 256, 0, stream>>>(wgt, sho, values, aggb);
  // 10) output projection (bf16 MFMA)
  k_mfma<128, 128><<<dim3(32, 16), 256, 0, stream>>>(aggb, wvT, out, 4096, 2048, 1024);
}

// Round 10
// 393.118 us; speedup vs baseline: 11.7674x; 1.1844x over previous
//
#include <hip/hip_runtime.h>
#include <float.h>
#include <math.h>

// ---------------------------------------------------------------------------
// UltraMemLayerV1 — round 10: bf16-MFMA prefilter for stage-1 selection.
//   score GEMM: plain-bf16 MFMA (q12bf [M][K] @ Bctbf [N][K]) -> s_r f32.
//     Margin: rank32-rank48 gap ~0.2*sigma >> bf16 score err ~4e-3*sigma,
//     so true f32 top-32 is inside bf16 top-48 (50-sigma margin).
//   k_topk1: bf16 top-48 per (side,b,h), ballot/popc-counted bisection.
//   k_sel:   exact f32 rescore of the 48 candidates (line-dense Bg reads),
//            exact top-32 via single-ballot bisection, emits i1/i2/g1/g2.
//   q GEMM stays f32 (no margin for q error). stage2: ballot counting.
// ---------------------------------------------------------------------------

typedef __attribute__((ext_vector_type(8))) __bf16 bf16x8;
typedef __attribute__((ext_vector_type(4))) float f32x4;

__device__ __forceinline__ unsigned short f2bf(float x) {
  unsigned int u = __float_as_uint(x);
  return (unsigned short)((u + 0x7FFFu + ((u >> 16) & 1u)) >> 16);
}

__device__ __forceinline__ float wave_sum(float x) {
#pragma unroll
  for (int o = 32; o; o >>= 1) x += __shfl_xor(x, o, 64);
  return x;
}

__device__ __forceinline__ void gll16(const float* g, float* l) {
  __builtin_amdgcn_global_load_lds(
      (const __attribute__((address_space(1))) void*)g,
      (__attribute__((address_space(3))) void*)l, 16, 0, 0);
}

// monotone f32 -> u32 key (order-preserving) and inverse
__device__ __forceinline__ unsigned int f2key(float f) {
  const unsigned int u = __float_as_uint(f);
  return u ^ (((unsigned int)((int)u >> 31)) | 0x80000000u);
}
__device__ __forceinline__ float key2f(unsigned int k) {
  return __uint_as_float((k & 0x80000000u) ? (k ^ 0x80000000u) : ~k);
}

// ---------------- keys prep: LN, fold knorm + tucker u/v; bf16 Bct ----------
__global__ void k_prep32(const float* __restrict__ keys, const float* __restrict__ knw,
                         const float* __restrict__ tu, const float* __restrict__ tv,
                         unsigned short* __restrict__ Bctbf, float* __restrict__ Bg) {
  const int bid = blockIdx.x;  // 4096 = c*2048 + h*1024 + k
  const int lane = threadIdx.x;
  const int k = bid & 1023, h = (bid >> 10) & 1, c = bid >> 11;
  const float* base = keys + (size_t)((h * 2 + c) * 1024 + k) * 512;  // (h,c,k,d,r)
  float x0[4], x1[4];
  float s0 = 0.f, s1 = 0.f, sq0 = 0.f, sq1 = 0.f;
#pragma unroll
  for (int i = 0; i < 4; ++i) {
    const int d = lane + i * 64;
    const float2 p = *(const float2*)&base[d * 2];
    x0[i] = p.x; x1[i] = p.y;
    s0 += p.x; sq0 += p.x * p.x;
    s1 += p.y; sq1 += p.y * p.y;
  }
  s0 = wave_sum(s0); sq0 = wave_sum(sq0);
  s1 = wave_sum(s1); sq1 = wave_sum(sq1);
  const float m0 = s0 * (1.f / 256.f), m1 = s1 * (1.f / 256.f);
  const float rs0 = 1.f / sqrtf(sq0 * (1.f / 256.f) - m0 * m0 + 1e-5f);
  const float rs1 = 1.f / sqrtf(sq1 * (1.f / 256.f) - m1 * m1 + 1e-5f);
  const float* uv = c ? tv : tu;
  const float u0 = uv[h * 2 + 0], u1 = uv[h * 2 + 1];
  const int chk = c * 2048 + h * 1024 + k;
  float* bg = Bg + (size_t)chk * 512;
  unsigned short* bc = Bctbf + (size_t)chk * 256;
#pragma unroll
  for (int i = 0; i < 4; ++i) {
    const int d = lane + i * 64;
    const float w = knw[d];
    const float y0 = (x0[i] - m0) * rs0 * w;
    const float y1 = (x1[i] - m1) * rs1 * w;
    bg[d] = y0;
    bg[256 + d] = y1;
    bc[d] = f2bf(y0 * u0 + y1 * u1);
  }
}

// ---------------- f32 transpose: src[R][C] -> dst[C][R] ---------------------
__global__ __launch_bounds__(256) void k_tr32(const float* __restrict__ src,
                                              float* __restrict__ dst, int R, int C) {
  __shared__ float t[64][65];
  const int br = blockIdx.x * 64, bc = blockIdx.y * 64;
  const int tid = threadIdx.x;
  for (int idx = tid; idx < 4096; idx += 256) {
    const int r = idx >> 6, c = idx & 63;
    t[r][c] = src[(size_t)(br + r) * C + bc + c];
  }
  __syncthreads();
  for (int idx = tid; idx < 4096; idx += 256) {
    const int cc = idx >> 6, rr = idx & 63;
    dst[(size_t)(bc + cc) * R + br + rr] = t[rr][cc];
  }
}

// ---------------- f32 GEMM, [K][*] operands, 2-phase prefetch dbuf ----------
template <int SPLITK>
__global__ __launch_bounds__(256) void k_gemm32(
    const float* __restrict__ AT, int lda,
    const float* __restrict__ BT, int ldb, int bsk, int m_split,
    float* __restrict__ C, int M, int N, int K) {
  constexpr int BK = 16;
  __shared__ float As[2][BK][128];
  __shared__ float Bs[2][BK][128];
  const int tid = threadIdx.x;
  const int lane = tid & 63;
  const int w = tid >> 6;
  const int tx = tid & 15, ty = tid >> 4;
  const int bm = blockIdx.x * 128, bn = blockIdx.y * 128;
  const int bcol = bn + ((bm >= m_split) ? bsk : 0);
  const int Ks = K / SPLITK;
  const int kbeg = blockIdx.z * Ks;
  float* Cp = C + (size_t)blockIdx.z * M * N;
  const int l5 = lane >> 5, l31 = lane & 31;
  float acc[8][8] = {};

  auto stage = [&](int buf, int t) {
    const int k0 = t * BK;
#pragma unroll
    for (int i = 0; i < 2; ++i) {
      const int rr = w * 4 + i * 2;
      const size_t krow = (size_t)(kbeg + k0 + rr + l5);
      gll16(&AT[krow * lda + bm + l31 * 4], &As[buf][rr][0]);
      gll16(&BT[krow * ldb + bcol + l31 * 4], &Bs[buf][rr][0]);
    }
  };

  const int T = Ks / BK;
  stage(0, 0);
  __syncthreads();
  int cur = 0;
  for (int t = 0; t < T; ++t) {
    if (t + 1 < T) stage(cur ^ 1, t + 1);  // prefetch under compute
#pragma unroll
    for (int kk = 0; kk < BK; ++kk) {
      float a[8], b[8];
      *(float4*)&a[0] = *(const float4*)&As[cur][kk][ty * 4];
      *(float4*)&a[4] = *(const float4*)&As[cur][kk][64 + ty * 4];
      *(float4*)&b[0] = *(const float4*)&Bs[cur][kk][tx * 4];
      *(float4*)&b[4] = *(const float4*)&Bs[cur][kk][64 + tx * 4];
#pragma unroll
      for (int i = 0; i < 8; ++i)
#pragma unroll
        for (int j = 0; j < 8; ++j) acc[i][j] += a[i] * b[j];
    }
    __syncthreads();
    cur ^= 1;
  }
#pragma unroll
  for (int ih = 0; ih < 2; ++ih)
#pragma unroll
    for (int i = 0; i < 4; ++i) {
      const size_t r = bm + ih * 64 + ty * 4 + i;
#pragma unroll
      for (int jh = 0; jh < 2; ++jh) {
        float4 v = {acc[ih * 4 + i][jh * 4 + 0], acc[ih * 4 + i][jh * 4 + 1],
                    acc[ih * 4 + i][jh * 4 + 2], acc[ih * 4 + i][jh * 4 + 3]};
        *(float4*)&Cp[r * N + bn + jh * 64 + tx * 4] = v;
      }
    }
}

// ---------------- q: sum split-K partials (4) + LN -> q12n (f32 + bf16) -----
__global__ void k_ln_q(const float* __restrict__ qpart, const float* __restrict__ qnw,
                       float* __restrict__ q12n, unsigned short* __restrict__ q12bf) {
  const int bid = blockIdx.x;  // b*2 + c
  const int lane = threadIdx.x;
  const int b = bid >> 1, c = bid & 1;
  float x[4] = {};
#pragma unroll
  for (int s = 0; s < 4; ++s) {
    const float4 p = *(const float4*)&qpart[(size_t)s * 4096 * 512 + (size_t)b * 512 + c * 256 + lane * 4];
    x[0] += p.x; x[1] += p.y; x[2] += p.z; x[3] += p.w;
  }
  float sm = x[0] + x[1] + x[2] + x[3];
  float sq = x[0] * x[0] + x[1] * x[1] + x[2] * x[2] + x[3] * x[3];
  sm = wave_sum(sm);
  sq = wave_sum(sq);
  const float mean = sm * (1.f / 256.f);
  const float rs = 1.f / sqrtf(sq * (1.f / 256.f) - mean * mean + 1e-5f);
  const float4 w4 = *(const float4*)&qnw[lane * 4];
  float4 o;
  o.x = (x[0] - mean) * rs * w4.x;
  o.y = (x[1] - mean) * rs * w4.y;
  o.z = (x[2] - mean) * rs * w4.z;
  o.w = (x[3] - mean) * rs * w4.w;
  const size_t base = (size_t)(c * 4096 + b) * 256 + lane * 4;
  *(float4*)&q12n[base] = o;
  ushort4 ob;
  ob.x = f2bf(o.x); ob.y = f2bf(o.y); ob.z = f2bf(o.z); ob.w = f2bf(o.w);
  *(ushort4*)&q12bf[base] = ob;
}

// ---------------- stage-1 top-48 prefilter (ballot-counted bisection) -------
__global__ void k_topk1(const float* __restrict__ s_r,
                        int* __restrict__ i1c, int* __restrict__ i2c) {
  const int bid = blockIdx.x;  // side*8192 + b*2 + h
  const int side = bid >> 13;
  const int bh = bid & 8191;
  const int b = bh >> 1, h = bh & 1;
  const int lane = threadIdx.x;
  const float* row = s_r + (size_t)(side * 4096 + b) * 2048 + h * 1024;
  unsigned int ku[16];
#pragma unroll
  for (int i = 0; i < 16; ++i) ku[i] = f2key(row[lane + (i << 6)]);
  unsigned int T = 0u;
  for (int bpos = 31; bpos >= 0; --bpos) {
    const unsigned int cand = T | (1u << bpos);
    int c = 0;
#pragma unroll
    for (int i = 0; i < 16; ++i) c += (int)__popcll(__ballot(ku[i] >= cand));
    if (c >= 48) T = cand;  // uniform
  }
  int cgt = 0, ceq = 0;
#pragma unroll
  for (int i = 0; i < 16; ++i) {
    cgt += (ku[i] > T) ? 1 : 0;
    ceq += (ku[i] == T) ? 1 : 0;
  }
  int pgt = cgt, peq = ceq;
#pragma unroll
  for (int o = 1; o < 64; o <<= 1) {
    const int t1 = __shfl_up(pgt, o, 64);
    const int t2 = __shfl_up(peq, o, 64);
    if (lane >= o) { pgt += t1; peq += t2; }
  }
  const int total_gt = __shfl(pgt, 63, 64);  // < 48
  const int need_eq = 48 - total_gt;
  int sgt = pgt - cgt;
  int seq = peq - ceq;
  int* iout = (side ? i2c : i1c) + bh * 48;
#pragma unroll
  for (int i = 0; i < 16; ++i) {
    const int idx = (i << 6) + lane;
    if (ku[i] > T) {
      iout[sgt++] = idx;
    } else if (ku[i] == T) {
      if (seq < need_eq) iout[total_gt + seq] = idx;
      ++seq;
    }
  }
}

// ---------------- exact rescore of 48 candidates + exact top-32 -------------
// 256 thr per (side,b,h): 4-lane groups do line-dense f32 dots for both
// ranks; wave 0 bisects top-32 of the 48 combined scores (1 cand/lane).
__global__ __launch_bounds__(256) void k_sel(
    const float* __restrict__ q12n, const float* __restrict__ Bg,
    const int* __restrict__ i1c, const int* __restrict__ i2c,
    const float* __restrict__ tu, const float* __restrict__ tv,
    int* __restrict__ i1, int* __restrict__ i2,
    float* __restrict__ g1, float* __restrict__ g2) {
  __shared__ float qs[256];
  __shared__ int ssel[48];
  __shared__ float sc[48], sd0[48], sd1[48];
  const int bid = blockIdx.x;  // side*8192 + b*2 + h
  const int side = bid >> 13;
  const int bh = bid & 8191;
  const int b = bh >> 1, h = bh & 1;
  const int tid = threadIdx.x;
  if (tid < 64) {
    *(float4*)&qs[tid * 4] =
        *(const float4*)&q12n[(size_t)(side * 4096 + b) * 256 + tid * 4];
  } else if (tid < 112) {
    ssel[tid - 64] = (side ? i2c : i1c)[bh * 48 + (tid - 64)];
  }
  __syncthreads();
  const int g = tid >> 2, c4 = tid & 3;
  if (g < 48) {
    const int sel = ssel[g];
    const float* kbase = Bg + (size_t)((side * 2048 + h * 1024 + sel) * 2) * 256;
    float d0 = 0.f, d1 = 0.f;
#pragma unroll
    for (int r = 0; r < 2; ++r) {
      const float* krow = kbase + r * 256;
      float px = 0.f, py = 0.f, pz = 0.f, pw = 0.f;
#pragma unroll
      for (int i = 0; i < 16; ++i) {
        const int e = (i * 4 + c4) * 4;  // 4-lane group covers one 64B line
        const float4 kv = *(const float4*)&krow[e];
        const float4 qv = *(const float4*)&qs[e];
        px += kv.x * qv.x;
        py += kv.y * qv.y;
        pz += kv.z * qv.z;
        pw += kv.w * qv.w;
      }
      float a = (px + py) + (pz + pw);
      a += __shfl_xor(a, 1, 64);
      a += __shfl_xor(a, 2, 64);
      if (r == 0) d0 = a; else d1 = a;
    }
    if (c4 == 0) {
      const float* uv = side ? tv : tu;
      sd0[g] = d0;
      sd1[g] = d1;
      sc[g] = d0 * uv[h * 2 + 0] + d1 * uv[h * 2 + 1];
    }
  }
  __syncthreads();
  if (tid < 64) {
    const int lane = tid;
    const unsigned int kv = (lane < 48) ? f2key(sc[lane]) : 0u;
    unsigned int T = 0u;
    for (int bpos = 31; bpos >= 0; --bpos) {
      const unsigned int cand = T | (1u << bpos);
      const int c = (int)__popcll(__ballot(kv >= cand));
      if (c >= 32) T = cand;
    }
    const unsigned long long mgt = __ballot(kv > T);
    const unsigned long long meq = __ballot((kv == T) && (lane < 48));
    const unsigned long long below = ((unsigned long long)1 << lane) - 1;
    const int total_gt = (int)__popcll(mgt);
    const int need = 32 - total_gt;
    int slot = -1;
    if (kv > T) {
      slot = (int)__popcll(mgt & below);
    } else if (kv == T && lane < 48) {
      const int r = (int)__popcll(meq & below);
      if (r < need) slot = total_gt + r;
    }
    if (slot >= 0) {
      int* iout = (side ? i2 : i1) + bh * 32;
      float* gout = (side ? g2 : g1) + (size_t)bh * 64;
      iout[slot] = ssel[lane];
      gout[slot * 2 + 0] = sd0[lane];
      gout[slot * 2 + 1] = sd1[lane];
    }
  }
}

// ---------------- stage-2: bilinear scores, bisection top-32, set-softmax ---
__global__ void k_stage2(const float* __restrict__ g1, const float* __restrict__ g2,
                         const int* __restrict__ i1, const int* __restrict__ i2,
                         const float* __restrict__ tucker_core,
                         const int* __restrict__ shuffle_index,
                         float* __restrict__ w_out, int* __restrict__ sh_out) {
  __shared__ float sg1x[32], sg1y[32], sg2x[32], sg2y[32];
  __shared__ int si1[32], si2[32];
  const int bh = blockIdx.x;
  const int h = bh & 1;
  const int lane = threadIdx.x;
  if (lane < 32) {
    const float2 p1 = *(const float2*)&g1[(bh * 32 + lane) * 2];
    const float2 p2 = *(const float2*)&g2[(bh * 32 + lane) * 2];
    sg1x[lane] = p1.x;
    sg1y[lane] = p1.y;
    sg2x[lane] = p2.x;
    sg2y[lane] = p2.y;
    si1[lane] = i1[bh * 32 + lane];
    si2[lane] = i2[bh * 32 + lane];
  }
  __syncthreads();
  const float c00 = tucker_core[h * 4 + 0] + tucker_core[8 + h * 4 + 0];
  const float c01 = tucker_core[h * 4 + 1] + tucker_core[8 + h * 4 + 1];
  const float c10 = tucker_core[h * 4 + 2] + tucker_core[8 + h * 4 + 2];
  const float c11 = tucker_core[h * 4 + 3] + tucker_core[8 + h * 4 + 3];
  float sv[16];
  unsigned int ku[16];
  float m = -FLT_MAX;
#pragma unroll
  for (int i = 0; i < 16; ++i) {
    const int p = lane + (i << 6);
    const int k = p >> 5, l = p & 31;
    const float a0 = sg1x[k] * c00 + sg1y[k] * c10;
    const float a1 = sg1x[k] * c01 + sg1y[k] * c11;
    sv[i] = a0 * sg2x[l] + a1 * sg2y[l];
    ku[i] = f2key(sv[i]);
    m = fmaxf(m, sv[i]);
  }
#pragma unroll
  for (int o = 32; o; o >>= 1) m = fmaxf(m, __shfl_xor(m, o, 64));
  unsigned int T = 0u;
  for (int bpos = 31; bpos >= 0; --bpos) {
    const unsigned int cand = T | (1u << bpos);
    int c = 0;
#pragma unroll
    for (int i = 0; i < 16; ++i) c += (int)__popcll(__ballot(ku[i] >= cand));
    if (c >= 32) T = cand;
  }
  int cgt = 0, ceq = 0;
  float zp = 0.f;
#pragma unroll
  for (int i = 0; i < 16; ++i) {
    if (ku[i] > T) { ++cgt; zp += expf(sv[i] - m); }
    ceq += (ku[i] == T) ? 1 : 0;
  }
  int pgt = cgt, peq = ceq;
#pragma unroll
  for (int o = 1; o < 64; o <<= 1) {
    const int t1 = __shfl_up(pgt, o, 64);
    const int t2 = __shfl_up(peq, o, 64);
    if (lane >= o) { pgt += t1; peq += t2; }
  }
  const int total_gt = __shfl(pgt, 63, 64);
  const int need_eq = 32 - total_gt;
  const float eT = expf(key2f(T) - m);
  const float Z = wave_sum(zp) + (float)need_eq * eT;
  const float rZ = 1.f / Z;
  int sgt = pgt - cgt;
  int seq = peq - ceq;
  float* wp = w_out + bh * 32;
  int* shp = sh_out + bh * 32;
#pragma unroll
  for (int i = 0; i < 16; ++i) {
    int slot = -1;
    if (ku[i] > T) {
      slot = sgt++;
    } else if (ku[i] == T) {
      if (seq < need_eq) slot = total_gt + seq;
      ++seq;
    }
    if (slot >= 0) {
      const int p = lane + (i << 6);
      const int k = p >> 5, l = p & 31;
      const int ai = si1[k] * 1024 + si2[l];
      wp[slot] = expf(sv[i] - m) * rZ;
      shp[slot] = shuffle_index[ai];  // = (eidx<<18) | vidx
    }
  }
}

// ---------------- weighted value gather/aggregate -> bf16 agg ---------------
__global__ __launch_bounds__(256) void k_agg(const float* __restrict__ w_out,
                                             const int* __restrict__ sh_out,
                                             const float* __restrict__ values,
                                             unsigned short* __restrict__ aggb) {
  __shared__ float acc[4][1024];
  const int b = blockIdx.x;
  const int tid = threadIdx.x;
  const int wave = tid >> 6, lane = tid & 63;
  for (int i = tid; i < 4096; i += 256) ((float*)acc)[i] = 0.f;
  __syncthreads();
  for (int j = wave; j < 64; j += 4) {
    const float wgt = w_out[b * 64 + j];
    const int sh = sh_out[b * 64 + j];
    const int vidx = sh & 0x3FFFF;
    const int e = sh >> 18;
    const float4 v = *(const float4*)&values[(size_t)vidx * 256 + lane * 4];
    float* dst = &acc[wave][e * 256 + lane * 4];
    dst[0] += wgt * v.x;
    dst[1] += wgt * v.y;
    dst[2] += wgt * v.z;
    dst[3] += wgt * v.w;
  }
  __syncthreads();
  for (int i = tid; i < 1024; i += 256)
    aggb[(size_t)b * 1024 + i] = f2bf(acc[0][i] + acc[1][i] + acc[2][i] + acc[3][i]);
}

// ---------------- transpose + convert f32 -> bf16 (for wv) ------------------
__global__ __launch_bounds__(256) void k_tcvt(const float* __restrict__ src,
                                              unsigned short* __restrict__ dst,
                                              int R, int C) {
  __shared__ float tile[64][65];
  const int br = blockIdx.x * 64;
  const int bc = blockIdx.y * 64;
  const int tid = threadIdx.x;
  for (int idx = tid; idx < 4096; idx += 256) {
    const int r = idx >> 6, c = idx & 63;
    tile[r][c] = src[(size_t)(br + r) * C + bc + c];
  }
  __syncthreads();
  for (int idx = tid; idx < 4096; idx += 256) {
    const int cc = idx >> 6, rr = idx & 63;
    dst[(size_t)(bc + cc) * R + br + rr] = f2bf(tile[rr][cc]);
  }
}

// ---------------- bf16 MFMA GEMM (scores + final projection) ----------------
// C[M][N] = A[M][K] @ Bt[N][K]^T; B-column offset bsk applied for rows >=
// m_split (fused two-sided score GEMM); pass bsk=0, m_split=big otherwise.
template <int BM, int BN>
__global__ __launch_bounds__(256) void k_mfma(const unsigned short* __restrict__ A,
                                              const unsigned short* __restrict__ Bt,
                                              float* __restrict__ C,
                                              int M, int N, int K,
                                              int bsk, int m_split) {
  constexpr int FM = BM / 32;
  constexpr int FN = BN / 32;
  __shared__ float4 As[BM * 4];
  __shared__ float4 Bs[BN * 4];
  const int tid = threadIdx.x;
  const int lane = tid & 63;
  const int w = tid >> 6;
  const int wr = w >> 1, wc = w & 1;
  const int bm = blockIdx.x * BM, bn = blockIdx.y * BN;
  const int bcol = bn + ((bm >= m_split) ? bsk : 0);
  f32x4 acc[FM][FN];
#pragma unroll
  for (int i = 0; i < FM; ++i)
#pragma unroll
    for (int j = 0; j < FN; ++j) acc[i][j] = 0.f;

  for (int k0 = 0; k0 < K; k0 += 32) {
#pragma unroll
    for (int u = 0; u < BM * 4 / 256; ++u) {
      const int q = tid + u * 256;
      const int m = q >> 2, c = q & 3;
      As[(m >> 4) * 64 + c * 16 + (m & 15)] =
          *(const float4*)&A[(size_t)(bm + m) * K + k0 + c * 8];
    }
#pragma unroll
    for (int u = 0; u < BN * 4 / 256; ++u) {
      const int q = tid + u * 256;
      const int n = q >> 2, c = q & 3;
      Bs[(n >> 4) * 64 + c * 16 + (n & 15)] =
          *(const float4*)&Bt[(size_t)(bcol + n) * K + k0 + c * 8];
    }
    __syncthreads();
    bf16x8 af[FM], bfr[FN];
#pragma unroll
    for (int i = 0; i < FM; ++i) af[i] = *(const bf16x8*)&As[(wr * FM + i) * 64 + lane];
#pragma unroll
    for (int j = 0; j < FN; ++j) bfr[j] = *(const bf16x8*)&Bs[(wc * FN + j) * 64 + lane];
#pragma unroll
    for (int i = 0; i < FM; ++i)
#pragma unroll
      for (int j = 0; j < FN; ++j)
        acc[i][j] = __builtin_amdgcn_mfma_f32_16x16x32_bf16(af[i], bfr[j], acc[i][j], 0, 0, 0);
    __syncthreads();
  }
#pragma unroll
  for (int i = 0; i < FM; ++i) {
    const int r0 = bm + (wr * FM + i) * 16 + (lane >> 4) * 4;
#pragma unroll
    for (int j = 0; j < FN; ++j) {
      const int cc = bn + (wc * FN + j) * 16 + (lane & 15);
#pragma unroll
      for (int v = 0; v < 4; ++v) C[(size_t)(r0 + v) * N + cc] = acc[i][j][v];
    }
  }
}

// ---------------------------------------------------------------------------
extern "C" void kernel_launch(void* const* d_in, const int* in_sizes, int n_in,
                              void* d_out, int out_size, void* d_ws, size_t ws_size,
                              hipStream_t stream) {
  const float* hidden = (const float*)d_in[0];
  const float* wq     = (const float*)d_in[1];
  const float* qnw    = (const float*)d_in[2];
  const float* knw    = (const float*)d_in[3];
  const float* keys   = (const float*)d_in[4];
  const float* tcore  = (const float*)d_in[5];
  const float* tu     = (const float*)d_in[6];
  const float* tv     = (const float*)d_in[7];
  const float* values = (const float*)d_in[8];
  const float* wvm    = (const float*)d_in[9];
  const int*   shuf   = (const int*)d_in[10];
  float* out = (float*)d_out;

  char* ws = (char*)d_ws;
  size_t off = 0;
  auto alloc = [&](size_t bytes) -> void* {
    void* p = ws + off;
    off += (bytes + 255) & ~(size_t)255;
    return p;
  };
  unsigned short* Bctbf = (unsigned short*)alloc((size_t)4096 * 256 * 2);  // 2 MB
  float* Bg    = (float*)alloc((size_t)4096 * 512 * 4);                    // 8 MB
  float* q12n  = (float*)alloc((size_t)8192 * 256 * 4);                    // 8 MB
  unsigned short* q12bf = (unsigned short*)alloc((size_t)8192 * 256 * 2);  // 4 MB
  unsigned short* wvT  = (unsigned short*)alloc((size_t)2048 * 1024 * 2);  // 4 MB
  unsigned short* aggb = (unsigned short*)alloc((size_t)4096 * 1024 * 2);  // 8 MB
  int*   i1c = (int*)  alloc((size_t)8192 * 48 * 4);
  int*   i2c = (int*)  alloc((size_t)8192 * 48 * 4);
  int*   i1  = (int*)  alloc((size_t)8192 * 32 * 4);
  int*   i2  = (int*)  alloc((size_t)8192 * 32 * 4);
  float* g1  = (float*)alloc((size_t)8192 * 64 * 4);
  float* g2  = (float*)alloc((size_t)8192 * 64 * 4);
  float* wgt = (float*)alloc((size_t)8192 * 32 * 4);
  int*   sho = (int*)  alloc((size_t)8192 * 32 * 4);
  float* hiddenT = (float*)alloc((size_t)2048 * 4096 * 4);  // 32 MB
  float* big = (float*)alloc((size_t)8192 * 2048 * 4);      // 64 MB shared
  float* qpart = big;  // 4 x 4096 x 512 (32 MB), dead after k_ln_q
  float* s_r   = big;  // 8192 x 2048 (64 MB), written after
  (void)ws_size; (void)in_sizes; (void)n_in; (void)out_size;

  // 1) keys -> Bg (raw keysn, f32) + Bctbf (u/v-combined, bf16)
  k_prep32<<<4096, 64, 0, stream>>>(keys, knw, tu, tv, Bctbf, Bg);
  // 2) wv -> bf16 transposed; hidden -> hiddenT
  k_tcvt<<<dim3(16, 32), 256, 0, stream>>>(wvm, wvT, 1024, 2048);
  k_tr32<<<dim3(64, 32), 256, 0, stream>>>(hidden, hiddenT, 4096, 2048);
  // 3) q projection, f32 split-K=4
  k_gemm32<4><<<dim3(32, 4, 4), 256, 0, stream>>>(
      hiddenT, 4096, wq, 512, 0, 1 << 30, qpart, 4096, 512, 2048);
  // 4) sum partials + LN -> q12n (f32) + q12bf (bf16)
  k_ln_q<<<8192, 64, 0, stream>>>(qpart, qnw, q12n, q12bf);
  // 5) prefilter score GEMM (bf16 MFMA, fused sides via bsk/m_split)
  k_mfma<128, 128><<<dim3(64, 16), 256, 0, stream>>>(
      q12bf, Bctbf, s_r, 8192, 2048, 256, 2048, 4096);
  // 6) stage-1 top-48 prefilter
  k_topk1<<<16384, 64, 0, stream>>>(s_r, i1c, i2c);
  // 7) exact f32 rescore + exact top-32 + per-rank g emission
  k_sel<<<16384, 256, 0, stream>>>(q12n, Bg, i1c, i2c, tu, tv, i1, i2, g1, g2);
  // 8) stage-2 bisection top-32 + set-softmax + shuffle
  k_stage2<<<8192, 64, 0, stream>>>(g1, g2, i1, i2, tcore, shuf, wgt, sho);
  // 9) weighted value gather -> bf16 agg
  k_agg<<<4096, 256, 0, stream>>>(wgt, sho, values, aggb);
  // 10) output projection (bf16 MFMA)
  k_mfma<128, 128><<<dim3(32, 16), 256, 0, stream>>>(
      aggb, wvT, out, 4096, 2048, 1024, 0, 1 << 30);
}